// Round 7
// baseline (2076.569 us; speedup 1.0000x reference)
//
#include <hip/hip_runtime.h>

#define TOKENS 4096
#define HD 2048
#define FF 8192
#define NE 8
#define NS 2

typedef __attribute__((ext_vector_type(8))) short bf16x8;
typedef __attribute__((ext_vector_type(4))) float f32x4;

__device__ __forceinline__ unsigned rnd_bf(unsigned u) {
  return u + 0x7fffu + ((u >> 16) & 1u);
}
__device__ __forceinline__ unsigned short f2bf(float f) {
  unsigned u = __builtin_bit_cast(unsigned, f);
  return (unsigned short)(rnd_bf(u) >> 16);
}

#define GLDS16(gp, lp)                                                         \
  __builtin_amdgcn_global_load_lds(                                            \
      (const __attribute__((address_space(1))) unsigned*)(const void*)(gp),    \
      (__attribute__((address_space(3))) unsigned*)(lp), 16, 0, 0)

// ---------------- cast x f32 -> bf16 ----------------
__global__ void cast_x_kernel(const float* __restrict__ x, unsigned short* __restrict__ xb) {
  const size_t i = ((size_t)blockIdx.x * 256 + threadIdx.x) * 4;
  float4 v = *(const float4*)(x + i);
  ushort4 o;
  o.x = f2bf(v.x); o.y = f2bf(v.y); o.z = f2bf(v.z); o.w = f2bf(v.w);
  *(ushort4*)(xb + i) = o;
}

// ---------------- router ----------------
__global__ void router_kernel(const float* __restrict__ x, const float* __restrict__ wg,
                              float* __restrict__ logits_out, int* __restrict__ topi,
                              float* __restrict__ topv, int* __restrict__ counts) {
  const int wave = threadIdx.x >> 6, lane = threadIdx.x & 63;
  const int t = blockIdx.x * 4 + wave;
  const float* xr = x + (size_t)t * HD;
  float acc[8];
#pragma unroll
  for (int e = 0; e < 8; ++e) acc[e] = 0.f;
  for (int d = lane; d < HD; d += 64) {
    const float xv = xr[d];
    const float4 w0 = *(const float4*)(wg + (size_t)d * 8);
    const float4 w1 = *(const float4*)(wg + (size_t)d * 8 + 4);
    acc[0] += xv * w0.x; acc[1] += xv * w0.y; acc[2] += xv * w0.z; acc[3] += xv * w0.w;
    acc[4] += xv * w1.x; acc[5] += xv * w1.y; acc[6] += xv * w1.z; acc[7] += xv * w1.w;
  }
#pragma unroll
  for (int e = 0; e < 8; ++e) {
#pragma unroll
    for (int off = 32; off > 0; off >>= 1) acc[e] += __shfl_xor(acc[e], off);
  }
  if (lane == 0) {
    *(float4*)(logits_out + (size_t)t * 8)     = make_float4(acc[0], acc[1], acc[2], acc[3]);
    *(float4*)(logits_out + (size_t)t * 8 + 4) = make_float4(acc[4], acc[5], acc[6], acc[7]);
    float mx = acc[0];
#pragma unroll
    for (int e = 1; e < 8; ++e) mx = fmaxf(mx, acc[e]);
    float p[8], s = 0.f;
#pragma unroll
    for (int e = 0; e < 8; ++e) { p[e] = expf(acc[e] - mx); s += p[e]; }
    const float inv = 1.f / s;
    int i1 = 0;
#pragma unroll
    for (int e = 1; e < 8; ++e) if (acc[e] > acc[i1]) i1 = e;
    int i2 = (i1 == 0) ? 1 : 0;
#pragma unroll
    for (int e = 0; e < 8; ++e) if (e != i1 && acc[e] > acc[i2]) i2 = e;
    topi[2 * t]     = i1; topv[2 * t]     = p[i1] * inv;
    topi[2 * t + 1] = i2; topv[2 * t + 1] = p[i2] * inv;
    atomicAdd(&counts[i1], 1);
    atomicAdd(&counts[i2], 1);
  }
}

__global__ void offs_kernel(const int* __restrict__ counts, int* __restrict__ offs,
                            int* __restrict__ cursors) {
  if (threadIdx.x == 0) {
    int r = 0;
    for (int e = 0; e < NE; ++e) { offs[e] = r; cursors[e] = r; r += counts[e]; }
  }
}

__global__ void gather_kernel(const unsigned short* __restrict__ xb,
                              const int* __restrict__ topi, const float* __restrict__ topv,
                              int* __restrict__ cursors, unsigned short* __restrict__ xg,
                              int* __restrict__ row_token, float* __restrict__ row_gate) {
  const int wave = threadIdx.x >> 6, lane = threadIdx.x & 63;
  const int t = blockIdx.x * 4 + wave;
  const uint4* src = (const uint4*)(xb + (size_t)t * HD);
#pragma unroll
  for (int j = 0; j < 2; ++j) {
    const int e = topi[2 * t + j];
    int pos = 0;
    if (lane == 0) {
      pos = atomicAdd(&cursors[e], 1);
      row_token[pos] = t;
      row_gate[pos] = topv[2 * t + j];
    }
    pos = __shfl(pos, 0);
    uint4* dst = (uint4*)(xg + (size_t)pos * HD);
#pragma unroll
    for (int c = lane; c < 256; c += 64) dst[c] = src[c];
  }
}

// ---------------- pack: f32 [K][N] -> bf16 B^T [N][K] ----------------
template <int K, int N>
__global__ __launch_bounds__(256) void pack_wt(const float* __restrict__ we,
                                               const float* __restrict__ ws,
                                               unsigned short* __restrict__ dstw) {
  const int e = blockIdx.z;
  const float* src = (e < NE) ? (we + (size_t)e * K * N) : (ws + (size_t)(e - NE) * K * N);
  unsigned short* dst = dstw + (size_t)e * K * N;
  const int nt = blockIdx.x * 64;
  const int kt = blockIdx.y * 64;
  __shared__ unsigned short t[64][73];
  const int tid = threadIdx.x;
  const int rr = tid >> 4, cc = (tid & 15) * 4;
#pragma unroll
  for (int i = 0; i < 4; ++i) {
    const int k = rr + i * 16;
    float4 v = *(const float4*)(src + (size_t)(kt + k) * N + nt + cc);
    t[k][cc + 0] = f2bf(v.x);
    t[k][cc + 1] = f2bf(v.y);
    t[k][cc + 2] = f2bf(v.z);
    t[k][cc + 3] = f2bf(v.w);
  }
  __syncthreads();
  const int nr = tid >> 2, kc = (tid & 3) * 16;
  unsigned u[8];
#pragma unroll
  for (int j = 0; j < 8; ++j)
    u[j] = (unsigned)t[kc + 2 * j][nr] | ((unsigned)t[kc + 2 * j + 1][nr] << 16);
  unsigned short* dp = dst + (size_t)(nt + nr) * K + kt + kc;
  uint4 v0; v0.x = u[0]; v0.y = u[1]; v0.z = u[2]; v0.w = u[3];
  uint4 v1; v1.x = u[4]; v1.y = u[5]; v1.z = u[6]; v1.w = u[7];
  *(uint4*)dp = v0;
  *(uint4*)(dp + 8) = v1;
}

// ---------------- frag read / mfma helpers ----------
template <int MS>
__device__ __forceinline__ void rd_a(bf16x8 (&d)[8], const unsigned short* base,
                                     int wr, int fr, int fq, int swz) {
#pragma unroll
  for (int mi = 0; mi < 4; ++mi)
#pragma unroll
    for (int ks = 0; ks < 2; ++ks)
      d[mi * 2 + ks] = *(const bf16x8*)(base + (wr * 128 + MS * 64 + mi * 16 + fr) * 64 +
                                        (((ks * 4 + fq) ^ swz) << 3));
}
template <int NSUB>
__device__ __forceinline__ void rd_b(bf16x8 (&d)[4], const unsigned short* base,
                                     int wc, int fr, int fq, int swz) {
#pragma unroll
  for (int ni = 0; ni < 2; ++ni)
#pragma unroll
    for (int ks = 0; ks < 2; ++ks)
      d[ni * 2 + ks] = *(const bf16x8*)(base + (wc * 64 + NSUB * 32 + ni * 16 + fr) * 64 +
                                        (((ks * 4 + fq) ^ swz) << 3));
}
template <int MS, int NSUB>
__device__ __forceinline__ void mm16(f32x4 (&acc)[8][4], const bf16x8 (&a)[8],
                                     const bf16x8 (&b)[4]) {
  __builtin_amdgcn_s_setprio(1);
#pragma unroll
  for (int mi = 0; mi < 4; ++mi)
#pragma unroll
    for (int ni = 0; ni < 2; ++ni)
#pragma unroll
      for (int ks = 0; ks < 2; ++ks)
        acc[MS * 4 + mi][NSUB * 2 + ni] = __builtin_amdgcn_mfma_f32_16x16x32_bf16(
            a[mi * 2 + ks], b[ni * 2 + ks], acc[MS * 4 + mi][NSUB * 2 + ni], 0, 0, 0);
  __builtin_amdgcn_s_setprio(0);
}

// phase fence sequence: pin reads/stages before the barrier, drain LDS after
// it, and keep the MFMA cluster intact (m201 discipline; raw s_barrier is NOT
// a scheduling fence for hipcc, so without these the phases collapse).
#define PH_BAR_PRE()                                                           \
  __builtin_amdgcn_sched_barrier(0);                                           \
  __builtin_amdgcn_s_barrier();                                                \
  asm volatile("s_waitcnt lgkmcnt(0)" ::: "memory");                           \
  __builtin_amdgcn_sched_barrier(0)
#define PH_BAR_POST()                                                          \
  __builtin_amdgcn_sched_barrier(0);                                           \
  __builtin_amdgcn_s_barrier()

// ---------------- 256x256 8-phase grouped GEMM, fenced schedule ----------
template <int MODE>
__global__ __launch_bounds__(512, 2) void gemm8p(
    const unsigned short* __restrict__ Ash,   // MODE0: xb, MODE1: hbuf
    const unsigned short* __restrict__ Art,   // MODE0: xg, MODE1: hbuf
    const unsigned short* __restrict__ wt,    // packed B^T [10][N*K]
    const float* __restrict__ bE, const float* __restrict__ bS,
    unsigned short* __restrict__ hout, float* __restrict__ out,
    const int* __restrict__ counts, const int* __restrict__ offs,
    const int* __restrict__ row_token, const float* __restrict__ row_gate) {
  constexpr int K = (MODE == 0) ? HD : FF;
  constexpr int N = (MODE == 0) ? FF : HD;
  constexpr int NBX = N / 256;          // 32 or 8
  constexpr int NWG = NBX * 16;         // xy blocks per expert (%8==0)
  extern __shared__ unsigned short smem[];  // [2][A 16384 | B 16384] ushorts

  const int e = blockIdx.z;
  int M;
  const unsigned short* A;
  const float* bias;
  int hbase = 0;
  const int* tok = nullptr;
  const float* gt = nullptr;

  if (e < NE) {
    M = counts[e];
    const int off = offs[e];
    A = Art + (size_t)off * K;
    if (MODE == 1) { tok = row_token + off; gt = row_gate + off; }
    bias = bE + (size_t)e * N;
    hbase = off;
  } else {
    M = TOKENS;
    const int se = e - NE;
    hbase = 2 * TOKENS + se * TOKENS;
    if (MODE == 0) A = Ash;
    else           A = Ash + (size_t)hbase * K;
    bias = bS + (size_t)se * N;
  }
  const unsigned short* Bt = wt + (size_t)e * HD * FF;  // [N][K]

  // chunked XCD swizzle, m-fast (period 16 divides chunk): uniform validity.
  int flat = blockIdx.x + NBX * blockIdx.y;
  flat = (flat & 7) * (NWG >> 3) + (flat >> 3);
  const int m0 = (flat & 15) * 256;
  const int n0 = (flat >> 4) * 256;
  if (m0 >= M) return;

  const int tid = threadIdx.x;
  const int wid = tid >> 6, ln = tid & 63;
  const int wr = wid >> 2, wc = wid & 3;
  const int fr = ln & 15, fq = ln >> 4;
  const int swz = fr & 7;

  // wave-aligned staging lanes: 8 rows x 8 col-octets per instruction
  const int lr8 = ln >> 3;                 // 0..7 (row within 8-row group)
  const int lc8 = ln & 7;                  // col octet
  const int scol = (lc8 ^ lr8) << 3;       // pre-swizzled global col (elems)
  const int wrA = wr * 128 + wc * 16;      // wave's A staging base row (+s*64)
  const int wcB = wc * 64 + wr * 16;       // wave's B staging base row (+s*32)

#define SA(s, kt, b)                                                           \
  { const int r0_ = wrA + (s) * 64 + lr8;                                      \
    const unsigned short* s_ = A + (size_t)(m0 + r0_) * K + (kt) * 64 + scol;  \
    unsigned short* d_ = smem + (b) * 32768 + r0_ * 64 + lc8 * 8;              \
    GLDS16(s_, d_); GLDS16(s_ + (size_t)8 * K, d_ + 8 * 64); }
#define SB(s, kt, b)                                                           \
  { const int r0_ = wcB + (s) * 32 + lr8;                                      \
    const unsigned short* s_ = Bt + (size_t)(n0 + r0_) * K + (kt) * 64 + scol; \
    unsigned short* d_ = smem + (b) * 32768 + 16384 + r0_ * 64 + lc8 * 8;      \
    GLDS16(s_, d_); GLDS16(s_ + (size_t)8 * K, d_ + 8 * 64); }

  f32x4 acc[8][4];
#pragma unroll
  for (int i = 0; i < 8; ++i)
#pragma unroll
    for (int j = 0; j < 4; ++j) acc[i][j] = (f32x4){0.f, 0.f, 0.f, 0.f};

  // prologue: tile0 -> buf0, tile1 -> buf1; wait for tile0 only.
  SA(0, 0, 0); SA(1, 0, 0); SB(0, 0, 0); SB(1, 0, 0);
  SA(0, 1, 1); SA(1, 1, 1); SB(0, 1, 1); SB(1, 1, 1);
  asm volatile("s_waitcnt vmcnt(8)" ::: "memory");
  __builtin_amdgcn_s_barrier();

  bf16x8 a0[8], a1[8], b0[4], b1[4];
  const int nkt = K / 64;
  for (int t = 0; t < nkt; ++t) {
    const int cur = t & 1;
    const int tp2 = (t + 2 < nkt) ? t + 2 : t;  // tail: re-stage own tile (same
                                                // buffer parity, same bytes)
    const unsigned short* As_c = smem + cur * 32768;
    const unsigned short* Bs_c = As_c + 16384;
    // ---- ph1: Q(m0,n0) ---- (12 ds_reads -> partial drain hint pre-barrier)
    rd_a<0>(a0, As_c, wr, fr, fq, swz);
    rd_b<0>(b0, Bs_c, wc, fr, fq, swz);
    asm volatile("s_waitcnt lgkmcnt(8)" ::: "memory");
    PH_BAR_PRE();
    mm16<0, 0>(acc, a0, b0);
    PH_BAR_POST();
    // ---- ph2: Q(m0,n1) ---- (A-sub0 & B-sub0 of cur fully read in ph1)
    rd_b<1>(b1, Bs_c, wc, fr, fq, swz);
    SA(0, tp2, cur); SB(0, tp2, cur);
    PH_BAR_PRE();
    mm16<0, 1>(acc, a0, b1);
    PH_BAR_POST();
    // ---- ph3: Q(m1,n1) ---- (B-sub1 fully read in ph2)
    rd_a<1>(a1, As_c, wr, fr, fq, swz);
    SB(1, tp2, cur);
    PH_BAR_PRE();
    mm16<1, 1>(acc, a1, b1);
    PH_BAR_POST();
    // ---- ph4: Q(m1,n0) ---- (A-sub1 fully read in ph3; no ds_reads here)
    SA(1, tp2, cur);
    __builtin_amdgcn_sched_barrier(0);
    __builtin_amdgcn_s_barrier();
    __builtin_amdgcn_sched_barrier(0);
    mm16<1, 0>(acc, a1, b0);
    __builtin_amdgcn_sched_barrier(0);
    // boundary: tile t+1 (issued in iter t-1 / prologue) must be landed;
    // tile t+2's 8 loads (issued this iter) stay in flight.
    asm volatile("s_waitcnt vmcnt(8)" ::: "memory");
    __builtin_amdgcn_s_barrier();
  }
#undef SA
#undef SB

  if (MODE == 0) {
#pragma unroll
    for (int nn = 0; nn < 4; ++nn) {
      const int col = n0 + wc * 64 + (nn >> 1) * 32 + (nn & 1) * 16 + fr;
      const float bb = bias[col];
#pragma unroll
      for (int mm = 0; mm < 8; ++mm) {
#pragma unroll
        for (int j = 0; j < 4; ++j) {
          const int r = m0 + wr * 128 + (mm >> 2) * 64 + (mm & 3) * 16 + fq * 4 + j;
          if (r < M) {
            float v = acc[mm][nn][j] + bb;
            v = v > 0.f ? v : 0.f;
            hout[(size_t)(hbase + r) * FF + col] = f2bf(v);
          }
        }
      }
    }
  } else {
#pragma unroll
    for (int mm = 0; mm < 8; ++mm) {
#pragma unroll
      for (int j = 0; j < 4; ++j) {
        const int r = m0 + wr * 128 + (mm >> 2) * 64 + (mm & 3) * 16 + fq * 4 + j;
        if (r < M) {
          const int t = tok ? tok[r] : r;
          const float g = gt ? gt[r] : 1.f;
          float* orow = out + (size_t)t * HD + n0;
#pragma unroll
          for (int nn = 0; nn < 4; ++nn) {
            const int col = wc * 64 + (nn >> 1) * 32 + (nn & 1) * 16 + fr;
            atomicAdd(orow + col, g * (acc[mm][nn][j] + bias[n0 + col]));
          }
        }
      }
    }
  }
}

extern "C" void kernel_launch(void* const* d_in, const int* in_sizes, int n_in,
                              void* d_out, int out_size, void* d_ws, size_t ws_size,
                              hipStream_t stream) {
  const float* x     = (const float*)d_in[0];
  const float* ws_w1 = (const float*)d_in[1];
  const float* ws_b1 = (const float*)d_in[2];
  const float* ws_w2 = (const float*)d_in[3];
  const float* ws_b2 = (const float*)d_in[4];
  const float* we_w1 = (const float*)d_in[5];
  const float* we_b1 = (const float*)d_in[6];
  const float* we_w2 = (const float*)d_in[7];
  const float* we_b2 = (const float*)d_in[8];
  const float* wg    = (const float*)d_in[9];

  float* out = (float*)d_out;
  float* logits = out + (size_t)TOKENS * HD;

  // layout: wt | xb | xg | hbuf | ctrl  (xg before hbuf so 256-tile A-overruns
  // of the last routed expert land inside hbuf, not past the workspace)
  char* ws = (char*)d_ws;
  unsigned short* wt   = (unsigned short*)ws;                   // 335,544,320 B
  unsigned short* xb   = (unsigned short*)(ws + 335544320);     //  16,777,216 B
  unsigned short* xg   = (unsigned short*)(ws + 352321536);     //  34,078,720 B
  unsigned short* hbuf = (unsigned short*)(ws + 386400256);     // 268,435,456 B
  char* ctrl = ws + 654835712;
  int*   row_token = (int*)(ctrl);
  float* row_gate  = (float*)(ctrl + 32768);
  int*   topi      = (int*)(ctrl + 65536);
  float* topv      = (float*)(ctrl + 98304);
  int*   counts    = (int*)(ctrl + 131072);
  int*   offs      = (int*)(ctrl + 131104);
  int*   cursors   = (int*)(ctrl + 131136);

  hipFuncSetAttribute(reinterpret_cast<const void*>(gemm8p<0>),
                      hipFuncAttributeMaxDynamicSharedMemorySize, 131072);
  hipFuncSetAttribute(reinterpret_cast<const void*>(gemm8p<1>),
                      hipFuncAttributeMaxDynamicSharedMemorySize, 131072);

  hipMemsetAsync(out, 0, (size_t)TOKENS * HD * sizeof(float), stream);
  hipMemsetAsync(counts, 0, NE * sizeof(int), stream);

  cast_x_kernel<<<8192, 256, 0, stream>>>(x, xb);
  router_kernel<<<1024, 256, 0, stream>>>(x, wg, logits, topi, topv, counts);
  offs_kernel<<<1, 64, 0, stream>>>(counts, offs, cursors);
  gather_kernel<<<1024, 256, 0, stream>>>(xb, topi, topv, cursors, xg, row_token, row_gate);

  // pack W1 [10][2048][8192] f32 -> [10][8192][2048] bf16
  pack_wt<HD, FF><<<dim3(FF / 64, HD / 64, 10), 256, 0, stream>>>(we_w1, ws_w1, wt);
  // GEMM1: h = relu(x*W1+b1)   (N=8192 -> 32 n-blocks, 16 m-blocks, 10 experts)
  gemm8p<0><<<dim3(32, 16, 10), 512, 131072, stream>>>(
      xb, xg, wt, we_b1, ws_b1, hbuf, nullptr, counts, offs, nullptr, nullptr);
  // pack W2 [10][8192][2048] f32 -> [10][2048][8192] bf16 (reuses wt)
  pack_wt<FF, HD><<<dim3(HD / 64, FF / 64, 10), 256, 0, stream>>>(we_w2, ws_w2, wt);
  // GEMM2: out += gate*(h*W2+b2)  (N=2048 -> 8 n-blocks)
  gemm8p<1><<<dim3(8, 16, 10), 512, 131072, stream>>>(
      hbuf, hbuf, wt, we_b2, ws_b2, nullptr, out, counts, offs, row_token, row_gate);

  (void)in_sizes; (void)n_in; (void)out_size; (void)ws_size;
}

// Round 8
// 2076.361 us; speedup vs baseline: 1.0001x; 1.0001x over previous
//
#include <hip/hip_runtime.h>

#define TOKENS 4096
#define HD 2048
#define FF 8192
#define NE 8
#define NS 2

typedef __attribute__((ext_vector_type(8))) short bf16x8;
typedef __attribute__((ext_vector_type(4))) float f32x4;

__device__ __forceinline__ unsigned rnd_bf(unsigned u) {
  return u + 0x7fffu + ((u >> 16) & 1u);
}
__device__ __forceinline__ unsigned short f2bf(float f) {
  unsigned u = __builtin_bit_cast(unsigned, f);
  return (unsigned short)(rnd_bf(u) >> 16);
}

#define GLDS16(gp, lp)                                                         \
  __builtin_amdgcn_global_load_lds(                                            \
      (const __attribute__((address_space(1))) unsigned*)(const void*)(gp),    \
      (__attribute__((address_space(3))) unsigned*)(lp), 16, 0, 0)

// ---------------- cast x f32 -> bf16 ----------------
__global__ void cast_x_kernel(const float* __restrict__ x, unsigned short* __restrict__ xb) {
  const size_t i = ((size_t)blockIdx.x * 256 + threadIdx.x) * 4;
  float4 v = *(const float4*)(x + i);
  ushort4 o;
  o.x = f2bf(v.x); o.y = f2bf(v.y); o.z = f2bf(v.z); o.w = f2bf(v.w);
  *(ushort4*)(xb + i) = o;
}

// ---------------- router ----------------
__global__ void router_kernel(const float* __restrict__ x, const float* __restrict__ wg,
                              float* __restrict__ logits_out, int* __restrict__ topi,
                              float* __restrict__ topv, int* __restrict__ counts) {
  const int wave = threadIdx.x >> 6, lane = threadIdx.x & 63;
  const int t = blockIdx.x * 4 + wave;
  const float* xr = x + (size_t)t * HD;
  float acc[8];
#pragma unroll
  for (int e = 0; e < 8; ++e) acc[e] = 0.f;
  for (int d = lane; d < HD; d += 64) {
    const float xv = xr[d];
    const float4 w0 = *(const float4*)(wg + (size_t)d * 8);
    const float4 w1 = *(const float4*)(wg + (size_t)d * 8 + 4);
    acc[0] += xv * w0.x; acc[1] += xv * w0.y; acc[2] += xv * w0.z; acc[3] += xv * w0.w;
    acc[4] += xv * w1.x; acc[5] += xv * w1.y; acc[6] += xv * w1.z; acc[7] += xv * w1.w;
  }
#pragma unroll
  for (int e = 0; e < 8; ++e) {
#pragma unroll
    for (int off = 32; off > 0; off >>= 1) acc[e] += __shfl_xor(acc[e], off);
  }
  if (lane == 0) {
    *(float4*)(logits_out + (size_t)t * 8)     = make_float4(acc[0], acc[1], acc[2], acc[3]);
    *(float4*)(logits_out + (size_t)t * 8 + 4) = make_float4(acc[4], acc[5], acc[6], acc[7]);
    float mx = acc[0];
#pragma unroll
    for (int e = 1; e < 8; ++e) mx = fmaxf(mx, acc[e]);
    float p[8], s = 0.f;
#pragma unroll
    for (int e = 0; e < 8; ++e) { p[e] = expf(acc[e] - mx); s += p[e]; }
    const float inv = 1.f / s;
    int i1 = 0;
#pragma unroll
    for (int e = 1; e < 8; ++e) if (acc[e] > acc[i1]) i1 = e;
    int i2 = (i1 == 0) ? 1 : 0;
#pragma unroll
    for (int e = 0; e < 8; ++e) if (e != i1 && acc[e] > acc[i2]) i2 = e;
    topi[2 * t]     = i1; topv[2 * t]     = p[i1] * inv;
    topi[2 * t + 1] = i2; topv[2 * t + 1] = p[i2] * inv;
    atomicAdd(&counts[i1], 1);
    atomicAdd(&counts[i2], 1);
  }
}

__global__ void offs_kernel(const int* __restrict__ counts, int* __restrict__ offs,
                            int* __restrict__ cursors) {
  if (threadIdx.x == 0) {
    int r = 0;
    for (int e = 0; e < NE; ++e) { offs[e] = r; cursors[e] = r; r += counts[e]; }
  }
}

__global__ void gather_kernel(const unsigned short* __restrict__ xb,
                              const int* __restrict__ topi, const float* __restrict__ topv,
                              int* __restrict__ cursors, unsigned short* __restrict__ xg,
                              int* __restrict__ row_token, float* __restrict__ row_gate) {
  const int wave = threadIdx.x >> 6, lane = threadIdx.x & 63;
  const int t = blockIdx.x * 4 + wave;
  const uint4* src = (const uint4*)(xb + (size_t)t * HD);
#pragma unroll
  for (int j = 0; j < 2; ++j) {
    const int e = topi[2 * t + j];
    int pos = 0;
    if (lane == 0) {
      pos = atomicAdd(&cursors[e], 1);
      row_token[pos] = t;
      row_gate[pos] = topv[2 * t + j];
    }
    pos = __shfl(pos, 0);
    uint4* dst = (uint4*)(xg + (size_t)pos * HD);
#pragma unroll
    for (int c = lane; c < 256; c += 64) dst[c] = src[c];
  }
}

// ---------------- pack: f32 [K][N] -> bf16 B^T [N][K] ----------------
template <int K, int N>
__global__ __launch_bounds__(256) void pack_wt(const float* __restrict__ we,
                                               const float* __restrict__ ws,
                                               unsigned short* __restrict__ dstw) {
  const int e = blockIdx.z;
  const float* src = (e < NE) ? (we + (size_t)e * K * N) : (ws + (size_t)(e - NE) * K * N);
  unsigned short* dst = dstw + (size_t)e * K * N;
  const int nt = blockIdx.x * 64;
  const int kt = blockIdx.y * 64;
  __shared__ unsigned short t[64][73];
  const int tid = threadIdx.x;
  const int rr = tid >> 4, cc = (tid & 15) * 4;
#pragma unroll
  for (int i = 0; i < 4; ++i) {
    const int k = rr + i * 16;
    float4 v = *(const float4*)(src + (size_t)(kt + k) * N + nt + cc);
    t[k][cc + 0] = f2bf(v.x);
    t[k][cc + 1] = f2bf(v.y);
    t[k][cc + 2] = f2bf(v.z);
    t[k][cc + 3] = f2bf(v.w);
  }
  __syncthreads();
  const int nr = tid >> 2, kc = (tid & 3) * 16;
  unsigned u[8];
#pragma unroll
  for (int j = 0; j < 8; ++j)
    u[j] = (unsigned)t[kc + 2 * j][nr] | ((unsigned)t[kc + 2 * j + 1][nr] << 16);
  unsigned short* dp = dst + (size_t)(nt + nr) * K + kt + kc;
  uint4 v0; v0.x = u[0]; v0.y = u[1]; v0.z = u[2]; v0.w = u[3];
  uint4 v1; v1.x = u[4]; v1.y = u[5]; v1.z = u[6]; v1.w = u[7];
  *(uint4*)dp = v0;
  *(uint4*)(dp + 8) = v1;
}

// ---------------- frag read / mfma helpers ----------
template <int MS>
__device__ __forceinline__ void rd_a(bf16x8 (&d)[8], const unsigned short* base,
                                     int wr, int fr, int fq, int swz) {
#pragma unroll
  for (int mi = 0; mi < 4; ++mi)
#pragma unroll
    for (int ks = 0; ks < 2; ++ks)
      d[mi * 2 + ks] = *(const bf16x8*)(base + (wr * 128 + MS * 64 + mi * 16 + fr) * 64 +
                                        (((ks * 4 + fq) ^ swz) << 3));
}
template <int NSUB>
__device__ __forceinline__ void rd_b(bf16x8 (&d)[4], const unsigned short* base,
                                     int wc, int fr, int fq, int swz) {
#pragma unroll
  for (int ni = 0; ni < 2; ++ni)
#pragma unroll
    for (int ks = 0; ks < 2; ++ks)
      d[ni * 2 + ks] = *(const bf16x8*)(base + (wc * 64 + NSUB * 32 + ni * 16 + fr) * 64 +
                                        (((ks * 4 + fq) ^ swz) << 3));
}
template <int MS, int NSUB>
__device__ __forceinline__ void mm16(f32x4 (&acc)[8][4], const bf16x8 (&a)[8],
                                     const bf16x8 (&b)[4]) {
  __builtin_amdgcn_s_setprio(1);
#pragma unroll
  for (int mi = 0; mi < 4; ++mi)
#pragma unroll
    for (int ni = 0; ni < 2; ++ni)
#pragma unroll
      for (int ks = 0; ks < 2; ++ks)
        acc[MS * 4 + mi][NSUB * 2 + ni] = __builtin_amdgcn_mfma_f32_16x16x32_bf16(
            a[mi * 2 + ks], b[ni * 2 + ks], acc[MS * 4 + mi][NSUB * 2 + ni], 0, 0, 0);
  __builtin_amdgcn_s_setprio(0);
}
// 32-MFMA cluster: a-half x (b0|b1) -> acc rows [MS*4, MS*4+4)
template <int MS>
__device__ __forceinline__ void mm32(f32x4 (&acc)[8][4], const bf16x8 (&a)[8],
                                     const bf16x8 (&b0)[4], const bf16x8 (&b1)[4]) {
  __builtin_amdgcn_s_setprio(1);
#pragma unroll
  for (int mi = 0; mi < 4; ++mi)
#pragma unroll
    for (int nn = 0; nn < 4; ++nn)
#pragma unroll
      for (int ks = 0; ks < 2; ++ks) {
        const bf16x8& bb = (nn < 2) ? b0[(nn & 1) * 2 + ks] : b1[(nn & 1) * 2 + ks];
        acc[MS * 4 + mi][nn] = __builtin_amdgcn_mfma_f32_16x16x32_bf16(
            a[mi * 2 + ks], bb, acc[MS * 4 + mi][nn], 0, 0, 0);
      }
  __builtin_amdgcn_s_setprio(0);
}

#define PH_BAR_PRE()                                                           \
  __builtin_amdgcn_sched_barrier(0);                                           \
  __builtin_amdgcn_s_barrier();                                                \
  asm volatile("s_waitcnt lgkmcnt(0)" ::: "memory");                           \
  __builtin_amdgcn_sched_barrier(0)
#define PH_BAR_POST()                                                          \
  __builtin_amdgcn_sched_barrier(0);                                           \
  __builtin_amdgcn_s_barrier()

// =======================================================================
// GEMM1: 256x256, 2 merged phases per K-tile (4 barriers/K-tile instead of
// 8), counted vmcnt(8), wave-aligned staging, both-sides XOR swizzle.
// h = relu(A[M x 2048] * W1t^T + b1) -> bf16 hbuf
// =======================================================================
__global__ __launch_bounds__(512, 2) void gemm2p(
    const unsigned short* __restrict__ Ash,   // xb (shared experts)
    const unsigned short* __restrict__ Art,   // xg (routed, gathered)
    const unsigned short* __restrict__ wt,    // packed W1^T [10][FF][HD]
    const float* __restrict__ bE, const float* __restrict__ bS,
    unsigned short* __restrict__ hout,
    const int* __restrict__ counts, const int* __restrict__ offs) {
  constexpr int K = HD;                 // 2048
  constexpr int NBX = FF / 256;         // 32
  constexpr int NWG = NBX * 16;         // 512
  extern __shared__ unsigned short smem[];

  const int e = blockIdx.z;
  int M;
  const unsigned short* A;
  const float* bias;
  int hbase;
  if (e < NE) {
    M = counts[e];
    A = Art + (size_t)offs[e] * K;
    bias = bE + (size_t)e * FF;
    hbase = offs[e];
  } else {
    M = TOKENS;
    A = Ash;
    bias = bS + (size_t)(e - NE) * FF;
    hbase = 2 * TOKENS + (e - NE) * TOKENS;
  }
  const unsigned short* Bt = wt + (size_t)e * HD * FF;

  int flat = blockIdx.x + NBX * blockIdx.y;
  flat = (flat & 7) * (NWG >> 3) + (flat >> 3);
  const int m0 = (flat & 15) * 256;
  const int n0 = (flat >> 4) * 256;
  if (m0 >= M) return;

  const int tid = threadIdx.x;
  const int wid = tid >> 6, ln = tid & 63;
  const int wr = wid >> 2, wc = wid & 3;
  const int fr = ln & 15, fq = ln >> 4;
  const int swz = fr & 7;

  const int lr8 = ln >> 3;
  const int lc8 = ln & 7;
  const int scol = (lc8 ^ lr8) << 3;
  const int wrA = wr * 128 + wc * 16;
  const int wcB = wc * 64 + wr * 16;

#define SA(s, kt, b)                                                           \
  { const int r0_ = wrA + (s) * 64 + lr8;                                      \
    const unsigned short* s_ = A + (size_t)(m0 + r0_) * K + (kt) * 64 + scol;  \
    unsigned short* d_ = smem + (b) * 32768 + r0_ * 64 + lc8 * 8;              \
    GLDS16(s_, d_); GLDS16(s_ + (size_t)8 * K, d_ + 8 * 64); }
#define SB(s, kt, b)                                                           \
  { const int r0_ = wcB + (s) * 32 + lr8;                                      \
    const unsigned short* s_ = Bt + (size_t)(n0 + r0_) * K + (kt) * 64 + scol; \
    unsigned short* d_ = smem + (b) * 32768 + 16384 + r0_ * 64 + lc8 * 8;      \
    GLDS16(s_, d_); GLDS16(s_ + (size_t)8 * K, d_ + 8 * 64); }

  f32x4 acc[8][4];
#pragma unroll
  for (int i = 0; i < 8; ++i)
#pragma unroll
    for (int j = 0; j < 4; ++j) acc[i][j] = (f32x4){0.f, 0.f, 0.f, 0.f};

  SA(0, 0, 0); SA(1, 0, 0); SB(0, 0, 0); SB(1, 0, 0);
  SA(0, 1, 1); SA(1, 1, 1); SB(0, 1, 1); SB(1, 1, 1);
  asm volatile("s_waitcnt vmcnt(8)" ::: "memory");
  __builtin_amdgcn_s_barrier();

  bf16x8 a0[8], a1[8], b0[4], b1[4];
  const int nkt = K / 64;   // 32
  for (int t = 0; t < nkt; ++t) {
    const int cur = t & 1;
    const int tp2 = (t + 2 < nkt) ? t + 2 : t;
    const unsigned short* As_c = smem + cur * 32768;
    const unsigned short* Bs_c = As_c + 16384;
    // ---- phA: 16 ds_reads -> 32 MFMA (m-half 0 x full n) ----
    rd_a<0>(a0, As_c, wr, fr, fq, swz);
    rd_b<0>(b0, Bs_c, wc, fr, fq, swz);
    rd_b<1>(b1, Bs_c, wc, fr, fq, swz);
    asm volatile("s_waitcnt lgkmcnt(8)" ::: "memory");
    PH_BAR_PRE();
    mm32<0>(acc, a0, b0, b1);
    PH_BAR_POST();
    // ---- phB: 8 ds_reads + B-stage -> 32 MFMA -> A-stage ----
    // (cur.B fully read in phA -> stage B of t+2 now; cur.A read finishes
    //  in phB -> stage A of t+2 after the pre-MFMA barrier, when all waves'
    //  A-reads are already in the LDS pipe.)
    rd_a<1>(a1, As_c, wr, fr, fq, swz);
    SB(0, tp2, cur); SB(1, tp2, cur);
    PH_BAR_PRE();
    mm32<1>(acc, a1, b1, b0);
    __builtin_amdgcn_sched_barrier(0);
    SA(0, tp2, cur); SA(1, tp2, cur);
    __builtin_amdgcn_sched_barrier(0);
    asm volatile("s_waitcnt vmcnt(8)" ::: "memory");
    __builtin_amdgcn_s_barrier();
  }
#undef SA
#undef SB

  // epilogue (mm32<1> computed acc rows with n order b1,b0 -> nn mapping:
  // for MS=1 the nn<2 slots used b1 (n-cols 32..63) and nn>=2 used b0 (0..31))
#pragma unroll
  for (int nn = 0; nn < 4; ++nn) {
#pragma unroll
    for (int mm = 0; mm < 8; ++mm) {
      // column sub-block for this acc slot:
      const int nsub_lo = (mm < 4) ? (nn >> 1) : 1 - (nn >> 1);  // 0:cols0-31,1:32-63
      const int col = n0 + wc * 64 + nsub_lo * 32 + (nn & 1) * 16 + fr;
      const float bb = bias[col];
#pragma unroll
      for (int j = 0; j < 4; ++j) {
        const int r = m0 + wr * 128 + (mm >> 2) * 64 + (mm & 3) * 16 + fq * 4 + j;
        if (r < M) {
          float v = acc[mm][nn][j] + bb;
          v = v > 0.f ? v : 0.f;
          hout[(size_t)(hbase + r) * FF + col] = f2bf(v);
        }
      }
    }
  }
}

// =======================================================================
// GEMM2: R7 4-phase kernel (control), with the two shared experts merged
// into one z-slice via K-concatenation (K=16384, dual A/B base).
// out[token] += gate * (h * W2t^T + b2)   (atomic f32)
// =======================================================================
__global__ __launch_bounds__(512, 2) void gemm8p(
    const unsigned short* __restrict__ hbuf,
    const unsigned short* __restrict__ wt,    // packed W2^T [10][HD][FF]
    const float* __restrict__ bE, const float* __restrict__ bS,
    float* __restrict__ out,
    const int* __restrict__ counts, const int* __restrict__ offs,
    const int* __restrict__ row_token, const float* __restrict__ row_gate) {
  constexpr int K = FF;                 // row stride of A and B^T
  constexpr int NBX = HD / 256;         // 8
  constexpr int NWG = NBX * 16;         // 128
  extern __shared__ unsigned short smem[];

  const int e = blockIdx.z;             // 0..7 routed, 8 = merged shared
  const bool merged = (e == NE);
  int M;
  const unsigned short *A, *A2;
  const unsigned short *B, *B2;
  const float *bias, *bias2;
  const int* tok = nullptr;
  const float* gt = nullptr;

  if (!merged) {
    M = counts[e];
    const int off = offs[e];
    A = hbuf + (size_t)off * K;  A2 = A;
    tok = row_token + off; gt = row_gate + off;
    B = wt + (size_t)e * HD * FF;  B2 = B;
    bias = bE + (size_t)e * HD;  bias2 = bias;
  } else {
    M = TOKENS;
    A  = hbuf + (size_t)(2 * TOKENS) * K;          // h of shared expert 0
    A2 = hbuf + (size_t)(3 * TOKENS) * K;          // h of shared expert 1
    B  = wt + (size_t)NE * HD * FF;
    B2 = wt + (size_t)(NE + 1) * HD * FF;
    bias = bS;  bias2 = bS + HD;
  }

  int flat = blockIdx.x + NBX * blockIdx.y;
  flat = (flat & 7) * (NWG >> 3) + (flat >> 3);
  const int m0 = (flat & 15) * 256;
  const int n0 = (flat >> 4) * 256;
  if (m0 >= M) return;

  const int tid = threadIdx.x;
  const int wid = tid >> 6, ln = tid & 63;
  const int wr = wid >> 2, wc = wid & 3;
  const int fr = ln & 15, fq = ln >> 4;
  const int swz = fr & 7;

  const int lr8 = ln >> 3;
  const int lc8 = ln & 7;
  const int scol = (lc8 ^ lr8) << 3;
  const int wrA = wr * 128 + wc * 16;
  const int wcB = wc * 64 + wr * 16;

#define SA(s, kt, b)                                                           \
  { int kl_ = (kt); const unsigned short* ab_ = A;                             \
    if (merged && kl_ >= 128) { ab_ = A2; kl_ -= 128; }                        \
    const int r0_ = wrA + (s) * 64 + lr8;                                      \
    const unsigned short* s_ = ab_ + (size_t)(m0 + r0_) * K + kl_ * 64 + scol; \
    unsigned short* d_ = smem + (b) * 32768 + r0_ * 64 + lc8 * 8;              \
    GLDS16(s_, d_); GLDS16(s_ + (size_t)8 * K, d_ + 8 * 64); }
#define SB(s, kt, b)                                                           \
  { int kl_ = (kt); const unsigned short* bb_ = B;                             \
    if (merged && kl_ >= 128) { bb_ = B2; kl_ -= 128; }                        \
    const int r0_ = wcB + (s) * 32 + lr8;                                      \
    const unsigned short* s_ = bb_ + (size_t)(n0 + r0_) * K + kl_ * 64 + scol; \
    unsigned short* d_ = smem + (b) * 32768 + 16384 + r0_ * 64 + lc8 * 8;      \
    GLDS16(s_, d_); GLDS16(s_ + (size_t)8 * K, d_ + 8 * 64); }

  f32x4 acc[8][4];
#pragma unroll
  for (int i = 0; i < 8; ++i)
#pragma unroll
    for (int j = 0; j < 4; ++j) acc[i][j] = (f32x4){0.f, 0.f, 0.f, 0.f};

  SA(0, 0, 0); SA(1, 0, 0); SB(0, 0, 0); SB(1, 0, 0);
  SA(0, 1, 1); SA(1, 1, 1); SB(0, 1, 1); SB(1, 1, 1);
  asm volatile("s_waitcnt vmcnt(8)" ::: "memory");
  __builtin_amdgcn_s_barrier();

  bf16x8 a0[8], a1[8], b0[4], b1[4];
  const int nkt = merged ? 256 : 128;
  for (int t = 0; t < nkt; ++t) {
    const int cur = t & 1;
    const int tp2 = (t + 2 < nkt) ? t + 2 : t;
    const unsigned short* As_c = smem + cur * 32768;
    const unsigned short* Bs_c = As_c + 16384;
    rd_a<0>(a0, As_c, wr, fr, fq, swz);
    rd_b<0>(b0, Bs_c, wc, fr, fq, swz);
    asm volatile("s_waitcnt lgkmcnt(8)" ::: "memory");
    PH_BAR_PRE();
    mm16<0, 0>(acc, a0, b0);
    PH_BAR_POST();
    rd_b<1>(b1, Bs_c, wc, fr, fq, swz);
    SA(0, tp2, cur); SB(0, tp2, cur);
    PH_BAR_PRE();
    mm16<0, 1>(acc, a0, b1);
    PH_BAR_POST();
    rd_a<1>(a1, As_c, wr, fr, fq, swz);
    SB(1, tp2, cur);
    PH_BAR_PRE();
    mm16<1, 1>(acc, a1, b1);
    PH_BAR_POST();
    SA(1, tp2, cur);
    __builtin_amdgcn_sched_barrier(0);
    __builtin_amdgcn_s_barrier();
    __builtin_amdgcn_sched_barrier(0);
    mm16<1, 0>(acc, a1, b0);
    __builtin_amdgcn_sched_barrier(0);
    asm volatile("s_waitcnt vmcnt(8)" ::: "memory");
    __builtin_amdgcn_s_barrier();
  }
#undef SA
#undef SB

#pragma unroll
  for (int mm = 0; mm < 8; ++mm) {
#pragma unroll
    for (int j = 0; j < 4; ++j) {
      const int r = m0 + wr * 128 + (mm >> 2) * 64 + (mm & 3) * 16 + fq * 4 + j;
      if (r < M) {
        const int t = tok ? tok[r] : r;
        const float g = gt ? gt[r] : 1.f;
        float* orow = out + (size_t)t * HD + n0;
#pragma unroll
        for (int nn = 0; nn < 4; ++nn) {
          const int col = wc * 64 + (nn >> 1) * 32 + (nn & 1) * 16 + fr;
          float bb = bias[n0 + col];
          if (merged) bb += bias2[n0 + col];
          atomicAdd(orow + col, g * (acc[mm][nn][j] + bb));
        }
      }
    }
  }
}

extern "C" void kernel_launch(void* const* d_in, const int* in_sizes, int n_in,
                              void* d_out, int out_size, void* d_ws, size_t ws_size,
                              hipStream_t stream) {
  const float* x     = (const float*)d_in[0];
  const float* ws_w1 = (const float*)d_in[1];
  const float* ws_b1 = (const float*)d_in[2];
  const float* ws_w2 = (const float*)d_in[3];
  const float* ws_b2 = (const float*)d_in[4];
  const float* we_w1 = (const float*)d_in[5];
  const float* we_b1 = (const float*)d_in[6];
  const float* we_w2 = (const float*)d_in[7];
  const float* we_b2 = (const float*)d_in[8];
  const float* wg    = (const float*)d_in[9];

  float* out = (float*)d_out;
  float* logits = out + (size_t)TOKENS * HD;

  char* ws = (char*)d_ws;
  unsigned short* wt   = (unsigned short*)ws;                   // 335,544,320 B
  unsigned short* xb   = (unsigned short*)(ws + 335544320);     //  16,777,216 B
  unsigned short* xg   = (unsigned short*)(ws + 352321536);     //  34,078,720 B
  unsigned short* hbuf = (unsigned short*)(ws + 386400256);     // 268,435,456 B
  char* ctrl = ws + 654835712;
  int*   row_token = (int*)(ctrl);
  float* row_gate  = (float*)(ctrl + 32768);
  int*   topi      = (int*)(ctrl + 65536);
  float* topv      = (float*)(ctrl + 98304);
  int*   counts    = (int*)(ctrl + 131072);
  int*   offs      = (int*)(ctrl + 131104);
  int*   cursors   = (int*)(ctrl + 131136);

  hipFuncSetAttribute(reinterpret_cast<const void*>(gemm2p),
                      hipFuncAttributeMaxDynamicSharedMemorySize, 131072);
  hipFuncSetAttribute(reinterpret_cast<const void*>(gemm8p),
                      hipFuncAttributeMaxDynamicSharedMemorySize, 131072);

  hipMemsetAsync(out, 0, (size_t)TOKENS * HD * sizeof(float), stream);
  hipMemsetAsync(counts, 0, NE * sizeof(int), stream);

  cast_x_kernel<<<8192, 256, 0, stream>>>(x, xb);
  router_kernel<<<1024, 256, 0, stream>>>(x, wg, logits, topi, topv, counts);
  offs_kernel<<<1, 64, 0, stream>>>(counts, offs, cursors);
  gather_kernel<<<1024, 256, 0, stream>>>(xb, topi, topv, cursors, xg, row_token, row_gate);

  // pack W1 [10][2048][8192] f32 -> [10][8192][2048] bf16
  pack_wt<HD, FF><<<dim3(FF / 64, HD / 64, 10), 256, 0, stream>>>(we_w1, ws_w1, wt);
  // GEMM1 (2-phase experiment)
  gemm2p<<<dim3(32, 16, 10), 512, 131072, stream>>>(
      xb, xg, wt, we_b1, ws_b1, hbuf, counts, offs);
  // pack W2 [10][8192][2048] f32 -> [10][2048][8192] bf16 (reuses wt)
  pack_wt<FF, HD><<<dim3(HD / 64, FF / 64, 10), 256, 0, stream>>>(we_w2, ws_w2, wt);
  // GEMM2 (4-phase control, shared experts K-merged -> z=9)
  gemm8p<<<dim3(8, 16, 9), 512, 131072, stream>>>(
      hbuf, wt, we_b2, ws_b2, out, counts, offs, row_token, row_gate);

  (void)in_sizes; (void)n_in; (void)out_size; (void)ws_size;
}

// Round 9
// 2032.657 us; speedup vs baseline: 1.0216x; 1.0215x over previous
//
#include <hip/hip_runtime.h>

#define TOKENS 4096
#define HD 2048
#define FF 8192
#define NE 8
#define NS 2

typedef __attribute__((ext_vector_type(8))) short bf16x8;
typedef __attribute__((ext_vector_type(4))) float f32x4;

__device__ __forceinline__ unsigned rnd_bf(unsigned u) {
  return u + 0x7fffu + ((u >> 16) & 1u);
}
__device__ __forceinline__ unsigned short f2bf(float f) {
  unsigned u = __builtin_bit_cast(unsigned, f);
  return (unsigned short)(rnd_bf(u) >> 16);
}

#define GLDS16(gp, lp)                                                         \
  __builtin_amdgcn_global_load_lds(                                            \
      (const __attribute__((address_space(1))) unsigned*)(const void*)(gp),    \
      (__attribute__((address_space(3))) unsigned*)(lp), 16, 0, 0)

// ---------------- cast x f32 -> bf16 ----------------
__global__ void cast_x_kernel(const float* __restrict__ x, unsigned short* __restrict__ xb) {
  const size_t i = ((size_t)blockIdx.x * 256 + threadIdx.x) * 4;
  float4 v = *(const float4*)(x + i);
  ushort4 o;
  o.x = f2bf(v.x); o.y = f2bf(v.y); o.z = f2bf(v.z); o.w = f2bf(v.w);
  *(ushort4*)(xb + i) = o;
}

// ---------------- router ----------------
__global__ void router_kernel(const float* __restrict__ x, const float* __restrict__ wg,
                              float* __restrict__ logits_out, int* __restrict__ topi,
                              float* __restrict__ topv, int* __restrict__ counts) {
  const int wave = threadIdx.x >> 6, lane = threadIdx.x & 63;
  const int t = blockIdx.x * 4 + wave;
  const float* xr = x + (size_t)t * HD;
  float acc[8];
#pragma unroll
  for (int e = 0; e < 8; ++e) acc[e] = 0.f;
  for (int d = lane; d < HD; d += 64) {
    const float xv = xr[d];
    const float4 w0 = *(const float4*)(wg + (size_t)d * 8);
    const float4 w1 = *(const float4*)(wg + (size_t)d * 8 + 4);
    acc[0] += xv * w0.x; acc[1] += xv * w0.y; acc[2] += xv * w0.z; acc[3] += xv * w0.w;
    acc[4] += xv * w1.x; acc[5] += xv * w1.y; acc[6] += xv * w1.z; acc[7] += xv * w1.w;
  }
#pragma unroll
  for (int e = 0; e < 8; ++e) {
#pragma unroll
    for (int off = 32; off > 0; off >>= 1) acc[e] += __shfl_xor(acc[e], off);
  }
  if (lane == 0) {
    *(float4*)(logits_out + (size_t)t * 8)     = make_float4(acc[0], acc[1], acc[2], acc[3]);
    *(float4*)(logits_out + (size_t)t * 8 + 4) = make_float4(acc[4], acc[5], acc[6], acc[7]);
    float mx = acc[0];
#pragma unroll
    for (int e = 1; e < 8; ++e) mx = fmaxf(mx, acc[e]);
    float p[8], s = 0.f;
#pragma unroll
    for (int e = 0; e < 8; ++e) { p[e] = expf(acc[e] - mx); s += p[e]; }
    const float inv = 1.f / s;
    int i1 = 0;
#pragma unroll
    for (int e = 1; e < 8; ++e) if (acc[e] > acc[i1]) i1 = e;
    int i2 = (i1 == 0) ? 1 : 0;
#pragma unroll
    for (int e = 0; e < 8; ++e) if (e != i1 && acc[e] > acc[i2]) i2 = e;
    topi[2 * t]     = i1; topv[2 * t]     = p[i1] * inv;
    topi[2 * t + 1] = i2; topv[2 * t + 1] = p[i2] * inv;
    atomicAdd(&counts[i1], 1);
    atomicAdd(&counts[i2], 1);
  }
}

__global__ void offs_kernel(const int* __restrict__ counts, int* __restrict__ offs,
                            int* __restrict__ cursors) {
  if (threadIdx.x == 0) {
    int r = 0;
    for (int e = 0; e < NE; ++e) { offs[e] = r; cursors[e] = r; r += counts[e]; }
  }
}

__global__ void gather_kernel(const unsigned short* __restrict__ xb,
                              const int* __restrict__ topi, const float* __restrict__ topv,
                              int* __restrict__ cursors, unsigned short* __restrict__ xg,
                              int* __restrict__ row_token, float* __restrict__ row_gate,
                              int* __restrict__ row_of) {
  const int wave = threadIdx.x >> 6, lane = threadIdx.x & 63;
  const int t = blockIdx.x * 4 + wave;
  const uint4* src = (const uint4*)(xb + (size_t)t * HD);
#pragma unroll
  for (int j = 0; j < 2; ++j) {
    const int e = topi[2 * t + j];
    int pos = 0;
    if (lane == 0) {
      pos = atomicAdd(&cursors[e], 1);
      row_token[pos] = t;
      row_gate[pos] = topv[2 * t + j];
      row_of[2 * t + j] = pos;
    }
    pos = __shfl(pos, 0);
    uint4* dst = (uint4*)(xg + (size_t)pos * HD);
#pragma unroll
    for (int c = lane; c < 256; c += 64) dst[c] = src[c];
  }
}

// ---------------- standalone pack: f32 [K][N] -> bf16 B^T [N][K] ----------------
template <int K, int N>
__global__ __launch_bounds__(256) void pack_wt(const float* __restrict__ we,
                                               const float* __restrict__ ws,
                                               unsigned short* __restrict__ dstw) {
  const int e = blockIdx.z;
  const float* src = (e < NE) ? (we + (size_t)e * K * N) : (ws + (size_t)(e - NE) * K * N);
  unsigned short* dst = dstw + (size_t)e * K * N;
  const int nt = blockIdx.x * 64;
  const int kt = blockIdx.y * 64;
  __shared__ unsigned short t[64][73];
  const int tid = threadIdx.x;
  const int rr = tid >> 4, cc = (tid & 15) * 4;
#pragma unroll
  for (int i = 0; i < 4; ++i) {
    const int k = rr + i * 16;
    float4 v = *(const float4*)(src + (size_t)(kt + k) * N + nt + cc);
    t[k][cc + 0] = f2bf(v.x);
    t[k][cc + 1] = f2bf(v.y);
    t[k][cc + 2] = f2bf(v.z);
    t[k][cc + 3] = f2bf(v.w);
  }
  __syncthreads();
  const int nr = tid >> 2, kc = (tid & 3) * 16;
  unsigned u[8];
#pragma unroll
  for (int j = 0; j < 8; ++j)
    u[j] = (unsigned)t[kc + 2 * j][nr] | ((unsigned)t[kc + 2 * j + 1][nr] << 16);
  unsigned short* dp = dst + (size_t)(nt + nr) * K + kt + kc;
  uint4 v0; v0.x = u[0]; v0.y = u[1]; v0.z = u[2]; v0.w = u[3];
  uint4 v1; v1.x = u[4]; v1.y = u[5]; v1.z = u[6]; v1.w = u[7];
  *(uint4*)dp = v0;
  *(uint4*)(dp + 8) = v1;
}

// ---------------- frag read / mfma helpers ----------
template <int MS>
__device__ __forceinline__ void rd_a(bf16x8 (&d)[8], const unsigned short* base,
                                     int wr, int fr, int fq, int swz) {
#pragma unroll
  for (int mi = 0; mi < 4; ++mi)
#pragma unroll
    for (int ks = 0; ks < 2; ++ks)
      d[mi * 2 + ks] = *(const bf16x8*)(base + (wr * 128 + MS * 64 + mi * 16 + fr) * 64 +
                                        (((ks * 4 + fq) ^ swz) << 3));
}
template <int NSUB>
__device__ __forceinline__ void rd_b(bf16x8 (&d)[4], const unsigned short* base,
                                     int wc, int fr, int fq, int swz) {
#pragma unroll
  for (int ni = 0; ni < 2; ++ni)
#pragma unroll
    for (int ks = 0; ks < 2; ++ks)
      d[ni * 2 + ks] = *(const bf16x8*)(base + (wc * 64 + NSUB * 32 + ni * 16 + fr) * 64 +
                                        (((ks * 4 + fq) ^ swz) << 3));
}
template <int MS, int NSUB>
__device__ __forceinline__ void mm16(f32x4 (&acc)[8][4], const bf16x8 (&a)[8],
                                     const bf16x8 (&b)[4]) {
  __builtin_amdgcn_s_setprio(1);
#pragma unroll
  for (int mi = 0; mi < 4; ++mi)
#pragma unroll
    for (int ni = 0; ni < 2; ++ni)
#pragma unroll
      for (int ks = 0; ks < 2; ++ks)
        acc[MS * 4 + mi][NSUB * 2 + ni] = __builtin_amdgcn_mfma_f32_16x16x32_bf16(
            a[mi * 2 + ks], b[ni * 2 + ks], acc[MS * 4 + mi][NSUB * 2 + ni], 0, 0, 0);
  __builtin_amdgcn_s_setprio(0);
}
template <int MS>
__device__ __forceinline__ void mm32(f32x4 (&acc)[8][4], const bf16x8 (&a)[8],
                                     const bf16x8 (&b0)[4], const bf16x8 (&b1)[4]) {
  __builtin_amdgcn_s_setprio(1);
#pragma unroll
  for (int mi = 0; mi < 4; ++mi)
#pragma unroll
    for (int nn = 0; nn < 4; ++nn)
#pragma unroll
      for (int ks = 0; ks < 2; ++ks) {
        const bf16x8& bb = (nn < 2) ? b0[(nn & 1) * 2 + ks] : b1[(nn & 1) * 2 + ks];
        acc[MS * 4 + mi][nn] = __builtin_amdgcn_mfma_f32_16x16x32_bf16(
            a[mi * 2 + ks], bb, acc[MS * 4 + mi][nn], 0, 0, 0);
      }
  __builtin_amdgcn_s_setprio(0);
}

#define PH_BAR_PRE()                                                           \
  __builtin_amdgcn_sched_barrier(0);                                           \
  __builtin_amdgcn_s_barrier();                                                \
  asm volatile("s_waitcnt lgkmcnt(0)" ::: "memory");                           \
  __builtin_amdgcn_sched_barrier(0)
#define PH_BAR_POST()                                                          \
  __builtin_amdgcn_sched_barrier(0);                                           \
  __builtin_amdgcn_s_barrier()

// =======================================================================
// GEMM1 (2-phase): h = relu(A[M x 2048] * W1t^T + b1) -> bf16 hbuf.
// Invalid blocks (m0 >= M) optionally pack W2 f32->bf16^T into wt2
// (do_pack=1), hiding the W2 pack pass under GEMM1's execution window.
// =======================================================================
__global__ __launch_bounds__(512, 2) void g1k(
    const unsigned short* __restrict__ Ash, const unsigned short* __restrict__ Art,
    const unsigned short* __restrict__ wt1,
    const float* __restrict__ bE, const float* __restrict__ bS,
    unsigned short* __restrict__ hout,
    const int* __restrict__ counts, const int* __restrict__ offs,
    int do_pack, const float* __restrict__ we_w2, const float* __restrict__ ws_w2,
    unsigned short* __restrict__ wt2) {
  constexpr int K = HD;
  constexpr int NBX = FF / 256;         // 32
  constexpr int NWG = NBX * 16;         // 512
  extern __shared__ unsigned short smem[];

  const int e = blockIdx.z;
  int M;
  const unsigned short* A;
  const float* bias;
  int hbase;
  if (e < NE) {
    M = counts[e];
    A = Art + (size_t)offs[e] * K;
    bias = bE + (size_t)e * FF;
    hbase = offs[e];
  } else {
    M = TOKENS;
    A = Ash;
    bias = bS + (size_t)(e - NE) * FF;
    hbase = 2 * TOKENS + (e - NE) * TOKENS;
  }
  const unsigned short* Bt = wt1 + (size_t)e * HD * FF;

  int flat = blockIdx.x + NBX * blockIdx.y;
  flat = (flat & 7) * (NWG >> 3) + (flat >> 3);
  const int m0 = (flat & 15) * 256;
  const int n0 = (flat >> 4) * 256;
  const int tid = threadIdx.x;

  if (m0 >= M) {
    if (!do_pack) return;
    // --------- deterministic rank among invalid blocks ---------
    int total = 0, prefix = 0;
    for (int e2 = 0; e2 < NE; ++e2) {
      int mb = (counts[e2] + 255) >> 8; if (mb > 16) mb = 16;
      const int inv = 32 * (16 - mb);
      if (e2 < e) prefix += inv;
      total += inv;
    }
    int mb_e = (counts[e] + 255) >> 8; if (mb_e > 16) mb_e = 16;
    const int m_idx = flat & 15, n_idx = flat >> 4;
    const int rank = prefix + n_idx * (16 - mb_e) + (m_idx - mb_e);
    // --------- pack W2 tiles: src [FF][HD] f32 -> dst [HD][FF] bf16 ---------
    unsigned short* ps = smem;  // [64][72]
    const int NT = 10 * 128 * 32;
    for (int i = rank; i < NT; i += total) {
      const int e2 = i >> 12;
      const int rem = i & 4095;
      const int ktt = rem >> 5;
      const int ntt = rem & 31;
      const float* src = (e2 < NE) ? (we_w2 + (size_t)e2 * FF * HD)
                                   : (ws_w2 + (size_t)(e2 - NE) * FF * HD);
      unsigned short* dst = wt2 + (size_t)e2 * HD * FF;
      __syncthreads();
      {
        const int kk = tid >> 3, cc = (tid & 7) * 8;
        const float* sp = src + (size_t)(ktt * 64 + kk) * HD + ntt * 64 + cc;
        const float4 v0 = *(const float4*)sp;
        const float4 v1 = *(const float4*)(sp + 4);
        unsigned short* tp = ps + kk * 72 + cc;
        tp[0] = f2bf(v0.x); tp[1] = f2bf(v0.y); tp[2] = f2bf(v0.z); tp[3] = f2bf(v0.w);
        tp[4] = f2bf(v1.x); tp[5] = f2bf(v1.y); tp[6] = f2bf(v1.z); tp[7] = f2bf(v1.w);
      }
      __syncthreads();
      {
        const int nn = tid >> 3, kc = (tid & 7) * 8;
        unsigned u[4];
#pragma unroll
        for (int j = 0; j < 4; ++j)
          u[j] = (unsigned)ps[(kc + 2 * j) * 72 + nn] |
                 ((unsigned)ps[(kc + 2 * j + 1) * 72 + nn] << 16);
        uint4 v; v.x = u[0]; v.y = u[1]; v.z = u[2]; v.w = u[3];
        *(uint4*)(dst + (size_t)(ntt * 64 + nn) * FF + ktt * 64 + kc) = v;
      }
    }
    return;
  }

  const int wid = tid >> 6, ln = tid & 63;
  const int wr = wid >> 2, wc = wid & 3;
  const int fr = ln & 15, fq = ln >> 4;
  const int swz = fr & 7;
  const int lr8 = ln >> 3;
  const int lc8 = ln & 7;
  const int scol = (lc8 ^ lr8) << 3;
  const int wrA = wr * 128 + wc * 16;
  const int wcB = wc * 64 + wr * 16;

#define SA1(s, kt, b)                                                          \
  { const int r0_ = wrA + (s) * 64 + lr8;                                      \
    const unsigned short* s_ = A + (size_t)(m0 + r0_) * K + (kt) * 64 + scol;  \
    unsigned short* d_ = smem + (b) * 32768 + r0_ * 64 + lc8 * 8;              \
    GLDS16(s_, d_); GLDS16(s_ + (size_t)8 * K, d_ + 8 * 64); }
#define SB1(s, kt, b)                                                          \
  { const int r0_ = wcB + (s) * 32 + lr8;                                      \
    const unsigned short* s_ = Bt + (size_t)(n0 + r0_) * K + (kt) * 64 + scol; \
    unsigned short* d_ = smem + (b) * 32768 + 16384 + r0_ * 64 + lc8 * 8;      \
    GLDS16(s_, d_); GLDS16(s_ + (size_t)8 * K, d_ + 8 * 64); }

  f32x4 acc[8][4];
#pragma unroll
  for (int i = 0; i < 8; ++i)
#pragma unroll
    for (int j = 0; j < 4; ++j) acc[i][j] = (f32x4){0.f, 0.f, 0.f, 0.f};

  SA1(0, 0, 0); SA1(1, 0, 0); SB1(0, 0, 0); SB1(1, 0, 0);
  SA1(0, 1, 1); SA1(1, 1, 1); SB1(0, 1, 1); SB1(1, 1, 1);
  asm volatile("s_waitcnt vmcnt(8)" ::: "memory");
  __builtin_amdgcn_s_barrier();

  bf16x8 a0[8], a1[8], b0[4], b1[4];
  const int nkt = K / 64;
  for (int t = 0; t < nkt; ++t) {
    const int cur = t & 1;
    const int tp2 = (t + 2 < nkt) ? t + 2 : t;
    const unsigned short* As_c = smem + cur * 32768;
    const unsigned short* Bs_c = As_c + 16384;
    rd_a<0>(a0, As_c, wr, fr, fq, swz);
    rd_b<0>(b0, Bs_c, wc, fr, fq, swz);
    rd_b<1>(b1, Bs_c, wc, fr, fq, swz);
    asm volatile("s_waitcnt lgkmcnt(8)" ::: "memory");
    PH_BAR_PRE();
    mm32<0>(acc, a0, b0, b1);
    PH_BAR_POST();
    rd_a<1>(a1, As_c, wr, fr, fq, swz);
    SB1(0, tp2, cur); SB1(1, tp2, cur);
    PH_BAR_PRE();
    mm32<1>(acc, a1, b1, b0);
    __builtin_amdgcn_sched_barrier(0);
    SA1(0, tp2, cur); SA1(1, tp2, cur);
    __builtin_amdgcn_sched_barrier(0);
    asm volatile("s_waitcnt vmcnt(8)" ::: "memory");
    __builtin_amdgcn_s_barrier();
  }
#undef SA1
#undef SB1

#pragma unroll
  for (int nn = 0; nn < 4; ++nn) {
#pragma unroll
    for (int mm = 0; mm < 8; ++mm) {
      const int nsub_lo = (mm < 4) ? (nn >> 1) : 1 - (nn >> 1);
      const int col = n0 + wc * 64 + nsub_lo * 32 + (nn & 1) * 16 + fr;
      const float bb = bias[col];
#pragma unroll
      for (int j = 0; j < 4; ++j) {
        const int r = m0 + wr * 128 + (mm >> 2) * 64 + (mm & 3) * 16 + fq * 4 + j;
        if (r < M) {
          float v = acc[mm][nn][j] + bb;
          v = v > 0.f ? v : 0.f;
          hout[(size_t)(hbase + r) * FF + col] = f2bf(v);
        }
      }
    }
  }
}

// =======================================================================
// GEMM2 (2-phase, new path): ybuf[row] = h * W2t^T + b2  (f32, NO gate,
// NO atomics). z=10; reduce pass combines with gates afterwards.
// =======================================================================
__global__ __launch_bounds__(512, 2) void g2k(
    const unsigned short* __restrict__ hbuf, const unsigned short* __restrict__ wt2,
    const float* __restrict__ bE, const float* __restrict__ bS,
    float* __restrict__ ybuf,
    const int* __restrict__ counts, const int* __restrict__ offs) {
  constexpr int K = FF;
  constexpr int NBX = HD / 256;         // 8
  constexpr int NWG = NBX * 16;         // 128
  extern __shared__ unsigned short smem[];

  const int e = blockIdx.z;
  int M;
  const unsigned short* A;
  const float* bias;
  int hbase;
  if (e < NE) {
    M = counts[e];
    A = hbuf + (size_t)offs[e] * K;
    bias = bE + (size_t)e * HD;
    hbase = offs[e];
  } else {
    M = TOKENS;
    hbase = 2 * TOKENS + (e - NE) * TOKENS;
    A = hbuf + (size_t)hbase * K;
    bias = bS + (size_t)(e - NE) * HD;
  }
  const unsigned short* Bt = wt2 + (size_t)e * HD * FF;

  int flat = blockIdx.x + NBX * blockIdx.y;
  flat = (flat & 7) * (NWG >> 3) + (flat >> 3);
  const int m0 = (flat & 15) * 256;
  const int n0 = (flat >> 4) * 256;
  if (m0 >= M) return;

  const int tid = threadIdx.x;
  const int wid = tid >> 6, ln = tid & 63;
  const int wr = wid >> 2, wc = wid & 3;
  const int fr = ln & 15, fq = ln >> 4;
  const int swz = fr & 7;
  const int lr8 = ln >> 3;
  const int lc8 = ln & 7;
  const int scol = (lc8 ^ lr8) << 3;
  const int wrA = wr * 128 + wc * 16;
  const int wcB = wc * 64 + wr * 16;

#define SA2(s, kt, b)                                                          \
  { const int r0_ = wrA + (s) * 64 + lr8;                                      \
    const unsigned short* s_ = A + (size_t)(m0 + r0_) * K + (kt) * 64 + scol;  \
    unsigned short* d_ = smem + (b) * 32768 + r0_ * 64 + lc8 * 8;              \
    GLDS16(s_, d_); GLDS16(s_ + (size_t)8 * K, d_ + 8 * 64); }
#define SB2(s, kt, b)                                                          \
  { const int r0_ = wcB + (s) * 32 + lr8;                                      \
    const unsigned short* s_ = Bt + (size_t)(n0 + r0_) * K + (kt) * 64 + scol; \
    unsigned short* d_ = smem + (b) * 32768 + 16384 + r0_ * 64 + lc8 * 8;      \
    GLDS16(s_, d_); GLDS16(s_ + (size_t)8 * K, d_ + 8 * 64); }

  f32x4 acc[8][4];
#pragma unroll
  for (int i = 0; i < 8; ++i)
#pragma unroll
    for (int j = 0; j < 4; ++j) acc[i][j] = (f32x4){0.f, 0.f, 0.f, 0.f};

  SA2(0, 0, 0); SA2(1, 0, 0); SB2(0, 0, 0); SB2(1, 0, 0);
  SA2(0, 1, 1); SA2(1, 1, 1); SB2(0, 1, 1); SB2(1, 1, 1);
  asm volatile("s_waitcnt vmcnt(8)" ::: "memory");
  __builtin_amdgcn_s_barrier();

  bf16x8 a0[8], a1[8], b0[4], b1[4];
  const int nkt = K / 64;   // 128
  for (int t = 0; t < nkt; ++t) {
    const int cur = t & 1;
    const int tp2 = (t + 2 < nkt) ? t + 2 : t;
    const unsigned short* As_c = smem + cur * 32768;
    const unsigned short* Bs_c = As_c + 16384;
    rd_a<0>(a0, As_c, wr, fr, fq, swz);
    rd_b<0>(b0, Bs_c, wc, fr, fq, swz);
    rd_b<1>(b1, Bs_c, wc, fr, fq, swz);
    asm volatile("s_waitcnt lgkmcnt(8)" ::: "memory");
    PH_BAR_PRE();
    mm32<0>(acc, a0, b0, b1);
    PH_BAR_POST();
    rd_a<1>(a1, As_c, wr, fr, fq, swz);
    SB2(0, tp2, cur); SB2(1, tp2, cur);
    PH_BAR_PRE();
    mm32<1>(acc, a1, b1, b0);
    __builtin_amdgcn_sched_barrier(0);
    SA2(0, tp2, cur); SA2(1, tp2, cur);
    __builtin_amdgcn_sched_barrier(0);
    asm volatile("s_waitcnt vmcnt(8)" ::: "memory");
    __builtin_amdgcn_s_barrier();
  }
#undef SA2
#undef SB2

#pragma unroll
  for (int nn = 0; nn < 4; ++nn) {
#pragma unroll
    for (int mm = 0; mm < 8; ++mm) {
      const int nsub_lo = (mm < 4) ? (nn >> 1) : 1 - (nn >> 1);
      const int colw = wc * 64 + nsub_lo * 32 + (nn & 1) * 16 + fr;
      const float bb = bias[n0 + colw];
#pragma unroll
      for (int j = 0; j < 4; ++j) {
        const int r = m0 + wr * 128 + (mm >> 2) * 64 + (mm & 3) * 16 + fq * 4 + j;
        if (r < M)
          ybuf[(size_t)(hbase + r) * HD + n0 + colw] = acc[mm][nn][j] + bb;
      }
    }
  }
}

// ---------------- final reduce: out = ysh0+ysh1+g0*ye0+g1*ye1 ----------------
__global__ __launch_bounds__(256) void reduce_kernel(
    const float* __restrict__ ybuf, const int* __restrict__ row_of,
    const float* __restrict__ topv, float* __restrict__ out) {
  const int t = blockIdx.x;
  const int d = threadIdx.x * 8;
  const float g0 = topv[2 * t], g1 = topv[2 * t + 1];
  const float* y0 = ybuf + (size_t)row_of[2 * t] * HD + d;
  const float* y1 = ybuf + (size_t)row_of[2 * t + 1] * HD + d;
  const float* s0 = ybuf + (size_t)(2 * TOKENS + t) * HD + d;
  const float* s1 = ybuf + (size_t)(3 * TOKENS + t) * HD + d;
  float* o = out + (size_t)t * HD + d;
#pragma unroll
  for (int q = 0; q < 2; ++q) {
    const float4 a = *(const float4*)(s0 + q * 4);
    const float4 b = *(const float4*)(s1 + q * 4);
    const float4 c = *(const float4*)(y0 + q * 4);
    const float4 e = *(const float4*)(y1 + q * 4);
    float4 r;
    r.x = a.x + b.x + g0 * c.x + g1 * e.x;
    r.y = a.y + b.y + g0 * c.y + g1 * e.y;
    r.z = a.z + b.z + g0 * c.z + g1 * e.z;
    r.w = a.w + b.w + g0 * c.w + g1 * e.w;
    *(float4*)(o + q * 4) = r;
  }
}

// =======================================================================
// Fallback GEMM2 (R8): 4-phase, atomics, shared experts K-merged (z=9).
// =======================================================================
__global__ __launch_bounds__(512, 2) void gemm8p(
    const unsigned short* __restrict__ hbuf,
    const unsigned short* __restrict__ wt,
    const float* __restrict__ bE, const float* __restrict__ bS,
    float* __restrict__ out,
    const int* __restrict__ counts, const int* __restrict__ offs,
    const int* __restrict__ row_token, const float* __restrict__ row_gate) {
  constexpr int K = FF;
  constexpr int NBX = HD / 256;
  constexpr int NWG = NBX * 16;
  extern __shared__ unsigned short smem[];

  const int e = blockIdx.z;
  const bool merged = (e == NE);
  int M;
  const unsigned short *A, *A2;
  const unsigned short *B, *B2;
  const float *bias, *bias2;
  const int* tok = nullptr;
  const float* gt = nullptr;

  if (!merged) {
    M = counts[e];
    const int off = offs[e];
    A = hbuf + (size_t)off * K;  A2 = A;
    tok = row_token + off; gt = row_gate + off;
    B = wt + (size_t)e * HD * FF;  B2 = B;
    bias = bE + (size_t)e * HD;  bias2 = bias;
  } else {
    M = TOKENS;
    A  = hbuf + (size_t)(2 * TOKENS) * K;
    A2 = hbuf + (size_t)(3 * TOKENS) * K;
    B  = wt + (size_t)NE * HD * FF;
    B2 = wt + (size_t)(NE + 1) * HD * FF;
    bias = bS;  bias2 = bS + HD;
  }

  int flat = blockIdx.x + NBX * blockIdx.y;
  flat = (flat & 7) * (NWG >> 3) + (flat >> 3);
  const int m0 = (flat & 15) * 256;
  const int n0 = (flat >> 4) * 256;
  if (m0 >= M) return;

  const int tid = threadIdx.x;
  const int wid = tid >> 6, ln = tid & 63;
  const int wr = wid >> 2, wc = wid & 3;
  const int fr = ln & 15, fq = ln >> 4;
  const int swz = fr & 7;
  const int lr8 = ln >> 3;
  const int lc8 = ln & 7;
  const int scol = (lc8 ^ lr8) << 3;
  const int wrA = wr * 128 + wc * 16;
  const int wcB = wc * 64 + wr * 16;

#define SAF(s, kt, b)                                                          \
  { int kl_ = (kt); const unsigned short* ab_ = A;                             \
    if (merged && kl_ >= 128) { ab_ = A2; kl_ -= 128; }                        \
    const int r0_ = wrA + (s) * 64 + lr8;                                      \
    const unsigned short* s_ = ab_ + (size_t)(m0 + r0_) * K + kl_ * 64 + scol; \
    unsigned short* d_ = smem + (b) * 32768 + r0_ * 64 + lc8 * 8;              \
    GLDS16(s_, d_); GLDS16(s_ + (size_t)8 * K, d_ + 8 * 64); }
#define SBF(s, kt, b)                                                          \
  { int kl_ = (kt); const unsigned short* bb_ = B;                             \
    if (merged && kl_ >= 128) { bb_ = B2; kl_ -= 128; }                        \
    const int r0_ = wcB + (s) * 32 + lr8;                                      \
    const unsigned short* s_ = bb_ + (size_t)(n0 + r0_) * K + kl_ * 64 + scol; \
    unsigned short* d_ = smem + (b) * 32768 + 16384 + r0_ * 64 + lc8 * 8;      \
    GLDS16(s_, d_); GLDS16(s_ + (size_t)8 * K, d_ + 8 * 64); }

  f32x4 acc[8][4];
#pragma unroll
  for (int i = 0; i < 8; ++i)
#pragma unroll
    for (int j = 0; j < 4; ++j) acc[i][j] = (f32x4){0.f, 0.f, 0.f, 0.f};

  SAF(0, 0, 0); SAF(1, 0, 0); SBF(0, 0, 0); SBF(1, 0, 0);
  SAF(0, 1, 1); SAF(1, 1, 1); SBF(0, 1, 1); SBF(1, 1, 1);
  asm volatile("s_waitcnt vmcnt(8)" ::: "memory");
  __builtin_amdgcn_s_barrier();

  bf16x8 a0[8], a1[8], b0[4], b1[4];
  const int nkt = merged ? 256 : 128;
  for (int t = 0; t < nkt; ++t) {
    const int cur = t & 1;
    const int tp2 = (t + 2 < nkt) ? t + 2 : t;
    const unsigned short* As_c = smem + cur * 32768;
    const unsigned short* Bs_c = As_c + 16384;
    rd_a<0>(a0, As_c, wr, fr, fq, swz);
    rd_b<0>(b0, Bs_c, wc, fr, fq, swz);
    asm volatile("s_waitcnt lgkmcnt(8)" ::: "memory");
    PH_BAR_PRE();
    mm16<0, 0>(acc, a0, b0);
    PH_BAR_POST();
    rd_b<1>(b1, Bs_c, wc, fr, fq, swz);
    SAF(0, tp2, cur); SBF(0, tp2, cur);
    PH_BAR_PRE();
    mm16<0, 1>(acc, a0, b1);
    PH_BAR_POST();
    rd_a<1>(a1, As_c, wr, fr, fq, swz);
    SBF(1, tp2, cur);
    PH_BAR_PRE();
    mm16<1, 1>(acc, a1, b1);
    PH_BAR_POST();
    SAF(1, tp2, cur);
    __builtin_amdgcn_sched_barrier(0);
    __builtin_amdgcn_s_barrier();
    __builtin_amdgcn_sched_barrier(0);
    mm16<1, 0>(acc, a1, b0);
    __builtin_amdgcn_sched_barrier(0);
    asm volatile("s_waitcnt vmcnt(8)" ::: "memory");
    __builtin_amdgcn_s_barrier();
  }
#undef SAF
#undef SBF

#pragma unroll
  for (int mm = 0; mm < 8; ++mm) {
#pragma unroll
    for (int j = 0; j < 4; ++j) {
      const int r = m0 + wr * 128 + (mm >> 2) * 64 + (mm & 3) * 16 + fq * 4 + j;
      if (r < M) {
        const int t = tok ? tok[r] : r;
        const float g = gt ? gt[r] : 1.f;
        float* orow = out + (size_t)t * HD + n0;
#pragma unroll
        for (int nn = 0; nn < 4; ++nn) {
          const int col = wc * 64 + (nn >> 1) * 32 + (nn & 1) * 16 + fr;
          float bb = bias[n0 + col];
          if (merged) bb += bias2[n0 + col];
          atomicAdd(orow + col, g * (acc[mm][nn][j] + bb));
        }
      }
    }
  }
}

extern "C" void kernel_launch(void* const* d_in, const int* in_sizes, int n_in,
                              void* d_out, int out_size, void* d_ws, size_t ws_size,
                              hipStream_t stream) {
  const float* x     = (const float*)d_in[0];
  const float* ws_w1 = (const float*)d_in[1];
  const float* ws_b1 = (const float*)d_in[2];
  const float* ws_w2 = (const float*)d_in[3];
  const float* ws_b2 = (const float*)d_in[4];
  const float* we_w1 = (const float*)d_in[5];
  const float* we_b1 = (const float*)d_in[6];
  const float* we_w2 = (const float*)d_in[7];
  const float* we_b2 = (const float*)d_in[8];
  const float* wg    = (const float*)d_in[9];

  float* out = (float*)d_out;
  float* logits = out + (size_t)TOKENS * HD;

  hipFuncSetAttribute(reinterpret_cast<const void*>(g1k),
                      hipFuncAttributeMaxDynamicSharedMemorySize, 131072);
  hipFuncSetAttribute(reinterpret_cast<const void*>(g2k),
                      hipFuncAttributeMaxDynamicSharedMemorySize, 131072);
  hipFuncSetAttribute(reinterpret_cast<const void*>(gemm8p),
                      hipFuncAttributeMaxDynamicSharedMemorySize, 131072);

  const size_t NEED2 = 990544000ull;  // dual-wt layout
  char* ws = (char*)d_ws;

  if (ws_size >= NEED2) {
    // ---------- new path: dual wt, pack2-in-gemm1, ybuf + reduce ----------
    unsigned short* wt1  = (unsigned short*)ws;                   // 335,544,320
    unsigned short* wt2  = (unsigned short*)(ws + 335544320);     // 335,544,320
    unsigned short* xb   = (unsigned short*)(ws + 671088640);     //  16,777,216
    unsigned short* xg   = (unsigned short*)(ws + 687865856);     //  34,078,720
    unsigned short* hbuf = (unsigned short*)(ws + 721944576);     // 268,435,456
    char* ctrl = ws + 990380032;
    float* ybuf = (float*)ws;                                     // alias wt1 (dead by GEMM2)
    int*   row_token = (int*)(ctrl);
    float* row_gate  = (float*)(ctrl + 32768);
    int*   topi      = (int*)(ctrl + 65536);
    float* topv      = (float*)(ctrl + 98304);
    int*   counts    = (int*)(ctrl + 131072);
    int*   offs      = (int*)(ctrl + 131104);
    int*   cursors   = (int*)(ctrl + 131136);
    int*   row_of    = (int*)(ctrl + 131168);

    hipMemsetAsync(counts, 0, NE * sizeof(int), stream);
    cast_x_kernel<<<8192, 256, 0, stream>>>(x, xb);
    router_kernel<<<1024, 256, 0, stream>>>(x, wg, logits, topi, topv, counts);
    offs_kernel<<<1, 64, 0, stream>>>(counts, offs, cursors);
    gather_kernel<<<1024, 256, 0, stream>>>(xb, topi, topv, cursors, xg,
                                            row_token, row_gate, row_of);
    // pack W1 -> wt1
    pack_wt<HD, FF><<<dim3(FF / 64, HD / 64, 10), 256, 0, stream>>>(we_w1, ws_w1, wt1);
    // GEMM1 (invalid blocks pack W2 -> wt2 concurrently)
    g1k<<<dim3(32, 16, 10), 512, 131072, stream>>>(
        xb, xg, wt1, we_b1, ws_b1, hbuf, counts, offs, 1, we_w2, ws_w2, wt2);
    // GEMM2 -> ybuf (f32, no gate, no atomics)
    g2k<<<dim3(8, 16, 10), 512, 131072, stream>>>(
        hbuf, wt2, we_b2, ws_b2, ybuf, counts, offs);
    // combine
    reduce_kernel<<<TOKENS, 256, 0, stream>>>(ybuf, row_of, topv, out);
  } else {
    // ---------- fallback: R8 path ----------
    unsigned short* wt   = (unsigned short*)ws;
    unsigned short* xb   = (unsigned short*)(ws + 335544320);
    unsigned short* xg   = (unsigned short*)(ws + 352321536);
    unsigned short* hbuf = (unsigned short*)(ws + 386400256);
    char* ctrl = ws + 654835712;
    int*   row_token = (int*)(ctrl);
    float* row_gate  = (float*)(ctrl + 32768);
    int*   topi      = (int*)(ctrl + 65536);
    float* topv      = (float*)(ctrl + 98304);
    int*   counts    = (int*)(ctrl + 131072);
    int*   offs      = (int*)(ctrl + 131104);
    int*   cursors   = (int*)(ctrl + 131136);
    int*   row_of    = (int*)(ctrl + 131168);

    hipMemsetAsync(out, 0, (size_t)TOKENS * HD * sizeof(float), stream);
    hipMemsetAsync(counts, 0, NE * sizeof(int), stream);

    cast_x_kernel<<<8192, 256, 0, stream>>>(x, xb);
    router_kernel<<<1024, 256, 0, stream>>>(x, wg, logits, topi, topv, counts);
    offs_kernel<<<1, 64, 0, stream>>>(counts, offs, cursors);
    gather_kernel<<<1024, 256, 0, stream>>>(xb, topi, topv, cursors, xg,
                                            row_token, row_gate, row_of);

    pack_wt<HD, FF><<<dim3(FF / 64, HD / 64, 10), 256, 0, stream>>>(we_w1, ws_w1, wt);
    g1k<<<dim3(32, 16, 10), 512, 131072, stream>>>(
        xb, xg, wt, we_b1, ws_b1, hbuf, counts, offs, 0, nullptr, nullptr, nullptr);
    pack_wt<FF, HD><<<dim3(HD / 64, FF / 64, 10), 256, 0, stream>>>(we_w2, ws_w2, wt);
    gemm8p<<<dim3(8, 16, 9), 512, 131072, stream>>>(
        hbuf, wt, we_b2, ws_b2, out, counts, offs, row_token, row_gate);
  }

  (void)in_sizes; (void)n_in; (void)out_size; (void)ws_size;
}

// Round 10
// 1913.564 us; speedup vs baseline: 1.0852x; 1.0622x over previous
//
#include <hip/hip_runtime.h>

#define TOKENS 4096
#define HD 2048
#define FF 8192
#define NE 8
#define NS 2

typedef __attribute__((ext_vector_type(8))) short bf16x8;
typedef __attribute__((ext_vector_type(4))) float f32x4;

__device__ __forceinline__ unsigned rnd_bf(unsigned u) {
  return u + 0x7fffu + ((u >> 16) & 1u);
}
__device__ __forceinline__ unsigned short f2bf(float f) {
  unsigned u = __builtin_bit_cast(unsigned, f);
  return (unsigned short)(rnd_bf(u) >> 16);
}

#define GLDS16(gp, lp)                                                         \
  __builtin_amdgcn_global_load_lds(                                            \
      (const __attribute__((address_space(1))) unsigned*)(const void*)(gp),    \
      (__attribute__((address_space(3))) unsigned*)(lp), 16, 0, 0)

// ---------------- cast x f32 -> bf16 ----------------
__global__ void cast_x_kernel(const float* __restrict__ x, unsigned short* __restrict__ xb) {
  const size_t i = ((size_t)blockIdx.x * 256 + threadIdx.x) * 4;
  float4 v = *(const float4*)(x + i);
  ushort4 o;
  o.x = f2bf(v.x); o.y = f2bf(v.y); o.z = f2bf(v.z); o.w = f2bf(v.w);
  *(ushort4*)(xb + i) = o;
}

// ---------------- router ----------------
__global__ void router_kernel(const float* __restrict__ x, const float* __restrict__ wg,
                              float* __restrict__ logits_out, int* __restrict__ topi,
                              float* __restrict__ topv, int* __restrict__ counts) {
  const int wave = threadIdx.x >> 6, lane = threadIdx.x & 63;
  const int t = blockIdx.x * 4 + wave;
  const float* xr = x + (size_t)t * HD;
  float acc[8];
#pragma unroll
  for (int e = 0; e < 8; ++e) acc[e] = 0.f;
  for (int d = lane; d < HD; d += 64) {
    const float xv = xr[d];
    const float4 w0 = *(const float4*)(wg + (size_t)d * 8);
    const float4 w1 = *(const float4*)(wg + (size_t)d * 8 + 4);
    acc[0] += xv * w0.x; acc[1] += xv * w0.y; acc[2] += xv * w0.z; acc[3] += xv * w0.w;
    acc[4] += xv * w1.x; acc[5] += xv * w1.y; acc[6] += xv * w1.z; acc[7] += xv * w1.w;
  }
#pragma unroll
  for (int e = 0; e < 8; ++e) {
#pragma unroll
    for (int off = 32; off > 0; off >>= 1) acc[e] += __shfl_xor(acc[e], off);
  }
  if (lane == 0) {
    *(float4*)(logits_out + (size_t)t * 8)     = make_float4(acc[0], acc[1], acc[2], acc[3]);
    *(float4*)(logits_out + (size_t)t * 8 + 4) = make_float4(acc[4], acc[5], acc[6], acc[7]);
    float mx = acc[0];
#pragma unroll
    for (int e = 1; e < 8; ++e) mx = fmaxf(mx, acc[e]);
    float p[8], s = 0.f;
#pragma unroll
    for (int e = 0; e < 8; ++e) { p[e] = expf(acc[e] - mx); s += p[e]; }
    const float inv = 1.f / s;
    int i1 = 0;
#pragma unroll
    for (int e = 1; e < 8; ++e) if (acc[e] > acc[i1]) i1 = e;
    int i2 = (i1 == 0) ? 1 : 0;
#pragma unroll
    for (int e = 0; e < 8; ++e) if (e != i1 && acc[e] > acc[i2]) i2 = e;
    topi[2 * t]     = i1; topv[2 * t]     = p[i1] * inv;
    topi[2 * t + 1] = i2; topv[2 * t + 1] = p[i2] * inv;
    atomicAdd(&counts[i1], 1);
    atomicAdd(&counts[i2], 1);
  }
}

__global__ void offs_kernel(const int* __restrict__ counts, int* __restrict__ offs,
                            int* __restrict__ cursors) {
  if (threadIdx.x == 0) {
    int r = 0;
    for (int e = 0; e < NE; ++e) { offs[e] = r; cursors[e] = r; r += counts[e]; }
  }
}

__global__ void gather_kernel(const unsigned short* __restrict__ xb,
                              const int* __restrict__ topi, const float* __restrict__ topv,
                              int* __restrict__ cursors, unsigned short* __restrict__ xg,
                              int* __restrict__ row_token, float* __restrict__ row_gate,
                              int* __restrict__ row_of) {
  const int wave = threadIdx.x >> 6, lane = threadIdx.x & 63;
  const int t = blockIdx.x * 4 + wave;
  const uint4* src = (const uint4*)(xb + (size_t)t * HD);
#pragma unroll
  for (int j = 0; j < 2; ++j) {
    const int e = topi[2 * t + j];
    int pos = 0;
    if (lane == 0) {
      pos = atomicAdd(&cursors[e], 1);
      row_token[pos] = t;
      row_gate[pos] = topv[2 * t + j];
      row_of[2 * t + j] = pos;
    }
    pos = __shfl(pos, 0);
    uint4* dst = (uint4*)(xg + (size_t)pos * HD);
#pragma unroll
    for (int c = lane; c < 256; c += 64) dst[c] = src[c];
  }
}

// ---------------- standalone pack: f32 [K][N] -> bf16 B^T [N][K] ----------------
template <int K, int N>
__global__ __launch_bounds__(256) void pack_wt(const float* __restrict__ we,
                                               const float* __restrict__ ws,
                                               unsigned short* __restrict__ dstw) {
  const int e = blockIdx.z;
  const float* src = (e < NE) ? (we + (size_t)e * K * N) : (ws + (size_t)(e - NE) * K * N);
  unsigned short* dst = dstw + (size_t)e * K * N;
  const int nt = blockIdx.x * 64;
  const int kt = blockIdx.y * 64;
  __shared__ unsigned short t[64][73];
  const int tid = threadIdx.x;
  const int rr = tid >> 4, cc = (tid & 15) * 4;
#pragma unroll
  for (int i = 0; i < 4; ++i) {
    const int k = rr + i * 16;
    float4 v = *(const float4*)(src + (size_t)(kt + k) * N + nt + cc);
    t[k][cc + 0] = f2bf(v.x);
    t[k][cc + 1] = f2bf(v.y);
    t[k][cc + 2] = f2bf(v.z);
    t[k][cc + 3] = f2bf(v.w);
  }
  __syncthreads();
  const int nr = tid >> 2, kc = (tid & 3) * 16;
  unsigned u[8];
#pragma unroll
  for (int j = 0; j < 8; ++j)
    u[j] = (unsigned)t[kc + 2 * j][nr] | ((unsigned)t[kc + 2 * j + 1][nr] << 16);
  unsigned short* dp = dst + (size_t)(nt + nr) * K + kt + kc;
  uint4 v0; v0.x = u[0]; v0.y = u[1]; v0.z = u[2]; v0.w = u[3];
  uint4 v1; v1.x = u[4]; v1.y = u[5]; v1.z = u[6]; v1.w = u[7];
  *(uint4*)dp = v0;
  *(uint4*)(dp + 8) = v1;
}

// ---------------- frag read / mfma helpers ----------
template <int MS>
__device__ __forceinline__ void rd_a(bf16x8 (&d)[8], const unsigned short* base,
                                     int wr, int fr, int fq, int swz) {
#pragma unroll
  for (int mi = 0; mi < 4; ++mi)
#pragma unroll
    for (int ks = 0; ks < 2; ++ks)
      d[mi * 2 + ks] = *(const bf16x8*)(base + (wr * 128 + MS * 64 + mi * 16 + fr) * 64 +
                                        (((ks * 4 + fq) ^ swz) << 3));
}
template <int NSUB>
__device__ __forceinline__ void rd_b(bf16x8 (&d)[4], const unsigned short* base,
                                     int wc, int fr, int fq, int swz) {
#pragma unroll
  for (int ni = 0; ni < 2; ++ni)
#pragma unroll
    for (int ks = 0; ks < 2; ++ks)
      d[ni * 2 + ks] = *(const bf16x8*)(base + (wc * 64 + NSUB * 32 + ni * 16 + fr) * 64 +
                                        (((ks * 4 + fq) ^ swz) << 3));
}
template <int MS, int NSUB>
__device__ __forceinline__ void mm16(f32x4 (&acc)[8][4], const bf16x8 (&a)[8],
                                     const bf16x8 (&b)[4]) {
  __builtin_amdgcn_s_setprio(1);
#pragma unroll
  for (int mi = 0; mi < 4; ++mi)
#pragma unroll
    for (int ni = 0; ni < 2; ++ni)
#pragma unroll
      for (int ks = 0; ks < 2; ++ks)
        acc[MS * 4 + mi][NSUB * 2 + ni] = __builtin_amdgcn_mfma_f32_16x16x32_bf16(
            a[mi * 2 + ks], b[ni * 2 + ks], acc[MS * 4 + mi][NSUB * 2 + ni], 0, 0, 0);
  __builtin_amdgcn_s_setprio(0);
}

#define PH_BAR_PRE()                                                           \
  __builtin_amdgcn_sched_barrier(0);                                           \
  __builtin_amdgcn_s_barrier();                                                \
  asm volatile("s_waitcnt lgkmcnt(0)" ::: "memory");                           \
  __builtin_amdgcn_sched_barrier(0)
#define PH_BAR_POST()                                                          \
  __builtin_amdgcn_sched_barrier(0);                                           \
  __builtin_amdgcn_s_barrier()

// =======================================================================
// Register-pipelined K-loop (shared by g1k/g2k): each MFMA cluster's
// operands were ds_read >= 1 phase earlier; 2 barriers + 1 vmcnt(4) +
// 1 lgkmcnt(0) per K-tile.
//   ph0: issue b1-reads(cur);          MFMA Q0(a0,b0)
//   ph1: issue a1-reads(cur);          MFMA Q1(a0,b1); lgkm(0); BAR
//   ph2: stage half t+2 -> cur;        MFMA Q2(a1,b0); vmcnt(4); BAR;
//        lookahead-read a0,b0 of tile t+1 from nxt
//   ph3: stage rest t+2 -> cur;        MFMA Q3(a1,b1)   (no wait)
// Cross-wave safety: B1's lgkm(0) drains all cur-reads before cur re-stage;
// B2's vmcnt(4) leaves exactly this-phase's 4 loads in flight -> tile t+1
// (prev iter's 8 loads) fully landed before lookahead reads.
// =======================================================================
template <int K>
__device__ __forceinline__ void kloop(
    const unsigned short* __restrict__ A, const unsigned short* __restrict__ Bt,
    unsigned short* smem, int m0, int n0, f32x4 (&acc)[8][4],
    int wr, int wc, int fr, int fq, int swz,
    int wrA, int wcB, int lr8, int lc8, int scol) {
#define SAK(s, kt, b)                                                          \
  { const int r0_ = wrA + (s) * 64 + lr8;                                      \
    const unsigned short* s_ = A + (size_t)(m0 + r0_) * K + (kt) * 64 + scol;  \
    unsigned short* d_ = smem + (b) * 32768 + r0_ * 64 + lc8 * 8;              \
    GLDS16(s_, d_); GLDS16(s_ + (size_t)8 * K, d_ + 8 * 64); }
#define SBK(s, kt, b)                                                          \
  { const int r0_ = wcB + (s) * 32 + lr8;                                      \
    const unsigned short* s_ = Bt + (size_t)(n0 + r0_) * K + (kt) * 64 + scol; \
    unsigned short* d_ = smem + (b) * 32768 + 16384 + r0_ * 64 + lc8 * 8;      \
    GLDS16(s_, d_); GLDS16(s_ + (size_t)8 * K, d_ + 8 * 64); }

  // prologue: tile0 -> buf0, tile1 -> buf1; wait tile0 only; pre-read Q0 frags.
  SAK(0, 0, 0); SAK(1, 0, 0); SBK(0, 0, 0); SBK(1, 0, 0);
  SAK(0, 1, 1); SAK(1, 1, 1); SBK(0, 1, 1); SBK(1, 1, 1);
  asm volatile("s_waitcnt vmcnt(8)" ::: "memory");
  __builtin_amdgcn_s_barrier();

  bf16x8 a0[8], a1[8], b0[4], b1[4];
  rd_a<0>(a0, smem, wr, fr, fq, swz);
  rd_b<0>(b0, smem + 16384, wc, fr, fq, swz);

  const int nkt = K / 64;
  for (int t = 0; t < nkt; ++t) {
    const int cur = t & 1;
    const int tp2 = (t + 2 < nkt) ? t + 2 : t;  // tail: benign same-parity re-stage
    const unsigned short* As_c = smem + cur * 32768;
    const unsigned short* Bs_c = As_c + 16384;
    const unsigned short* As_n = smem + (cur ^ 1) * 32768;
    const unsigned short* Bs_n = As_n + 16384;
    // ---- ph0 ----
    rd_b<1>(b1, Bs_c, wc, fr, fq, swz);
    mm16<0, 0>(acc, a0, b0);
    // ---- ph1 ----
    rd_a<1>(a1, As_c, wr, fr, fq, swz);
    mm16<0, 1>(acc, a0, b1);
    asm volatile("s_waitcnt lgkmcnt(0)" ::: "memory");   // B1: own cur-reads done
    __builtin_amdgcn_s_barrier();
    __builtin_amdgcn_sched_barrier(0);
    // ---- ph2 ----
    SAK(0, tp2, cur); SBK(0, tp2, cur);
    mm16<1, 0>(acc, a1, b0);
    asm volatile("s_waitcnt vmcnt(4)" ::: "memory");     // B2: tile t+1 landed
    __builtin_amdgcn_s_barrier();
    __builtin_amdgcn_sched_barrier(0);
    rd_a<0>(a0, As_n, wr, fr, fq, swz);                  // lookahead: next Q0 frags
    rd_b<0>(b0, Bs_n, wc, fr, fq, swz);
    // ---- ph3 ----
    SAK(1, tp2, cur); SBK(1, tp2, cur);
    mm16<1, 1>(acc, a1, b1);
  }
#undef SAK
#undef SBK
}

// =======================================================================
// GEMM1: h = relu(A[M x 2048] * W1t^T + b1) -> bf16 hbuf.
// Invalid blocks (m0 >= M) pack W2 f32->bf16^T into wt2 (do_pack=1).
// =======================================================================
__global__ __launch_bounds__(512, 2) void g1k(
    const unsigned short* __restrict__ Ash, const unsigned short* __restrict__ Art,
    const unsigned short* __restrict__ wt1,
    const float* __restrict__ bE, const float* __restrict__ bS,
    unsigned short* __restrict__ hout,
    const int* __restrict__ counts, const int* __restrict__ offs,
    int do_pack, const float* __restrict__ we_w2, const float* __restrict__ ws_w2,
    unsigned short* __restrict__ wt2) {
  constexpr int K = HD;
  constexpr int NBX = FF / 256;         // 32
  constexpr int NWG = NBX * 16;         // 512
  extern __shared__ unsigned short smem[];

  const int e = blockIdx.z;
  int M;
  const unsigned short* A;
  const float* bias;
  int hbase;
  if (e < NE) {
    M = counts[e];
    A = Art + (size_t)offs[e] * K;
    bias = bE + (size_t)e * FF;
    hbase = offs[e];
  } else {
    M = TOKENS;
    A = Ash;
    bias = bS + (size_t)(e - NE) * FF;
    hbase = 2 * TOKENS + (e - NE) * TOKENS;
  }
  const unsigned short* Bt = wt1 + (size_t)e * HD * FF;

  int flat = blockIdx.x + NBX * blockIdx.y;
  flat = (flat & 7) * (NWG >> 3) + (flat >> 3);
  const int m0 = (flat & 15) * 256;
  const int n0 = (flat >> 4) * 256;
  const int tid = threadIdx.x;

  if (m0 >= M) {
    if (!do_pack) return;
    int total = 0, prefix = 0;
    for (int e2 = 0; e2 < NE; ++e2) {
      int mb = (counts[e2] + 255) >> 8; if (mb > 16) mb = 16;
      const int inv = 32 * (16 - mb);
      if (e2 < e) prefix += inv;
      total += inv;
    }
    int mb_e = (counts[e] + 255) >> 8; if (mb_e > 16) mb_e = 16;
    const int m_idx = flat & 15, n_idx = flat >> 4;
    const int rank = prefix + n_idx * (16 - mb_e) + (m_idx - mb_e);
    unsigned short* ps = smem;  // [64][72]
    const int NT = 10 * 128 * 32;
    for (int i = rank; i < NT; i += total) {
      const int e2 = i >> 12;
      const int rem = i & 4095;
      const int ktt = rem >> 5;
      const int ntt = rem & 31;
      const float* src = (e2 < NE) ? (we_w2 + (size_t)e2 * FF * HD)
                                   : (ws_w2 + (size_t)(e2 - NE) * FF * HD);
      unsigned short* dst = wt2 + (size_t)e2 * HD * FF;
      __syncthreads();
      {
        const int kk = tid >> 3, cc = (tid & 7) * 8;
        const float* sp = src + (size_t)(ktt * 64 + kk) * HD + ntt * 64 + cc;
        const float4 v0 = *(const float4*)sp;
        const float4 v1 = *(const float4*)(sp + 4);
        unsigned short* tp = ps + kk * 72 + cc;
        tp[0] = f2bf(v0.x); tp[1] = f2bf(v0.y); tp[2] = f2bf(v0.z); tp[3] = f2bf(v0.w);
        tp[4] = f2bf(v1.x); tp[5] = f2bf(v1.y); tp[6] = f2bf(v1.z); tp[7] = f2bf(v1.w);
      }
      __syncthreads();
      {
        const int nn = tid >> 3, kc = (tid & 7) * 8;
        unsigned u[4];
#pragma unroll
        for (int j = 0; j < 4; ++j)
          u[j] = (unsigned)ps[(kc + 2 * j) * 72 + nn] |
                 ((unsigned)ps[(kc + 2 * j + 1) * 72 + nn] << 16);
        uint4 v; v.x = u[0]; v.y = u[1]; v.z = u[2]; v.w = u[3];
        *(uint4*)(dst + (size_t)(ntt * 64 + nn) * FF + ktt * 64 + kc) = v;
      }
    }
    return;
  }

  const int wid = tid >> 6, ln = tid & 63;
  const int wr = wid >> 2, wc = wid & 3;
  const int fr = ln & 15, fq = ln >> 4;
  const int swz = fr & 7;
  const int lr8 = ln >> 3;
  const int lc8 = ln & 7;
  const int scol = (lc8 ^ lr8) << 3;
  const int wrA = wr * 128 + wc * 16;
  const int wcB = wc * 64 + wr * 16;

  f32x4 acc[8][4];
#pragma unroll
  for (int i = 0; i < 8; ++i)
#pragma unroll
    for (int j = 0; j < 4; ++j) acc[i][j] = (f32x4){0.f, 0.f, 0.f, 0.f};

  kloop<K>(A, Bt, smem, m0, n0, acc, wr, wc, fr, fq, swz, wrA, wcB, lr8, lc8, scol);

#pragma unroll
  for (int nn = 0; nn < 4; ++nn) {
#pragma unroll
    for (int mm = 0; mm < 8; ++mm) {
      const int col = n0 + wc * 64 + (nn >> 1) * 32 + (nn & 1) * 16 + fr;
      const float bb = bias[col];
#pragma unroll
      for (int j = 0; j < 4; ++j) {
        const int r = m0 + wr * 128 + (mm >> 2) * 64 + (mm & 3) * 16 + fq * 4 + j;
        if (r < M) {
          float v = acc[mm][nn][j] + bb;
          v = v > 0.f ? v : 0.f;
          hout[(size_t)(hbase + r) * FF + col] = f2bf(v);
        }
      }
    }
  }
}

// =======================================================================
// GEMM2: ybuf[row] = h * W2t^T + b2  (f32, no gate, no atomics; z=10).
// =======================================================================
__global__ __launch_bounds__(512, 2) void g2k(
    const unsigned short* __restrict__ hbuf, const unsigned short* __restrict__ wt2,
    const float* __restrict__ bE, const float* __restrict__ bS,
    float* __restrict__ ybuf,
    const int* __restrict__ counts, const int* __restrict__ offs) {
  constexpr int K = FF;
  constexpr int NBX = HD / 256;         // 8
  constexpr int NWG = NBX * 16;         // 128
  extern __shared__ unsigned short smem[];

  const int e = blockIdx.z;
  int M;
  const unsigned short* A;
  const float* bias;
  int hbase;
  if (e < NE) {
    M = counts[e];
    A = hbuf + (size_t)offs[e] * K;
    bias = bE + (size_t)e * HD;
    hbase = offs[e];
  } else {
    M = TOKENS;
    hbase = 2 * TOKENS + (e - NE) * TOKENS;
    A = hbuf + (size_t)hbase * K;
    bias = bS + (size_t)(e - NE) * HD;
  }
  const unsigned short* Bt = wt2 + (size_t)e * HD * FF;

  int flat = blockIdx.x + NBX * blockIdx.y;
  flat = (flat & 7) * (NWG >> 3) + (flat >> 3);
  const int m0 = (flat & 15) * 256;
  const int n0 = (flat >> 4) * 256;
  if (m0 >= M) return;

  const int tid = threadIdx.x;
  const int wid = tid >> 6, ln = tid & 63;
  const int wr = wid >> 2, wc = wid & 3;
  const int fr = ln & 15, fq = ln >> 4;
  const int swz = fr & 7;
  const int lr8 = ln >> 3;
  const int lc8 = ln & 7;
  const int scol = (lc8 ^ lr8) << 3;
  const int wrA = wr * 128 + wc * 16;
  const int wcB = wc * 64 + wr * 16;

  f32x4 acc[8][4];
#pragma unroll
  for (int i = 0; i < 8; ++i)
#pragma unroll
    for (int j = 0; j < 4; ++j) acc[i][j] = (f32x4){0.f, 0.f, 0.f, 0.f};

  kloop<K>(A, Bt, smem, m0, n0, acc, wr, wc, fr, fq, swz, wrA, wcB, lr8, lc8, scol);

#pragma unroll
  for (int nn = 0; nn < 4; ++nn) {
#pragma unroll
    for (int mm = 0; mm < 8; ++mm) {
      const int colw = wc * 64 + (nn >> 1) * 32 + (nn & 1) * 16 + fr;
      const float bb = bias[n0 + colw];
#pragma unroll
      for (int j = 0; j < 4; ++j) {
        const int r = m0 + wr * 128 + (mm >> 2) * 64 + (mm & 3) * 16 + fq * 4 + j;
        if (r < M)
          ybuf[(size_t)(hbase + r) * HD + n0 + colw] = acc[mm][nn][j] + bb;
      }
    }
  }
}

// ---------------- final reduce: out = ysh0+ysh1+g0*ye0+g1*ye1 ----------------
__global__ __launch_bounds__(256) void reduce_kernel(
    const float* __restrict__ ybuf, const int* __restrict__ row_of,
    const float* __restrict__ topv, float* __restrict__ out) {
  const int t = blockIdx.x;
  const int d = threadIdx.x * 8;
  const float g0 = topv[2 * t], g1 = topv[2 * t + 1];
  const float* y0 = ybuf + (size_t)row_of[2 * t] * HD + d;
  const float* y1 = ybuf + (size_t)row_of[2 * t + 1] * HD + d;
  const float* s0 = ybuf + (size_t)(2 * TOKENS + t) * HD + d;
  const float* s1 = ybuf + (size_t)(3 * TOKENS + t) * HD + d;
  float* o = out + (size_t)t * HD + d;
#pragma unroll
  for (int q = 0; q < 2; ++q) {
    const float4 a = *(const float4*)(s0 + q * 4);
    const float4 b = *(const float4*)(s1 + q * 4);
    const float4 c = *(const float4*)(y0 + q * 4);
    const float4 e = *(const float4*)(y1 + q * 4);
    float4 r;
    r.x = a.x + b.x + g0 * c.x + g1 * e.x;
    r.y = a.y + b.y + g0 * c.y + g1 * e.y;
    r.z = a.z + b.z + g0 * c.z + g1 * e.z;
    r.w = a.w + b.w + g0 * c.w + g1 * e.w;
    *(float4*)(o + q * 4) = r;
  }
}

// =======================================================================
// Fallback GEMM2 (R8): 4-phase, atomics, shared experts K-merged (z=9).
// =======================================================================
__global__ __launch_bounds__(512, 2) void gemm8p(
    const unsigned short* __restrict__ hbuf,
    const unsigned short* __restrict__ wt,
    const float* __restrict__ bE, const float* __restrict__ bS,
    float* __restrict__ out,
    const int* __restrict__ counts, const int* __restrict__ offs,
    const int* __restrict__ row_token, const float* __restrict__ row_gate) {
  constexpr int K = FF;
  constexpr int NBX = HD / 256;
  constexpr int NWG = NBX * 16;
  extern __shared__ unsigned short smem[];

  const int e = blockIdx.z;
  const bool merged = (e == NE);
  int M;
  const unsigned short *A, *A2;
  const unsigned short *B, *B2;
  const float *bias, *bias2;
  const int* tok = nullptr;
  const float* gt = nullptr;

  if (!merged) {
    M = counts[e];
    const int off = offs[e];
    A = hbuf + (size_t)off * K;  A2 = A;
    tok = row_token + off; gt = row_gate + off;
    B = wt + (size_t)e * HD * FF;  B2 = B;
    bias = bE + (size_t)e * HD;  bias2 = bias;
  } else {
    M = TOKENS;
    A  = hbuf + (size_t)(2 * TOKENS) * K;
    A2 = hbuf + (size_t)(3 * TOKENS) * K;
    B  = wt + (size_t)NE * HD * FF;
    B2 = wt + (size_t)(NE + 1) * HD * FF;
    bias = bS;  bias2 = bS + HD;
  }

  int flat = blockIdx.x + NBX * blockIdx.y;
  flat = (flat & 7) * (NWG >> 3) + (flat >> 3);
  const int m0 = (flat & 15) * 256;
  const int n0 = (flat >> 4) * 256;
  if (m0 >= M) return;

  const int tid = threadIdx.x;
  const int wid = tid >> 6, ln = tid & 63;
  const int wr = wid >> 2, wc = wid & 3;
  const int fr = ln & 15, fq = ln >> 4;
  const int swz = fr & 7;
  const int lr8 = ln >> 3;
  const int lc8 = ln & 7;
  const int scol = (lc8 ^ lr8) << 3;
  const int wrA = wr * 128 + wc * 16;
  const int wcB = wc * 64 + wr * 16;

#define SAF(s, kt, b)                                                          \
  { int kl_ = (kt); const unsigned short* ab_ = A;                             \
    if (merged && kl_ >= 128) { ab_ = A2; kl_ -= 128; }                        \
    const int r0_ = wrA + (s) * 64 + lr8;                                      \
    const unsigned short* s_ = ab_ + (size_t)(m0 + r0_) * K + kl_ * 64 + scol; \
    unsigned short* d_ = smem + (b) * 32768 + r0_ * 64 + lc8 * 8;              \
    GLDS16(s_, d_); GLDS16(s_ + (size_t)8 * K, d_ + 8 * 64); }
#define SBF(s, kt, b)                                                          \
  { int kl_ = (kt); const unsigned short* bb_ = B;                             \
    if (merged && kl_ >= 128) { bb_ = B2; kl_ -= 128; }                        \
    const int r0_ = wcB + (s) * 32 + lr8;                                      \
    const unsigned short* s_ = bb_ + (size_t)(n0 + r0_) * K + kl_ * 64 + scol; \
    unsigned short* d_ = smem + (b) * 32768 + 16384 + r0_ * 64 + lc8 * 8;      \
    GLDS16(s_, d_); GLDS16(s_ + (size_t)8 * K, d_ + 8 * 64); }

  f32x4 acc[8][4];
#pragma unroll
  for (int i = 0; i < 8; ++i)
#pragma unroll
    for (int j = 0; j < 4; ++j) acc[i][j] = (f32x4){0.f, 0.f, 0.f, 0.f};

  SAF(0, 0, 0); SAF(1, 0, 0); SBF(0, 0, 0); SBF(1, 0, 0);
  SAF(0, 1, 1); SAF(1, 1, 1); SBF(0, 1, 1); SBF(1, 1, 1);
  asm volatile("s_waitcnt vmcnt(8)" ::: "memory");
  __builtin_amdgcn_s_barrier();

  bf16x8 a0[8], a1[8], b0[4], b1[4];
  const int nkt = merged ? 256 : 128;
  for (int t = 0; t < nkt; ++t) {
    const int cur = t & 1;
    const int tp2 = (t + 2 < nkt) ? t + 2 : t;
    const unsigned short* As_c = smem + cur * 32768;
    const unsigned short* Bs_c = As_c + 16384;
    rd_a<0>(a0, As_c, wr, fr, fq, swz);
    rd_b<0>(b0, Bs_c, wc, fr, fq, swz);
    asm volatile("s_waitcnt lgkmcnt(8)" ::: "memory");
    PH_BAR_PRE();
    mm16<0, 0>(acc, a0, b0);
    PH_BAR_POST();
    rd_b<1>(b1, Bs_c, wc, fr, fq, swz);
    SAF(0, tp2, cur); SBF(0, tp2, cur);
    PH_BAR_PRE();
    mm16<0, 1>(acc, a0, b1);
    PH_BAR_POST();
    rd_a<1>(a1, As_c, wr, fr, fq, swz);
    SBF(1, tp2, cur);
    PH_BAR_PRE();
    mm16<1, 1>(acc, a1, b1);
    PH_BAR_POST();
    SAF(1, tp2, cur);
    __builtin_amdgcn_sched_barrier(0);
    __builtin_amdgcn_s_barrier();
    __builtin_amdgcn_sched_barrier(0);
    mm16<1, 0>(acc, a1, b0);
    __builtin_amdgcn_sched_barrier(0);
    asm volatile("s_waitcnt vmcnt(8)" ::: "memory");
    __builtin_amdgcn_s_barrier();
  }
#undef SAF
#undef SBF

#pragma unroll
  for (int mm = 0; mm < 8; ++mm) {
#pragma unroll
    for (int j = 0; j < 4; ++j) {
      const int r = m0 + wr * 128 + (mm >> 2) * 64 + (mm & 3) * 16 + fq * 4 + j;
      if (r < M) {
        const int t = tok ? tok[r] : r;
        const float g = gt ? gt[r] : 1.f;
        float* orow = out + (size_t)t * HD + n0;
#pragma unroll
        for (int nn = 0; nn < 4; ++nn) {
          const int col = wc * 64 + (nn >> 1) * 32 + (nn & 1) * 16 + fr;
          float bb = bias[n0 + col];
          if (merged) bb += bias2[n0 + col];
          atomicAdd(orow + col, g * (acc[mm][nn][j] + bb));
        }
      }
    }
  }
}

extern "C" void kernel_launch(void* const* d_in, const int* in_sizes, int n_in,
                              void* d_out, int out_size, void* d_ws, size_t ws_size,
                              hipStream_t stream) {
  const float* x     = (const float*)d_in[0];
  const float* ws_w1 = (const float*)d_in[1];
  const float* ws_b1 = (const float*)d_in[2];
  const float* ws_w2 = (const float*)d_in[3];
  const float* ws_b2 = (const float*)d_in[4];
  const float* we_w1 = (const float*)d_in[5];
  const float* we_b1 = (const float*)d_in[6];
  const float* we_w2 = (const float*)d_in[7];
  const float* we_b2 = (const float*)d_in[8];
  const float* wg    = (const float*)d_in[9];

  float* out = (float*)d_out;
  float* logits = out + (size_t)TOKENS * HD;

  hipFuncSetAttribute(reinterpret_cast<const void*>(g1k),
                      hipFuncAttributeMaxDynamicSharedMemorySize, 131072);
  hipFuncSetAttribute(reinterpret_cast<const void*>(g2k),
                      hipFuncAttributeMaxDynamicSharedMemorySize, 131072);
  hipFuncSetAttribute(reinterpret_cast<const void*>(gemm8p),
                      hipFuncAttributeMaxDynamicSharedMemorySize, 131072);

  const size_t NEED2 = 990544000ull;  // dual-wt layout
  char* ws = (char*)d_ws;

  if (ws_size >= NEED2) {
    unsigned short* wt1  = (unsigned short*)ws;                   // 335,544,320
    unsigned short* wt2  = (unsigned short*)(ws + 335544320);     // 335,544,320
    unsigned short* xb   = (unsigned short*)(ws + 671088640);     //  16,777,216
    unsigned short* xg   = (unsigned short*)(ws + 687865856);     //  34,078,720
    unsigned short* hbuf = (unsigned short*)(ws + 721944576);     // 268,435,456
    char* ctrl = ws + 990380032;
    float* ybuf = (float*)ws;                                     // alias wt1 (dead by GEMM2)
    int*   row_token = (int*)(ctrl);
    float* row_gate  = (float*)(ctrl + 32768);
    int*   topi      = (int*)(ctrl + 65536);
    float* topv      = (float*)(ctrl + 98304);
    int*   counts    = (int*)(ctrl + 131072);
    int*   offs      = (int*)(ctrl + 131104);
    int*   cursors   = (int*)(ctrl + 131136);
    int*   row_of    = (int*)(ctrl + 131168);

    hipMemsetAsync(counts, 0, NE * sizeof(int), stream);
    cast_x_kernel<<<8192, 256, 0, stream>>>(x, xb);
    router_kernel<<<1024, 256, 0, stream>>>(x, wg, logits, topi, topv, counts);
    offs_kernel<<<1, 64, 0, stream>>>(counts, offs, cursors);
    gather_kernel<<<1024, 256, 0, stream>>>(xb, topi, topv, cursors, xg,
                                            row_token, row_gate, row_of);
    pack_wt<HD, FF><<<dim3(FF / 64, HD / 64, 10), 256, 0, stream>>>(we_w1, ws_w1, wt1);
    g1k<<<dim3(32, 16, 10), 512, 131072, stream>>>(
        xb, xg, wt1, we_b1, ws_b1, hbuf, counts, offs, 1, we_w2, ws_w2, wt2);
    g2k<<<dim3(8, 16, 10), 512, 131072, stream>>>(
        hbuf, wt2, we_b2, ws_b2, ybuf, counts, offs);
    reduce_kernel<<<TOKENS, 256, 0, stream>>>(ybuf, row_of, topv, out);
  } else {
    unsigned short* wt   = (unsigned short*)ws;
    unsigned short* xb   = (unsigned short*)(ws + 335544320);
    unsigned short* xg   = (unsigned short*)(ws + 352321536);
    unsigned short* hbuf = (unsigned short*)(ws + 386400256);
    char* ctrl = ws + 654835712;
    int*   row_token = (int*)(ctrl);
    float* row_gate  = (float*)(ctrl + 32768);
    int*   topi      = (int*)(ctrl + 65536);
    float* topv      = (float*)(ctrl + 98304);
    int*   counts    = (int*)(ctrl + 131072);
    int*   offs      = (int*)(ctrl + 131104);
    int*   cursors   = (int*)(ctrl + 131136);
    int*   row_of    = (int*)(ctrl + 131168);

    hipMemsetAsync(out, 0, (size_t)TOKENS * HD * sizeof(float), stream);
    hipMemsetAsync(counts, 0, NE * sizeof(int), stream);

    cast_x_kernel<<<8192, 256, 0, stream>>>(x, xb);
    router_kernel<<<1024, 256, 0, stream>>>(x, wg, logits, topi, topv, counts);
    offs_kernel<<<1, 64, 0, stream>>>(counts, offs, cursors);
    gather_kernel<<<1024, 256, 0, stream>>>(xb, topi, topv, cursors, xg,
                                            row_token, row_gate, row_of);

    pack_wt<HD, FF><<<dim3(FF / 64, HD / 64, 10), 256, 0, stream>>>(we_w1, ws_w1, wt);
    g1k<<<dim3(32, 16, 10), 512, 131072, stream>>>(
        xb, xg, wt, we_b1, ws_b1, hbuf, counts, offs, 0, nullptr, nullptr, nullptr);
    pack_wt<FF, HD><<<dim3(HD / 64, FF / 64, 10), 256, 0, stream>>>(we_w2, ws_w2, wt);
    gemm8p<<<dim3(8, 16, 9), 512, 131072, stream>>>(
        hbuf, wt, we_b2, ws_b2, out, counts, offs, row_token, row_gate);
  }

  (void)in_sizes; (void)n_in; (void)out_size; (void)ws_size;
}

// Round 11
// 1875.296 us; speedup vs baseline: 1.1073x; 1.0204x over previous
//
#include <hip/hip_runtime.h>

#define TOKENS 4096
#define HD 2048
#define FF 8192
#define NE 8
#define NS 2

typedef __attribute__((ext_vector_type(8))) short bf16x8;
typedef __attribute__((ext_vector_type(4))) float f32x4;

__device__ __forceinline__ unsigned rnd_bf(unsigned u) {
  return u + 0x7fffu + ((u >> 16) & 1u);
}
__device__ __forceinline__ unsigned short f2bf(float f) {
  unsigned u = __builtin_bit_cast(unsigned, f);
  return (unsigned short)(rnd_bf(u) >> 16);
}

#define GLDS16(gp, lp)                                                         \
  __builtin_amdgcn_global_load_lds(                                            \
      (const __attribute__((address_space(1))) unsigned*)(const void*)(gp),    \
      (__attribute__((address_space(3))) unsigned*)(lp), 16, 0, 0)

// ---------------- cast x f32 -> bf16 ----------------
__global__ void cast_x_kernel(const float* __restrict__ x, unsigned short* __restrict__ xb) {
  const size_t i = ((size_t)blockIdx.x * 256 + threadIdx.x) * 4;
  float4 v = *(const float4*)(x + i);
  ushort4 o;
  o.x = f2bf(v.x); o.y = f2bf(v.y); o.z = f2bf(v.z); o.w = f2bf(v.w);
  *(ushort4*)(xb + i) = o;
}

// ---------------- router ----------------
__global__ void router_kernel(const float* __restrict__ x, const float* __restrict__ wg,
                              float* __restrict__ logits_out, int* __restrict__ topi,
                              float* __restrict__ topv, int* __restrict__ counts) {
  const int wave = threadIdx.x >> 6, lane = threadIdx.x & 63;
  const int t = blockIdx.x * 4 + wave;
  const float* xr = x + (size_t)t * HD;
  float acc[8];
#pragma unroll
  for (int e = 0; e < 8; ++e) acc[e] = 0.f;
  for (int d = lane; d < HD; d += 64) {
    const float xv = xr[d];
    const float4 w0 = *(const float4*)(wg + (size_t)d * 8);
    const float4 w1 = *(const float4*)(wg + (size_t)d * 8 + 4);
    acc[0] += xv * w0.x; acc[1] += xv * w0.y; acc[2] += xv * w0.z; acc[3] += xv * w0.w;
    acc[4] += xv * w1.x; acc[5] += xv * w1.y; acc[6] += xv * w1.z; acc[7] += xv * w1.w;
  }
#pragma unroll
  for (int e = 0; e < 8; ++e) {
#pragma unroll
    for (int off = 32; off > 0; off >>= 1) acc[e] += __shfl_xor(acc[e], off);
  }
  if (lane == 0) {
    *(float4*)(logits_out + (size_t)t * 8)     = make_float4(acc[0], acc[1], acc[2], acc[3]);
    *(float4*)(logits_out + (size_t)t * 8 + 4) = make_float4(acc[4], acc[5], acc[6], acc[7]);
    float mx = acc[0];
#pragma unroll
    for (int e = 1; e < 8; ++e) mx = fmaxf(mx, acc[e]);
    float p[8], s = 0.f;
#pragma unroll
    for (int e = 0; e < 8; ++e) { p[e] = expf(acc[e] - mx); s += p[e]; }
    const float inv = 1.f / s;
    int i1 = 0;
#pragma unroll
    for (int e = 1; e < 8; ++e) if (acc[e] > acc[i1]) i1 = e;
    int i2 = (i1 == 0) ? 1 : 0;
#pragma unroll
    for (int e = 0; e < 8; ++e) if (e != i1 && acc[e] > acc[i2]) i2 = e;
    topi[2 * t]     = i1; topv[2 * t]     = p[i1] * inv;
    topi[2 * t + 1] = i2; topv[2 * t + 1] = p[i2] * inv;
    atomicAdd(&counts[i1], 1);
    atomicAdd(&counts[i2], 1);
  }
}

__global__ void offs_kernel(const int* __restrict__ counts, int* __restrict__ offs,
                            int* __restrict__ cursors) {
  if (threadIdx.x == 0) {
    int r = 0;
    for (int e = 0; e < NE; ++e) { offs[e] = r; cursors[e] = r; r += counts[e]; }
  }
}

__global__ void gather_kernel(const unsigned short* __restrict__ xb,
                              const int* __restrict__ topi, const float* __restrict__ topv,
                              int* __restrict__ cursors, unsigned short* __restrict__ xg,
                              int* __restrict__ row_token, float* __restrict__ row_gate,
                              int* __restrict__ row_of) {
  const int wave = threadIdx.x >> 6, lane = threadIdx.x & 63;
  const int t = blockIdx.x * 4 + wave;
  const uint4* src = (const uint4*)(xb + (size_t)t * HD);
#pragma unroll
  for (int j = 0; j < 2; ++j) {
    const int e = topi[2 * t + j];
    int pos = 0;
    if (lane == 0) {
      pos = atomicAdd(&cursors[e], 1);
      row_token[pos] = t;
      row_gate[pos] = topv[2 * t + j];
      row_of[2 * t + j] = pos;
    }
    pos = __shfl(pos, 0);
    uint4* dst = (uint4*)(xg + (size_t)pos * HD);
#pragma unroll
    for (int c = lane; c < 256; c += 64) dst[c] = src[c];
  }
}

// ---------------- standalone pack: f32 [K][N] -> bf16 B^T [N][K] ----------------
template <int K, int N>
__global__ __launch_bounds__(256) void pack_wt(const float* __restrict__ we,
                                               const float* __restrict__ ws,
                                               unsigned short* __restrict__ dstw) {
  const int e = blockIdx.z;
  const float* src = (e < NE) ? (we + (size_t)e * K * N) : (ws + (size_t)(e - NE) * K * N);
  unsigned short* dst = dstw + (size_t)e * K * N;
  const int nt = blockIdx.x * 64;
  const int kt = blockIdx.y * 64;
  __shared__ unsigned short t[64][73];
  const int tid = threadIdx.x;
  const int rr = tid >> 4, cc = (tid & 15) * 4;
#pragma unroll
  for (int i = 0; i < 4; ++i) {
    const int k = rr + i * 16;
    float4 v = *(const float4*)(src + (size_t)(kt + k) * N + nt + cc);
    t[k][cc + 0] = f2bf(v.x);
    t[k][cc + 1] = f2bf(v.y);
    t[k][cc + 2] = f2bf(v.z);
    t[k][cc + 3] = f2bf(v.w);
  }
  __syncthreads();
  const int nr = tid >> 2, kc = (tid & 3) * 16;
  unsigned u[8];
#pragma unroll
  for (int j = 0; j < 8; ++j)
    u[j] = (unsigned)t[kc + 2 * j][nr] | ((unsigned)t[kc + 2 * j + 1][nr] << 16);
  unsigned short* dp = dst + (size_t)(nt + nr) * K + kt + kc;
  uint4 v0; v0.x = u[0]; v0.y = u[1]; v0.z = u[2]; v0.w = u[3];
  uint4 v1; v1.x = u[4]; v1.y = u[5]; v1.z = u[6]; v1.w = u[7];
  *(uint4*)dp = v0;
  *(uint4*)(dp + 8) = v1;
}

// ---------------- frag read / mfma helpers ----------
template <int MS>
__device__ __forceinline__ void rd_a(bf16x8 (&d)[8], const unsigned short* base,
                                     int wr, int fr, int fq, int swz) {
#pragma unroll
  for (int mi = 0; mi < 4; ++mi)
#pragma unroll
    for (int ks = 0; ks < 2; ++ks)
      d[mi * 2 + ks] = *(const bf16x8*)(base + (wr * 128 + MS * 64 + mi * 16 + fr) * 64 +
                                        (((ks * 4 + fq) ^ swz) << 3));
}
template <int NSUB>
__device__ __forceinline__ void rd_b(bf16x8 (&d)[4], const unsigned short* base,
                                     int wc, int fr, int fq, int swz) {
#pragma unroll
  for (int ni = 0; ni < 2; ++ni)
#pragma unroll
    for (int ks = 0; ks < 2; ++ks)
      d[ni * 2 + ks] = *(const bf16x8*)(base + (wc * 64 + NSUB * 32 + ni * 16 + fr) * 64 +
                                        (((ks * 4 + fq) ^ swz) << 3));
}
template <int MS, int NSUB>
__device__ __forceinline__ void mm16(f32x4 (&acc)[8][4], const bf16x8 (&a)[8],
                                     const bf16x8 (&b)[4]) {
  __builtin_amdgcn_s_setprio(1);
#pragma unroll
  for (int mi = 0; mi < 4; ++mi)
#pragma unroll
    for (int ni = 0; ni < 2; ++ni)
#pragma unroll
      for (int ks = 0; ks < 2; ++ks)
        acc[MS * 4 + mi][NSUB * 2 + ni] = __builtin_amdgcn_mfma_f32_16x16x32_bf16(
            a[mi * 2 + ks], b[ni * 2 + ks], acc[MS * 4 + mi][NSUB * 2 + ni], 0, 0, 0);
  __builtin_amdgcn_s_setprio(0);
}

#define PH_BAR_PRE()                                                           \
  __builtin_amdgcn_sched_barrier(0);                                           \
  __builtin_amdgcn_s_barrier();                                                \
  asm volatile("s_waitcnt lgkmcnt(0)" ::: "memory");                           \
  __builtin_amdgcn_sched_barrier(0)
#define PH_BAR_POST()                                                          \
  __builtin_amdgcn_sched_barrier(0);                                           \
  __builtin_amdgcn_s_barrier()

// =======================================================================
// Register-pipelined K-loop (shared by g1k/g2k) — unchanged from R10.
// =======================================================================
template <int K>
__device__ __forceinline__ void kloop(
    const unsigned short* __restrict__ A, const unsigned short* __restrict__ Bt,
    unsigned short* smem, int m0, int n0, f32x4 (&acc)[8][4],
    int wr, int wc, int fr, int fq, int swz,
    int wrA, int wcB, int lr8, int lc8, int scol) {
#define SAK(s, kt, b)                                                          \
  { const int r0_ = wrA + (s) * 64 + lr8;                                      \
    const unsigned short* s_ = A + (size_t)(m0 + r0_) * K + (kt) * 64 + scol;  \
    unsigned short* d_ = smem + (b) * 32768 + r0_ * 64 + lc8 * 8;              \
    GLDS16(s_, d_); GLDS16(s_ + (size_t)8 * K, d_ + 8 * 64); }
#define SBK(s, kt, b)                                                          \
  { const int r0_ = wcB + (s) * 32 + lr8;                                      \
    const unsigned short* s_ = Bt + (size_t)(n0 + r0_) * K + (kt) * 64 + scol; \
    unsigned short* d_ = smem + (b) * 32768 + 16384 + r0_ * 64 + lc8 * 8;      \
    GLDS16(s_, d_); GLDS16(s_ + (size_t)8 * K, d_ + 8 * 64); }

  SAK(0, 0, 0); SAK(1, 0, 0); SBK(0, 0, 0); SBK(1, 0, 0);
  SAK(0, 1, 1); SAK(1, 1, 1); SBK(0, 1, 1); SBK(1, 1, 1);
  asm volatile("s_waitcnt vmcnt(8)" ::: "memory");
  __builtin_amdgcn_s_barrier();

  bf16x8 a0[8], a1[8], b0[4], b1[4];
  rd_a<0>(a0, smem, wr, fr, fq, swz);
  rd_b<0>(b0, smem + 16384, wc, fr, fq, swz);

  const int nkt = K / 64;
  for (int t = 0; t < nkt; ++t) {
    const int cur = t & 1;
    const int tp2 = (t + 2 < nkt) ? t + 2 : t;
    const unsigned short* As_c = smem + cur * 32768;
    const unsigned short* Bs_c = As_c + 16384;
    const unsigned short* As_n = smem + (cur ^ 1) * 32768;
    const unsigned short* Bs_n = As_n + 16384;
    // ---- ph0 ----
    rd_b<1>(b1, Bs_c, wc, fr, fq, swz);
    mm16<0, 0>(acc, a0, b0);
    // ---- ph1 ----
    rd_a<1>(a1, As_c, wr, fr, fq, swz);
    mm16<0, 1>(acc, a0, b1);
    asm volatile("s_waitcnt lgkmcnt(0)" ::: "memory");
    __builtin_amdgcn_s_barrier();
    __builtin_amdgcn_sched_barrier(0);
    // ---- ph2 ----
    SAK(0, tp2, cur); SBK(0, tp2, cur);
    mm16<1, 0>(acc, a1, b0);
    asm volatile("s_waitcnt vmcnt(4)" ::: "memory");
    __builtin_amdgcn_s_barrier();
    __builtin_amdgcn_sched_barrier(0);
    rd_a<0>(a0, As_n, wr, fr, fq, swz);
    rd_b<0>(b0, Bs_n, wc, fr, fq, swz);
    // ---- ph3 ----
    SAK(1, tp2, cur); SBK(1, tp2, cur);
    mm16<1, 1>(acc, a1, b1);
  }
#undef SAK
#undef SBK
}

// =======================================================================
// GEMM1: h = relu(A[M x 2048] * W1t^T + b1) -> bf16 hbuf.
// Invalid blocks pack W2 f32->bf16^T into wt2. Pack transpose tile now
// stride-73 (odd-dword -> ~4-way max bank aliasing vs 16-way at 72) and
// double-buffered (1 barrier per tile instead of 2).
// =======================================================================
__global__ __launch_bounds__(512, 2) void g1k(
    const unsigned short* __restrict__ Ash, const unsigned short* __restrict__ Art,
    const unsigned short* __restrict__ wt1,
    const float* __restrict__ bE, const float* __restrict__ bS,
    unsigned short* __restrict__ hout,
    const int* __restrict__ counts, const int* __restrict__ offs,
    int do_pack, const float* __restrict__ we_w2, const float* __restrict__ ws_w2,
    unsigned short* __restrict__ wt2) {
  constexpr int K = HD;
  constexpr int NBX = FF / 256;         // 32
  constexpr int NWG = NBX * 16;         // 512
  extern __shared__ unsigned short smem[];

  const int e = blockIdx.z;
  int M;
  const unsigned short* A;
  const float* bias;
  int hbase;
  if (e < NE) {
    M = counts[e];
    A = Art + (size_t)offs[e] * K;
    bias = bE + (size_t)e * FF;
    hbase = offs[e];
  } else {
    M = TOKENS;
    A = Ash;
    bias = bS + (size_t)(e - NE) * FF;
    hbase = 2 * TOKENS + (e - NE) * TOKENS;
  }
  const unsigned short* Bt = wt1 + (size_t)e * HD * FF;

  int flat = blockIdx.x + NBX * blockIdx.y;
  flat = (flat & 7) * (NWG >> 3) + (flat >> 3);
  const int m0 = (flat & 15) * 256;
  const int n0 = (flat >> 4) * 256;
  const int tid = threadIdx.x;

  if (m0 >= M) {
    if (!do_pack) return;
    int total = 0, prefix = 0;
    for (int e2 = 0; e2 < NE; ++e2) {
      int mb = (counts[e2] + 255) >> 8; if (mb > 16) mb = 16;
      const int inv = 32 * (16 - mb);
      if (e2 < e) prefix += inv;
      total += inv;
    }
    int mb_e = (counts[e] + 255) >> 8; if (mb_e > 16) mb_e = 16;
    const int m_idx = flat & 15, n_idx = flat >> 4;
    const int rank = prefix + n_idx * (16 - mb_e) + (m_idx - mb_e);
    // double-buffered stride-73 transpose tiles
    unsigned short* ps = smem;  // [2][64][73] = 18,688 B
    const int NT = 10 * 128 * 32;
    int it = 0;
    for (int i = rank; i < NT; i += total, ++it) {
      const int e2 = i >> 12;
      const int rem = i & 4095;
      const int ktt = rem >> 5;
      const int ntt = rem & 31;
      const float* src = (e2 < NE) ? (we_w2 + (size_t)e2 * FF * HD)
                                   : (ws_w2 + (size_t)(e2 - NE) * FF * HD);
      unsigned short* dst = wt2 + (size_t)e2 * HD * FF;
      unsigned short* pb = ps + (it & 1) * (64 * 73);
      {
        const int kk = tid >> 3, cc = (tid & 7) * 8;
        const float* sp = src + (size_t)(ktt * 64 + kk) * HD + ntt * 64 + cc;
        const float4 v0 = *(const float4*)sp;
        const float4 v1 = *(const float4*)(sp + 4);
        unsigned short* tp = pb + kk * 73 + cc;
        tp[0] = f2bf(v0.x); tp[1] = f2bf(v0.y); tp[2] = f2bf(v0.z); tp[3] = f2bf(v0.w);
        tp[4] = f2bf(v1.x); tp[5] = f2bf(v1.y); tp[6] = f2bf(v1.z); tp[7] = f2bf(v1.w);
      }
      __syncthreads();   // pb filled; other buffer's last write-phase is >=1 sync old
      {
        const int nn = tid >> 3, kc = (tid & 7) * 8;
        unsigned u[4];
#pragma unroll
        for (int j = 0; j < 4; ++j)
          u[j] = (unsigned)pb[(kc + 2 * j) * 73 + nn] |
                 ((unsigned)pb[(kc + 2 * j + 1) * 73 + nn] << 16);
        uint4 v; v.x = u[0]; v.y = u[1]; v.z = u[2]; v.w = u[3];
        *(uint4*)(dst + (size_t)(ntt * 64 + nn) * FF + ktt * 64 + kc) = v;
      }
    }
    return;
  }

  const int wid = tid >> 6, ln = tid & 63;
  const int wr = wid >> 2, wc = wid & 3;
  const int fr = ln & 15, fq = ln >> 4;
  const int swz = fr & 7;
  const int lr8 = ln >> 3;
  const int lc8 = ln & 7;
  const int scol = (lc8 ^ lr8) << 3;
  const int wrA = wr * 128 + wc * 16;
  const int wcB = wc * 64 + wr * 16;

  f32x4 acc[8][4];
#pragma unroll
  for (int i = 0; i < 8; ++i)
#pragma unroll
    for (int j = 0; j < 4; ++j) acc[i][j] = (f32x4){0.f, 0.f, 0.f, 0.f};

  kloop<K>(A, Bt, smem, m0, n0, acc, wr, wc, fr, fq, swz, wrA, wcB, lr8, lc8, scol);

#pragma unroll
  for (int nn = 0; nn < 4; ++nn) {
#pragma unroll
    for (int mm = 0; mm < 8; ++mm) {
      const int col = n0 + wc * 64 + (nn >> 1) * 32 + (nn & 1) * 16 + fr;
      const float bb = bias[col];
#pragma unroll
      for (int j = 0; j < 4; ++j) {
        const int r = m0 + wr * 128 + (mm >> 2) * 64 + (mm & 3) * 16 + fq * 4 + j;
        if (r < M) {
          float v = acc[mm][nn][j] + bb;
          v = v > 0.f ? v : 0.f;
          hout[(size_t)(hbase + r) * FF + col] = f2bf(v);
        }
      }
    }
  }
}

// =======================================================================
// GEMM2: ybuf[row] = h * W2t^T + b2  (f32, no gate, no atomics; z=10).
// =======================================================================
__global__ __launch_bounds__(512, 2) void g2k(
    const unsigned short* __restrict__ hbuf, const unsigned short* __restrict__ wt2,
    const float* __restrict__ bE, const float* __restrict__ bS,
    float* __restrict__ ybuf,
    const int* __restrict__ counts, const int* __restrict__ offs) {
  constexpr int K = FF;
  constexpr int NBX = HD / 256;         // 8
  constexpr int NWG = NBX * 16;         // 128
  extern __shared__ unsigned short smem[];

  const int e = blockIdx.z;
  int M;
  const unsigned short* A;
  const float* bias;
  int hbase;
  if (e < NE) {
    M = counts[e];
    A = hbuf + (size_t)offs[e] * K;
    bias = bE + (size_t)e * HD;
    hbase = offs[e];
  } else {
    M = TOKENS;
    hbase = 2 * TOKENS + (e - NE) * TOKENS;
    A = hbuf + (size_t)hbase * K;
    bias = bS + (size_t)(e - NE) * HD;
  }
  const unsigned short* Bt = wt2 + (size_t)e * HD * FF;

  int flat = blockIdx.x + NBX * blockIdx.y;
  flat = (flat & 7) * (NWG >> 3) + (flat >> 3);
  const int m0 = (flat & 15) * 256;
  const int n0 = (flat >> 4) * 256;
  if (m0 >= M) return;

  const int tid = threadIdx.x;
  const int wid = tid >> 6, ln = tid & 63;
  const int wr = wid >> 2, wc = wid & 3;
  const int fr = ln & 15, fq = ln >> 4;
  const int swz = fr & 7;
  const int lr8 = ln >> 3;
  const int lc8 = ln & 7;
  const int scol = (lc8 ^ lr8) << 3;
  const int wrA = wr * 128 + wc * 16;
  const int wcB = wc * 64 + wr * 16;

  f32x4 acc[8][4];
#pragma unroll
  for (int i = 0; i < 8; ++i)
#pragma unroll
    for (int j = 0; j < 4; ++j) acc[i][j] = (f32x4){0.f, 0.f, 0.f, 0.f};

  kloop<K>(A, Bt, smem, m0, n0, acc, wr, wc, fr, fq, swz, wrA, wcB, lr8, lc8, scol);

#pragma unroll
  for (int nn = 0; nn < 4; ++nn) {
#pragma unroll
    for (int mm = 0; mm < 8; ++mm) {
      const int colw = wc * 64 + (nn >> 1) * 32 + (nn & 1) * 16 + fr;
      const float bb = bias[n0 + colw];
#pragma unroll
      for (int j = 0; j < 4; ++j) {
        const int r = m0 + wr * 128 + (mm >> 2) * 64 + (mm & 3) * 16 + fq * 4 + j;
        if (r < M)
          ybuf[(size_t)(hbase + r) * HD + n0 + colw] = acc[mm][nn][j] + bb;
      }
    }
  }
}

// ---------------- final reduce: out = ysh0+ysh1+g0*ye0+g1*ye1 ----------------
__global__ __launch_bounds__(256) void reduce_kernel(
    const float* __restrict__ ybuf, const int* __restrict__ row_of,
    const float* __restrict__ topv, float* __restrict__ out) {
  const int t = blockIdx.x;
  const int d = threadIdx.x * 8;
  const float g0 = topv[2 * t], g1 = topv[2 * t + 1];
  const float* y0 = ybuf + (size_t)row_of[2 * t] * HD + d;
  const float* y1 = ybuf + (size_t)row_of[2 * t + 1] * HD + d;
  const float* s0 = ybuf + (size_t)(2 * TOKENS + t) * HD + d;
  const float* s1 = ybuf + (size_t)(3 * TOKENS + t) * HD + d;
  float* o = out + (size_t)t * HD + d;
#pragma unroll
  for (int q = 0; q < 2; ++q) {
    const float4 a = *(const float4*)(s0 + q * 4);
    const float4 b = *(const float4*)(s1 + q * 4);
    const float4 c = *(const float4*)(y0 + q * 4);
    const float4 e = *(const float4*)(y1 + q * 4);
    float4 r;
    r.x = a.x + b.x + g0 * c.x + g1 * e.x;
    r.y = a.y + b.y + g0 * c.y + g1 * e.y;
    r.z = a.z + b.z + g0 * c.z + g1 * e.z;
    r.w = a.w + b.w + g0 * c.w + g1 * e.w;
    *(float4*)(o + q * 4) = r;
  }
}

extern "C" void kernel_launch(void* const* d_in, const int* in_sizes, int n_in,
                              void* d_out, int out_size, void* d_ws, size_t ws_size,
                              hipStream_t stream) {
  const float* x     = (const float*)d_in[0];
  const float* ws_w1 = (const float*)d_in[1];
  const float* ws_b1 = (const float*)d_in[2];
  const float* ws_w2 = (const float*)d_in[3];
  const float* ws_b2 = (const float*)d_in[4];
  const float* we_w1 = (const float*)d_in[5];
  const float* we_b1 = (const float*)d_in[6];
  const float* we_w2 = (const float*)d_in[7];
  const float* we_b2 = (const float*)d_in[8];
  const float* wg    = (const float*)d_in[9];

  float* out = (float*)d_out;
  float* logits = out + (size_t)TOKENS * HD;

  hipFuncSetAttribute(reinterpret_cast<const void*>(g1k),
                      hipFuncAttributeMaxDynamicSharedMemorySize, 131072);
  hipFuncSetAttribute(reinterpret_cast<const void*>(g2k),
                      hipFuncAttributeMaxDynamicSharedMemorySize, 131072);

  char* ws = (char*)d_ws;
  unsigned short* wt1  = (unsigned short*)ws;                   // 335,544,320
  unsigned short* wt2  = (unsigned short*)(ws + 335544320);     // 335,544,320
  unsigned short* xb   = (unsigned short*)(ws + 671088640);     //  16,777,216
  unsigned short* xg   = (unsigned short*)(ws + 687865856);     //  34,078,720
  unsigned short* hbuf = (unsigned short*)(ws + 721944576);     // 268,435,456
  char* ctrl = ws + 990380032;
  float* ybuf = (float*)ws;                                     // alias wt1 (dead by GEMM2)
  int*   row_token = (int*)(ctrl);
  float* row_gate  = (float*)(ctrl + 32768);
  int*   topi      = (int*)(ctrl + 65536);
  float* topv      = (float*)(ctrl + 98304);
  int*   counts    = (int*)(ctrl + 131072);
  int*   offs      = (int*)(ctrl + 131104);
  int*   cursors   = (int*)(ctrl + 131136);
  int*   row_of    = (int*)(ctrl + 131168);

  hipMemsetAsync(counts, 0, NE * sizeof(int), stream);
  cast_x_kernel<<<8192, 256, 0, stream>>>(x, xb);
  router_kernel<<<1024, 256, 0, stream>>>(x, wg, logits, topi, topv, counts);
  offs_kernel<<<1, 64, 0, stream>>>(counts, offs, cursors);
  gather_kernel<<<1024, 256, 0, stream>>>(xb, topi, topv, cursors, xg,
                                          row_token, row_gate, row_of);
  pack_wt<HD, FF><<<dim3(FF / 64, HD / 64, 10), 256, 0, stream>>>(we_w1, ws_w1, wt1);
  g1k<<<dim3(32, 16, 10), 512, 131072, stream>>>(
      xb, xg, wt1, we_b1, ws_b1, hbuf, counts, offs, 1, we_w2, ws_w2, wt2);
  g2k<<<dim3(8, 16, 10), 512, 131072, stream>>>(
      hbuf, wt2, we_b2, ws_b2, ybuf, counts, offs);
  reduce_kernel<<<TOKENS, 256, 0, stream>>>(ybuf, row_of, topv, out);

  (void)in_sizes; (void)n_in; (void)out_size; (void)ws_size;
}

// Round 12
// 1867.228 us; speedup vs baseline: 1.1121x; 1.0043x over previous
//
#include <hip/hip_runtime.h>

#define TOKENS 4096
#define HD 2048
#define FF 8192
#define NE 8
#define NS 2
#define YHALF 33554432  // 16384 * 2048 floats per K-split half

typedef __attribute__((ext_vector_type(8))) short bf16x8;
typedef __attribute__((ext_vector_type(4))) float f32x4;

__device__ __forceinline__ unsigned rnd_bf(unsigned u) {
  return u + 0x7fffu + ((u >> 16) & 1u);
}
__device__ __forceinline__ unsigned short f2bf(float f) {
  unsigned u = __builtin_bit_cast(unsigned, f);
  return (unsigned short)(rnd_bf(u) >> 16);
}

#define GLDS16(gp, lp)                                                         \
  __builtin_amdgcn_global_load_lds(                                            \
      (const __attribute__((address_space(1))) unsigned*)(const void*)(gp),    \
      (__attribute__((address_space(3))) unsigned*)(lp), 16, 0, 0)

// ---------------- cast x f32 -> bf16 ----------------
__global__ void cast_x_kernel(const float* __restrict__ x, unsigned short* __restrict__ xb) {
  const size_t i = ((size_t)blockIdx.x * 256 + threadIdx.x) * 4;
  float4 v = *(const float4*)(x + i);
  ushort4 o;
  o.x = f2bf(v.x); o.y = f2bf(v.y); o.z = f2bf(v.z); o.w = f2bf(v.w);
  *(ushort4*)(xb + i) = o;
}

// ---------------- router ----------------
__global__ void router_kernel(const float* __restrict__ x, const float* __restrict__ wg,
                              float* __restrict__ logits_out, int* __restrict__ topi,
                              float* __restrict__ topv, int* __restrict__ counts) {
  const int wave = threadIdx.x >> 6, lane = threadIdx.x & 63;
  const int t = blockIdx.x * 4 + wave;
  const float* xr = x + (size_t)t * HD;
  float acc[8];
#pragma unroll
  for (int e = 0; e < 8; ++e) acc[e] = 0.f;
  for (int d = lane; d < HD; d += 64) {
    const float xv = xr[d];
    const float4 w0 = *(const float4*)(wg + (size_t)d * 8);
    const float4 w1 = *(const float4*)(wg + (size_t)d * 8 + 4);
    acc[0] += xv * w0.x; acc[1] += xv * w0.y; acc[2] += xv * w0.z; acc[3] += xv * w0.w;
    acc[4] += xv * w1.x; acc[5] += xv * w1.y; acc[6] += xv * w1.z; acc[7] += xv * w1.w;
  }
#pragma unroll
  for (int e = 0; e < 8; ++e) {
#pragma unroll
    for (int off = 32; off > 0; off >>= 1) acc[e] += __shfl_xor(acc[e], off);
  }
  if (lane == 0) {
    *(float4*)(logits_out + (size_t)t * 8)     = make_float4(acc[0], acc[1], acc[2], acc[3]);
    *(float4*)(logits_out + (size_t)t * 8 + 4) = make_float4(acc[4], acc[5], acc[6], acc[7]);
    float mx = acc[0];
#pragma unroll
    for (int e = 1; e < 8; ++e) mx = fmaxf(mx, acc[e]);
    float p[8], s = 0.f;
#pragma unroll
    for (int e = 0; e < 8; ++e) { p[e] = expf(acc[e] - mx); s += p[e]; }
    const float inv = 1.f / s;
    int i1 = 0;
#pragma unroll
    for (int e = 1; e < 8; ++e) if (acc[e] > acc[i1]) i1 = e;
    int i2 = (i1 == 0) ? 1 : 0;
#pragma unroll
    for (int e = 0; e < 8; ++e) if (e != i1 && acc[e] > acc[i2]) i2 = e;
    topi[2 * t]     = i1; topv[2 * t]     = p[i1] * inv;
    topi[2 * t + 1] = i2; topv[2 * t + 1] = p[i2] * inv;
    atomicAdd(&counts[i1], 1);
    atomicAdd(&counts[i2], 1);
  }
}

__global__ void offs_kernel(const int* __restrict__ counts, int* __restrict__ offs,
                            int* __restrict__ cursors) {
  if (threadIdx.x == 0) {
    int r = 0;
    for (int e = 0; e < NE; ++e) { offs[e] = r; cursors[e] = r; r += counts[e]; }
  }
}

__global__ void gather_kernel(const unsigned short* __restrict__ xb,
                              const int* __restrict__ topi, const float* __restrict__ topv,
                              int* __restrict__ cursors, unsigned short* __restrict__ xg,
                              int* __restrict__ row_token, float* __restrict__ row_gate,
                              int* __restrict__ row_of) {
  const int wave = threadIdx.x >> 6, lane = threadIdx.x & 63;
  const int t = blockIdx.x * 4 + wave;
  const uint4* src = (const uint4*)(xb + (size_t)t * HD);
#pragma unroll
  for (int j = 0; j < 2; ++j) {
    const int e = topi[2 * t + j];
    int pos = 0;
    if (lane == 0) {
      pos = atomicAdd(&cursors[e], 1);
      row_token[pos] = t;
      row_gate[pos] = topv[2 * t + j];
      row_of[2 * t + j] = pos;
    }
    pos = __shfl(pos, 0);
    uint4* dst = (uint4*)(xg + (size_t)pos * HD);
#pragma unroll
    for (int c = lane; c < 256; c += 64) dst[c] = src[c];
  }
}

// ---------------- standalone pack: f32 [K][N] -> bf16 B^T [N][K] ----------------
template <int K, int N>
__global__ __launch_bounds__(256) void pack_wt(const float* __restrict__ we,
                                               const float* __restrict__ ws,
                                               unsigned short* __restrict__ dstw) {
  const int e = blockIdx.z;
  const float* src = (e < NE) ? (we + (size_t)e * K * N) : (ws + (size_t)(e - NE) * K * N);
  unsigned short* dst = dstw + (size_t)e * K * N;
  const int nt = blockIdx.x * 64;
  const int kt = blockIdx.y * 64;
  __shared__ unsigned short t[64][73];
  const int tid = threadIdx.x;
  const int rr = tid >> 4, cc = (tid & 15) * 4;
#pragma unroll
  for (int i = 0; i < 4; ++i) {
    const int k = rr + i * 16;
    float4 v = *(const float4*)(src + (size_t)(kt + k) * N + nt + cc);
    t[k][cc + 0] = f2bf(v.x);
    t[k][cc + 1] = f2bf(v.y);
    t[k][cc + 2] = f2bf(v.z);
    t[k][cc + 3] = f2bf(v.w);
  }
  __syncthreads();
  const int nr = tid >> 2, kc = (tid & 3) * 16;
  unsigned u[8];
#pragma unroll
  for (int j = 0; j < 8; ++j)
    u[j] = (unsigned)t[kc + 2 * j][nr] | ((unsigned)t[kc + 2 * j + 1][nr] << 16);
  unsigned short* dp = dst + (size_t)(nt + nr) * K + kt + kc;
  uint4 v0; v0.x = u[0]; v0.y = u[1]; v0.z = u[2]; v0.w = u[3];
  uint4 v1; v1.x = u[4]; v1.y = u[5]; v1.z = u[6]; v1.w = u[7];
  *(uint4*)dp = v0;
  *(uint4*)(dp + 8) = v1;
}

// ---------------- frag read / mfma helpers ----------
template <int MS>
__device__ __forceinline__ void rd_a(bf16x8 (&d)[8], const unsigned short* base,
                                     int wr, int fr, int fq, int swz) {
#pragma unroll
  for (int mi = 0; mi < 4; ++mi)
#pragma unroll
    for (int ks = 0; ks < 2; ++ks)
      d[mi * 2 + ks] = *(const bf16x8*)(base + (wr * 128 + MS * 64 + mi * 16 + fr) * 64 +
                                        (((ks * 4 + fq) ^ swz) << 3));
}
template <int NSUB>
__device__ __forceinline__ void rd_b(bf16x8 (&d)[4], const unsigned short* base,
                                     int wc, int fr, int fq, int swz) {
#pragma unroll
  for (int ni = 0; ni < 2; ++ni)
#pragma unroll
    for (int ks = 0; ks < 2; ++ks)
      d[ni * 2 + ks] = *(const bf16x8*)(base + (wc * 64 + NSUB * 32 + ni * 16 + fr) * 64 +
                                        (((ks * 4 + fq) ^ swz) << 3));
}
template <int MS, int NSUB>
__device__ __forceinline__ void mm16(f32x4 (&acc)[8][4], const bf16x8 (&a)[8],
                                     const bf16x8 (&b)[4]) {
  __builtin_amdgcn_s_setprio(1);
#pragma unroll
  for (int mi = 0; mi < 4; ++mi)
#pragma unroll
    for (int ni = 0; ni < 2; ++ni)
#pragma unroll
      for (int ks = 0; ks < 2; ++ks)
        acc[MS * 4 + mi][NSUB * 2 + ni] = __builtin_amdgcn_mfma_f32_16x16x32_bf16(
            a[mi * 2 + ks], b[ni * 2 + ks], acc[MS * 4 + mi][NSUB * 2 + ni], 0, 0, 0);
  __builtin_amdgcn_s_setprio(0);
}

// =======================================================================
// Register-pipelined K-loop (R10 schedule) with K-window [kt0, kt0+nkt).
// =======================================================================
template <int K>
__device__ __forceinline__ void kloop(
    const unsigned short* __restrict__ A, const unsigned short* __restrict__ Bt,
    unsigned short* smem, int m0, int n0, f32x4 (&acc)[8][4],
    int wr, int wc, int fr, int fq, int swz,
    int wrA, int wcB, int lr8, int lc8, int scol, int kt0, int nkt) {
#define SAK(s, kt, b)                                                          \
  { const int r0_ = wrA + (s) * 64 + lr8;                                      \
    const unsigned short* s_ = A + (size_t)(m0 + r0_) * K + (kt) * 64 + scol;  \
    unsigned short* d_ = smem + (b) * 32768 + r0_ * 64 + lc8 * 8;              \
    GLDS16(s_, d_); GLDS16(s_ + (size_t)8 * K, d_ + 8 * 64); }
#define SBK(s, kt, b)                                                          \
  { const int r0_ = wcB + (s) * 32 + lr8;                                      \
    const unsigned short* s_ = Bt + (size_t)(n0 + r0_) * K + (kt) * 64 + scol; \
    unsigned short* d_ = smem + (b) * 32768 + 16384 + r0_ * 64 + lc8 * 8;      \
    GLDS16(s_, d_); GLDS16(s_ + (size_t)8 * K, d_ + 8 * 64); }

  SAK(0, kt0, 0); SAK(1, kt0, 0); SBK(0, kt0, 0); SBK(1, kt0, 0);
  SAK(0, kt0 + 1, 1); SAK(1, kt0 + 1, 1); SBK(0, kt0 + 1, 1); SBK(1, kt0 + 1, 1);
  asm volatile("s_waitcnt vmcnt(8)" ::: "memory");
  __builtin_amdgcn_s_barrier();

  bf16x8 a0[8], a1[8], b0[4], b1[4];
  rd_a<0>(a0, smem, wr, fr, fq, swz);
  rd_b<0>(b0, smem + 16384, wc, fr, fq, swz);

  for (int t = 0; t < nkt; ++t) {
    const int cur = t & 1;
    const int tp2 = kt0 + ((t + 2 < nkt) ? t + 2 : t);
    const unsigned short* As_c = smem + cur * 32768;
    const unsigned short* Bs_c = As_c + 16384;
    const unsigned short* As_n = smem + (cur ^ 1) * 32768;
    const unsigned short* Bs_n = As_n + 16384;
    // ---- ph0 ----
    rd_b<1>(b1, Bs_c, wc, fr, fq, swz);
    mm16<0, 0>(acc, a0, b0);
    // ---- ph1 ----
    rd_a<1>(a1, As_c, wr, fr, fq, swz);
    mm16<0, 1>(acc, a0, b1);
    asm volatile("s_waitcnt lgkmcnt(0)" ::: "memory");
    __builtin_amdgcn_s_barrier();
    __builtin_amdgcn_sched_barrier(0);
    // ---- ph2 ----
    SAK(0, tp2, cur); SBK(0, tp2, cur);
    mm16<1, 0>(acc, a1, b0);
    asm volatile("s_waitcnt vmcnt(4)" ::: "memory");
    __builtin_amdgcn_s_barrier();
    __builtin_amdgcn_sched_barrier(0);
    rd_a<0>(a0, As_n, wr, fr, fq, swz);
    rd_b<0>(b0, Bs_n, wc, fr, fq, swz);
    // ---- ph3 ----
    SAK(1, tp2, cur); SBK(1, tp2, cur);
    mm16<1, 1>(acc, a1, b1);
  }
#undef SAK
#undef SBK
}

// =======================================================================
// GEMM1: h = relu(A[M x 2048] * W1t^T + b1) -> bf16 hbuf.
// Invalid blocks pack W2 f32->bf16^T into wt2, with reg-staged prefetch of
// the NEXT tile's f32 before the current tile's transpose (hides ~900cyc
// HBM latency under transpose+store; double LDS buffer, 1 sync/tile).
// =======================================================================
__global__ __launch_bounds__(512, 2) void g1k(
    const unsigned short* __restrict__ Ash, const unsigned short* __restrict__ Art,
    const unsigned short* __restrict__ wt1,
    const float* __restrict__ bE, const float* __restrict__ bS,
    unsigned short* __restrict__ hout,
    const int* __restrict__ counts, const int* __restrict__ offs,
    int do_pack, const float* __restrict__ we_w2, const float* __restrict__ ws_w2,
    unsigned short* __restrict__ wt2) {
  constexpr int K = HD;
  constexpr int NBX = FF / 256;         // 32
  constexpr int NWG = NBX * 16;         // 512
  extern __shared__ unsigned short smem[];

  const int e = blockIdx.z;
  int M;
  const unsigned short* A;
  const float* bias;
  int hbase;
  if (e < NE) {
    M = counts[e];
    A = Art + (size_t)offs[e] * K;
    bias = bE + (size_t)e * FF;
    hbase = offs[e];
  } else {
    M = TOKENS;
    A = Ash;
    bias = bS + (size_t)(e - NE) * FF;
    hbase = 2 * TOKENS + (e - NE) * TOKENS;
  }
  const unsigned short* Bt = wt1 + (size_t)e * HD * FF;

  int flat = blockIdx.x + NBX * blockIdx.y;
  flat = (flat & 7) * (NWG >> 3) + (flat >> 3);
  const int m0 = (flat & 15) * 256;
  const int n0 = (flat >> 4) * 256;
  const int tid = threadIdx.x;

  if (m0 >= M) {
    if (!do_pack) return;
    int total = 0, prefix = 0;
    for (int e2 = 0; e2 < NE; ++e2) {
      int mb = (counts[e2] + 255) >> 8; if (mb > 16) mb = 16;
      const int inv = 32 * (16 - mb);
      if (e2 < e) prefix += inv;
      total += inv;
    }
    int mb_e = (counts[e] + 255) >> 8; if (mb_e > 16) mb_e = 16;
    const int m_idx = flat & 15, n_idx = flat >> 4;
    const int rank = prefix + n_idx * (16 - mb_e) + (m_idx - mb_e);
    unsigned short* ps = smem;  // [2][64][73]
    const int NT = 10 * 128 * 32;
    const int kk = tid >> 3, cc = (tid & 7) * 8;   // load coords
    // prefetch tile(rank) into regs
    float4 r0a, r0b;
    int i = rank;
    if (i < NT) {
      const int e2 = i >> 12, rem = i & 4095, ktt = rem >> 5, ntt = rem & 31;
      const float* src = (e2 < NE) ? (we_w2 + (size_t)e2 * FF * HD)
                                   : (ws_w2 + (size_t)(e2 - NE) * FF * HD);
      const float* sp = src + (size_t)(ktt * 64 + kk) * HD + ntt * 64 + cc;
      r0a = *(const float4*)sp; r0b = *(const float4*)(sp + 4);
    }
    int it = 0;
    while (i < NT) {
      const int inext = i + total;
      float4 r1a, r1b;
      if (inext < NT) {  // issue next tile's loads early (latency hidden)
        const int e2 = inext >> 12, rem = inext & 4095, ktt = rem >> 5, ntt = rem & 31;
        const float* src = (e2 < NE) ? (we_w2 + (size_t)e2 * FF * HD)
                                     : (ws_w2 + (size_t)(e2 - NE) * FF * HD);
        const float* sp = src + (size_t)(ktt * 64 + kk) * HD + ntt * 64 + cc;
        r1a = *(const float4*)sp; r1b = *(const float4*)(sp + 4);
      }
      // write current tile -> LDS (cvt f32->bf16)
      unsigned short* pb = ps + (it & 1) * (64 * 73);
      {
        unsigned short* tp = pb + kk * 73 + cc;
        tp[0] = f2bf(r0a.x); tp[1] = f2bf(r0a.y); tp[2] = f2bf(r0a.z); tp[3] = f2bf(r0a.w);
        tp[4] = f2bf(r0b.x); tp[5] = f2bf(r0b.y); tp[6] = f2bf(r0b.z); tp[7] = f2bf(r0b.w);
      }
      __syncthreads();
      // transposed read -> global store for tile i
      {
        const int e2 = i >> 12, rem = i & 4095, ktt = rem >> 5, ntt = rem & 31;
        unsigned short* dst = wt2 + (size_t)e2 * HD * FF;
        const int nn = tid >> 3, kc = (tid & 7) * 8;
        unsigned u[4];
#pragma unroll
        for (int j = 0; j < 4; ++j)
          u[j] = (unsigned)pb[(kc + 2 * j) * 73 + nn] |
                 ((unsigned)pb[(kc + 2 * j + 1) * 73 + nn] << 16);
        uint4 v; v.x = u[0]; v.y = u[1]; v.z = u[2]; v.w = u[3];
        *(uint4*)(dst + (size_t)(ntt * 64 + nn) * FF + ktt * 64 + kc) = v;
      }
      r0a = r1a; r0b = r1b;
      i = inext; ++it;
    }
    return;
  }

  const int wid = tid >> 6, ln = tid & 63;
  const int wr = wid >> 2, wc = wid & 3;
  const int fr = ln & 15, fq = ln >> 4;
  const int swz = fr & 7;
  const int lr8 = ln >> 3;
  const int lc8 = ln & 7;
  const int scol = (lc8 ^ lr8) << 3;
  const int wrA = wr * 128 + wc * 16;
  const int wcB = wc * 64 + wr * 16;

  f32x4 acc[8][4];
#pragma unroll
  for (int i = 0; i < 8; ++i)
#pragma unroll
    for (int j = 0; j < 4; ++j) acc[i][j] = (f32x4){0.f, 0.f, 0.f, 0.f};

  kloop<K>(A, Bt, smem, m0, n0, acc, wr, wc, fr, fq, swz, wrA, wcB, lr8, lc8, scol,
           0, K / 64);

#pragma unroll
  for (int nn = 0; nn < 4; ++nn) {
#pragma unroll
    for (int mm = 0; mm < 8; ++mm) {
      const int col = n0 + wc * 64 + (nn >> 1) * 32 + (nn & 1) * 16 + fr;
      const float bb = bias[col];
#pragma unroll
      for (int j = 0; j < 4; ++j) {
        const int r = m0 + wr * 128 + (mm >> 2) * 64 + (mm & 3) * 16 + fq * 4 + j;
        if (r < M) {
          float v = acc[mm][nn][j] + bb;
          v = v > 0.f ? v : 0.f;
          hout[(size_t)(hbase + r) * FF + col] = f2bf(v);
        }
      }
    }
  }
}

// =======================================================================
// GEMM2 (K-split x2): ybuf[half][row] = h * W2t^T (+ b2 in half 0).
// z = 0..19: e = z % 10, half = z / 10; each half does 64 K-tiles.
// =======================================================================
__global__ __launch_bounds__(512, 2) void g2k(
    const unsigned short* __restrict__ hbuf, const unsigned short* __restrict__ wt2,
    const float* __restrict__ bE, const float* __restrict__ bS,
    float* __restrict__ ybuf,
    const int* __restrict__ counts, const int* __restrict__ offs) {
  constexpr int K = FF;
  constexpr int NBX = HD / 256;         // 8
  constexpr int NWG = NBX * 16;         // 128
  extern __shared__ unsigned short smem[];

  const int z = blockIdx.z;
  const int e = (z < 10) ? z : z - 10;
  const int half = (z < 10) ? 0 : 1;
  int M;
  const unsigned short* A;
  const float* bias;
  int hbase;
  if (e < NE) {
    M = counts[e];
    A = hbuf + (size_t)offs[e] * K;
    bias = bE + (size_t)e * HD;
    hbase = offs[e];
  } else {
    M = TOKENS;
    hbase = 2 * TOKENS + (e - NE) * TOKENS;
    A = hbuf + (size_t)hbase * K;
    bias = bS + (size_t)(e - NE) * HD;
  }
  const unsigned short* Bt = wt2 + (size_t)e * HD * FF;
  float* yout = ybuf + (size_t)half * YHALF;

  int flat = blockIdx.x + NBX * blockIdx.y;
  flat = (flat & 7) * (NWG >> 3) + (flat >> 3);
  const int m0 = (flat & 15) * 256;
  const int n0 = (flat >> 4) * 256;
  if (m0 >= M) return;

  const int tid = threadIdx.x;
  const int wid = tid >> 6, ln = tid & 63;
  const int wr = wid >> 2, wc = wid & 3;
  const int fr = ln & 15, fq = ln >> 4;
  const int swz = fr & 7;
  const int lr8 = ln >> 3;
  const int lc8 = ln & 7;
  const int scol = (lc8 ^ lr8) << 3;
  const int wrA = wr * 128 + wc * 16;
  const int wcB = wc * 64 + wr * 16;

  f32x4 acc[8][4];
#pragma unroll
  for (int i = 0; i < 8; ++i)
#pragma unroll
    for (int j = 0; j < 4; ++j) acc[i][j] = (f32x4){0.f, 0.f, 0.f, 0.f};

  kloop<K>(A, Bt, smem, m0, n0, acc, wr, wc, fr, fq, swz, wrA, wcB, lr8, lc8, scol,
           half * 64, 64);

#pragma unroll
  for (int nn = 0; nn < 4; ++nn) {
#pragma unroll
    for (int mm = 0; mm < 8; ++mm) {
      const int colw = wc * 64 + (nn >> 1) * 32 + (nn & 1) * 16 + fr;
      const float bb = (half == 0) ? bias[n0 + colw] : 0.f;
#pragma unroll
      for (int j = 0; j < 4; ++j) {
        const int r = m0 + wr * 128 + (mm >> 2) * 64 + (mm & 3) * 16 + fq * 4 + j;
        if (r < M)
          yout[(size_t)(hbase + r) * HD + n0 + colw] = acc[mm][nn][j] + bb;
      }
    }
  }
}

// ---------------- final reduce over both K-halves ----------------
__global__ __launch_bounds__(256) void reduce_kernel(
    const float* __restrict__ ybuf, const int* __restrict__ row_of,
    const float* __restrict__ topv, float* __restrict__ out) {
  const int t = blockIdx.x;
  const int d = threadIdx.x * 8;
  const float g0 = topv[2 * t], g1 = topv[2 * t + 1];
  const size_t r0 = (size_t)row_of[2 * t] * HD + d;
  const size_t r1 = (size_t)row_of[2 * t + 1] * HD + d;
  const size_t rs0 = (size_t)(2 * TOKENS + t) * HD + d;
  const size_t rs1 = (size_t)(3 * TOKENS + t) * HD + d;
  float* o = out + (size_t)t * HD + d;
#pragma unroll
  for (int q = 0; q < 2; ++q) {
    float4 r = {0.f, 0.f, 0.f, 0.f};
#pragma unroll
    for (int h = 0; h < 2; ++h) {
      const float* yb = ybuf + (size_t)h * YHALF;
      const float4 a = *(const float4*)(yb + rs0 + q * 4);
      const float4 b = *(const float4*)(yb + rs1 + q * 4);
      const float4 c = *(const float4*)(yb + r0 + q * 4);
      const float4 ee = *(const float4*)(yb + r1 + q * 4);
      r.x += a.x + b.x + g0 * c.x + g1 * ee.x;
      r.y += a.y + b.y + g0 * c.y + g1 * ee.y;
      r.z += a.z + b.z + g0 * c.z + g1 * ee.z;
      r.w += a.w + b.w + g0 * c.w + g1 * ee.w;
    }
    *(float4*)(o + q * 4) = r;
  }
}

extern "C" void kernel_launch(void* const* d_in, const int* in_sizes, int n_in,
                              void* d_out, int out_size, void* d_ws, size_t ws_size,
                              hipStream_t stream) {
  const float* x     = (const float*)d_in[0];
  const float* ws_w1 = (const float*)d_in[1];
  const float* ws_b1 = (const float*)d_in[2];
  const float* ws_w2 = (const float*)d_in[3];
  const float* ws_b2 = (const float*)d_in[4];
  const float* we_w1 = (const float*)d_in[5];
  const float* we_b1 = (const float*)d_in[6];
  const float* we_w2 = (const float*)d_in[7];
  const float* we_b2 = (const float*)d_in[8];
  const float* wg    = (const float*)d_in[9];

  float* out = (float*)d_out;
  float* logits = out + (size_t)TOKENS * HD;

  hipFuncSetAttribute(reinterpret_cast<const void*>(g1k),
                      hipFuncAttributeMaxDynamicSharedMemorySize, 131072);
  hipFuncSetAttribute(reinterpret_cast<const void*>(g2k),
                      hipFuncAttributeMaxDynamicSharedMemorySize, 131072);

  char* ws = (char*)d_ws;
  unsigned short* wt1  = (unsigned short*)ws;                   // 335,544,320
  unsigned short* wt2  = (unsigned short*)(ws + 335544320);     // 335,544,320
  unsigned short* xb   = (unsigned short*)(ws + 671088640);     //  16,777,216
  unsigned short* xg   = (unsigned short*)(ws + 687865856);     //  34,078,720
  unsigned short* hbuf = (unsigned short*)(ws + 721944576);     // 268,435,456
  char* ctrl = ws + 990380032;
  float* ybuf = (float*)ws;   // alias wt1: 2 halves x 134,217,728 B = 268 MB < wt1
  int*   row_token = (int*)(ctrl);
  float* row_gate  = (float*)(ctrl + 32768);
  int*   topi      = (int*)(ctrl + 65536);
  float* topv      = (float*)(ctrl + 98304);
  int*   counts    = (int*)(ctrl + 131072);
  int*   offs      = (int*)(ctrl + 131104);
  int*   cursors   = (int*)(ctrl + 131136);
  int*   row_of    = (int*)(ctrl + 131168);

  hipMemsetAsync(counts, 0, NE * sizeof(int), stream);
  cast_x_kernel<<<8192, 256, 0, stream>>>(x, xb);
  router_kernel<<<1024, 256, 0, stream>>>(x, wg, logits, topi, topv, counts);
  offs_kernel<<<1, 64, 0, stream>>>(counts, offs, cursors);
  gather_kernel<<<1024, 256, 0, stream>>>(xb, topi, topv, cursors, xg,
                                          row_token, row_gate, row_of);
  pack_wt<HD, FF><<<dim3(FF / 64, HD / 64, 10), 256, 0, stream>>>(we_w1, ws_w1, wt1);
  g1k<<<dim3(32, 16, 10), 512, 131072, stream>>>(
      xb, xg, wt1, we_b1, ws_b1, hbuf, counts, offs, 1, we_w2, ws_w2, wt2);
  g2k<<<dim3(8, 16, 20), 512, 131072, stream>>>(
      hbuf, wt2, we_b2, ws_b2, ybuf, counts, offs);
  reduce_kernel<<<TOKENS, 256, 0, stream>>>(ybuf, row_of, topv, out);

  (void)in_sizes; (void)n_in; (void)out_size; (void)ws_size;
}

// Round 13
// 1860.686 us; speedup vs baseline: 1.1160x; 1.0035x over previous
//
#include <hip/hip_runtime.h>

#define TOKENS 4096
#define HD 2048
#define FF 8192
#define NE 8
#define NS 2

typedef __attribute__((ext_vector_type(8))) short bf16x8;
typedef __attribute__((ext_vector_type(4))) float f32x4;

__device__ __forceinline__ unsigned rnd_bf(unsigned u) {
  return u + 0x7fffu + ((u >> 16) & 1u);
}
__device__ __forceinline__ unsigned short f2bf(float f) {
  unsigned u = __builtin_bit_cast(unsigned, f);
  return (unsigned short)(rnd_bf(u) >> 16);
}

#define GLDS16(gp, lp)                                                         \
  __builtin_amdgcn_global_load_lds(                                            \
      (const __attribute__((address_space(1))) unsigned*)(const void*)(gp),    \
      (__attribute__((address_space(3))) unsigned*)(lp), 16, 0, 0)

// ---------------- router (fused: also emits xb bf16) ----------------
__global__ void router_kernel(const float* __restrict__ x, const float* __restrict__ wg,
                              float* __restrict__ logits_out, int* __restrict__ topi,
                              float* __restrict__ topv, int* __restrict__ counts,
                              unsigned short* __restrict__ xb) {
  const int wave = threadIdx.x >> 6, lane = threadIdx.x & 63;
  const int t = blockIdx.x * 4 + wave;
  const float* xr = x + (size_t)t * HD;
  unsigned short* xbr = xb + (size_t)t * HD;
  float acc[8];
#pragma unroll
  for (int e = 0; e < 8; ++e) acc[e] = 0.f;
  for (int d = lane; d < HD; d += 64) {
    const float xv = xr[d];
    xbr[d] = f2bf(xv);
    const float4 w0 = *(const float4*)(wg + (size_t)d * 8);
    const float4 w1 = *(const float4*)(wg + (size_t)d * 8 + 4);
    acc[0] += xv * w0.x; acc[1] += xv * w0.y; acc[2] += xv * w0.z; acc[3] += xv * w0.w;
    acc[4] += xv * w1.x; acc[5] += xv * w1.y; acc[6] += xv * w1.z; acc[7] += xv * w1.w;
  }
#pragma unroll
  for (int e = 0; e < 8; ++e) {
#pragma unroll
    for (int off = 32; off > 0; off >>= 1) acc[e] += __shfl_xor(acc[e], off);
  }
  if (lane == 0) {
    *(float4*)(logits_out + (size_t)t * 8)     = make_float4(acc[0], acc[1], acc[2], acc[3]);
    *(float4*)(logits_out + (size_t)t * 8 + 4) = make_float4(acc[4], acc[5], acc[6], acc[7]);
    float mx = acc[0];
#pragma unroll
    for (int e = 1; e < 8; ++e) mx = fmaxf(mx, acc[e]);
    float p[8], s = 0.f;
#pragma unroll
    for (int e = 0; e < 8; ++e) { p[e] = expf(acc[e] - mx); s += p[e]; }
    const float inv = 1.f / s;
    int i1 = 0;
#pragma unroll
    for (int e = 1; e < 8; ++e) if (acc[e] > acc[i1]) i1 = e;
    int i2 = (i1 == 0) ? 1 : 0;
#pragma unroll
    for (int e = 0; e < 8; ++e) if (e != i1 && acc[e] > acc[i2]) i2 = e;
    topi[2 * t]     = i1; topv[2 * t]     = p[i1] * inv;
    topi[2 * t + 1] = i2; topv[2 * t + 1] = p[i2] * inv;
    atomicAdd(&counts[i1], 1);
    atomicAdd(&counts[i2], 1);
  }
}

__global__ void offs_kernel(const int* __restrict__ counts, int* __restrict__ offs,
                            int* __restrict__ cursors) {
  if (threadIdx.x == 0) {
    int r = 0;
    for (int e = 0; e < NE; ++e) { offs[e] = r; cursors[e] = r; r += counts[e]; }
  }
}

__global__ void gather_kernel(const unsigned short* __restrict__ xb,
                              const int* __restrict__ topi, const float* __restrict__ topv,
                              int* __restrict__ cursors, unsigned short* __restrict__ xg,
                              int* __restrict__ row_token, float* __restrict__ row_gate,
                              int* __restrict__ row_of) {
  const int wave = threadIdx.x >> 6, lane = threadIdx.x & 63;
  const int t = blockIdx.x * 4 + wave;
  const uint4* src = (const uint4*)(xb + (size_t)t * HD);
#pragma unroll
  for (int j = 0; j < 2; ++j) {
    const int e = topi[2 * t + j];
    int pos = 0;
    if (lane == 0) {
      pos = atomicAdd(&cursors[e], 1);
      row_token[pos] = t;
      row_gate[pos] = topv[2 * t + j];
      row_of[2 * t + j] = pos;
    }
    pos = __shfl(pos, 0);
    uint4* dst = (uint4*)(xg + (size_t)pos * HD);
#pragma unroll
    for (int c = lane; c < 256; c += 64) dst[c] = src[c];
  }
}

// ---------------- standalone pack: f32 [K][N] -> bf16 B^T [N][K] ----------------
template <int K, int N>
__global__ __launch_bounds__(256) void pack_wt(const float* __restrict__ we,
                                               const float* __restrict__ ws,
                                               unsigned short* __restrict__ dstw) {
  const int e = blockIdx.z;
  const float* src = (e < NE) ? (we + (size_t)e * K * N) : (ws + (size_t)(e - NE) * K * N);
  unsigned short* dst = dstw + (size_t)e * K * N;
  const int nt = blockIdx.x * 64;
  const int kt = blockIdx.y * 64;
  __shared__ unsigned short t[64][73];
  const int tid = threadIdx.x;
  const int rr = tid >> 4, cc = (tid & 15) * 4;
#pragma unroll
  for (int i = 0; i < 4; ++i) {
    const int k = rr + i * 16;
    float4 v = *(const float4*)(src + (size_t)(kt + k) * N + nt + cc);
    t[k][cc + 0] = f2bf(v.x);
    t[k][cc + 1] = f2bf(v.y);
    t[k][cc + 2] = f2bf(v.z);
    t[k][cc + 3] = f2bf(v.w);
  }
  __syncthreads();
  const int nr = tid >> 2, kc = (tid & 3) * 16;
  unsigned u[8];
#pragma unroll
  for (int j = 0; j < 8; ++j)
    u[j] = (unsigned)t[kc + 2 * j][nr] | ((unsigned)t[kc + 2 * j + 1][nr] << 16);
  unsigned short* dp = dst + (size_t)(nt + nr) * K + kt + kc;
  uint4 v0; v0.x = u[0]; v0.y = u[1]; v0.z = u[2]; v0.w = u[3];
  uint4 v1; v1.x = u[4]; v1.y = u[5]; v1.z = u[6]; v1.w = u[7];
  *(uint4*)dp = v0;
  *(uint4*)(dp + 8) = v1;
}

// ---------------- frag read / mfma helpers ----------
template <int MS>
__device__ __forceinline__ void rd_a(bf16x8 (&d)[8], const unsigned short* base,
                                     int wr, int fr, int fq, int swz) {
#pragma unroll
  for (int mi = 0; mi < 4; ++mi)
#pragma unroll
    for (int ks = 0; ks < 2; ++ks)
      d[mi * 2 + ks] = *(const bf16x8*)(base + (wr * 128 + MS * 64 + mi * 16 + fr) * 64 +
                                        (((ks * 4 + fq) ^ swz) << 3));
}
template <int NSUB>
__device__ __forceinline__ void rd_b(bf16x8 (&d)[4], const unsigned short* base,
                                     int wc, int fr, int fq, int swz) {
#pragma unroll
  for (int ni = 0; ni < 2; ++ni)
#pragma unroll
    for (int ks = 0; ks < 2; ++ks)
      d[ni * 2 + ks] = *(const bf16x8*)(base + (wc * 64 + NSUB * 32 + ni * 16 + fr) * 64 +
                                        (((ks * 4 + fq) ^ swz) << 3));
}
template <int MS, int NSUB>
__device__ __forceinline__ void mm16(f32x4 (&acc)[8][4], const bf16x8 (&a)[8],
                                     const bf16x8 (&b)[4]) {
  __builtin_amdgcn_s_setprio(1);
#pragma unroll
  for (int mi = 0; mi < 4; ++mi)
#pragma unroll
    for (int ni = 0; ni < 2; ++ni)
#pragma unroll
      for (int ks = 0; ks < 2; ++ks)
        acc[MS * 4 + mi][NSUB * 2 + ni] = __builtin_amdgcn_mfma_f32_16x16x32_bf16(
            a[mi * 2 + ks], b[ni * 2 + ks], acc[MS * 4 + mi][NSUB * 2 + ni], 0, 0, 0);
  __builtin_amdgcn_s_setprio(0);
}

// =======================================================================
// Register-pipelined K-loop (R10 schedule) with dual-base K-concat support:
// K-tile kt >= ksw reads from (A2, Bt2) at kt-ksw (merged shared experts).
// =======================================================================
template <int K>
__device__ __forceinline__ void kloop(
    const unsigned short* __restrict__ A, const unsigned short* __restrict__ A2,
    const unsigned short* __restrict__ Bt, const unsigned short* __restrict__ Bt2,
    int ksw, unsigned short* smem, int m0, int n0, f32x4 (&acc)[8][4],
    int wr, int wc, int fr, int fq, int swz,
    int wrA, int wcB, int lr8, int lc8, int scol, int nkt) {
#define SAK(s, kt, b)                                                          \
  { int kl_ = (kt); const unsigned short* ab_ = A;                             \
    if (kl_ >= ksw) { ab_ = A2; kl_ -= ksw; }                                  \
    const int r0_ = wrA + (s) * 64 + lr8;                                      \
    const unsigned short* s_ = ab_ + (size_t)(m0 + r0_) * K + kl_ * 64 + scol; \
    unsigned short* d_ = smem + (b) * 32768 + r0_ * 64 + lc8 * 8;              \
    GLDS16(s_, d_); GLDS16(s_ + (size_t)8 * K, d_ + 8 * 64); }
#define SBK(s, kt, b)                                                          \
  { int kl_ = (kt); const unsigned short* bb_ = Bt;                            \
    if (kl_ >= ksw) { bb_ = Bt2; kl_ -= ksw; }                                 \
    const int r0_ = wcB + (s) * 32 + lr8;                                      \
    const unsigned short* s_ = bb_ + (size_t)(n0 + r0_) * K + kl_ * 64 + scol; \
    unsigned short* d_ = smem + (b) * 32768 + 16384 + r0_ * 64 + lc8 * 8;      \
    GLDS16(s_, d_); GLDS16(s_ + (size_t)8 * K, d_ + 8 * 64); }

  SAK(0, 0, 0); SAK(1, 0, 0); SBK(0, 0, 0); SBK(1, 0, 0);
  SAK(0, 1, 1); SAK(1, 1, 1); SBK(0, 1, 1); SBK(1, 1, 1);
  asm volatile("s_waitcnt vmcnt(8)" ::: "memory");
  __builtin_amdgcn_s_barrier();

  bf16x8 a0[8], a1[8], b0[4], b1[4];
  rd_a<0>(a0, smem, wr, fr, fq, swz);
  rd_b<0>(b0, smem + 16384, wc, fr, fq, swz);

  for (int t = 0; t < nkt; ++t) {
    const int cur = t & 1;
    const int tp2 = (t + 2 < nkt) ? t + 2 : t;
    const unsigned short* As_c = smem + cur * 32768;
    const unsigned short* Bs_c = As_c + 16384;
    const unsigned short* As_n = smem + (cur ^ 1) * 32768;
    const unsigned short* Bs_n = As_n + 16384;
    // ---- ph0 ----
    rd_b<1>(b1, Bs_c, wc, fr, fq, swz);
    mm16<0, 0>(acc, a0, b0);
    // ---- ph1 ----
    rd_a<1>(a1, As_c, wr, fr, fq, swz);
    mm16<0, 1>(acc, a0, b1);
    asm volatile("s_waitcnt lgkmcnt(0)" ::: "memory");
    __builtin_amdgcn_s_barrier();
    __builtin_amdgcn_sched_barrier(0);
    // ---- ph2 ----
    SAK(0, tp2, cur); SBK(0, tp2, cur);
    mm16<1, 0>(acc, a1, b0);
    asm volatile("s_waitcnt vmcnt(4)" ::: "memory");
    __builtin_amdgcn_s_barrier();
    __builtin_amdgcn_sched_barrier(0);
    rd_a<0>(a0, As_n, wr, fr, fq, swz);
    rd_b<0>(b0, Bs_n, wc, fr, fq, swz);
    // ---- ph3 ----
    SAK(1, tp2, cur); SBK(1, tp2, cur);
    mm16<1, 1>(acc, a1, b1);
  }
#undef SAK
#undef SBK
}

// =======================================================================
// GEMM1: h = relu(A[M x 2048] * W1t^T + b1) -> bf16 hbuf.
// Invalid blocks pack W2 f32->bf16^T into wt2 (reg-prefetched, stride-73,
// double LDS buffer) — unchanged from R12.
// =======================================================================
__global__ __launch_bounds__(512, 2) void g1k(
    const unsigned short* __restrict__ Ash, const unsigned short* __restrict__ Art,
    const unsigned short* __restrict__ wt1,
    const float* __restrict__ bE, const float* __restrict__ bS,
    unsigned short* __restrict__ hout,
    const int* __restrict__ counts, const int* __restrict__ offs,
    int do_pack, const float* __restrict__ we_w2, const float* __restrict__ ws_w2,
    unsigned short* __restrict__ wt2) {
  constexpr int K = HD;
  constexpr int NBX = FF / 256;         // 32
  constexpr int NWG = NBX * 16;         // 512
  extern __shared__ unsigned short smem[];

  const int e = blockIdx.z;
  int M;
  const unsigned short* A;
  const float* bias;
  int hbase;
  if (e < NE) {
    M = counts[e];
    A = Art + (size_t)offs[e] * K;
    bias = bE + (size_t)e * FF;
    hbase = offs[e];
  } else {
    M = TOKENS;
    A = Ash;
    bias = bS + (size_t)(e - NE) * FF;
    hbase = 2 * TOKENS + (e - NE) * TOKENS;
  }
  const unsigned short* Bt = wt1 + (size_t)e * HD * FF;

  int flat = blockIdx.x + NBX * blockIdx.y;
  flat = (flat & 7) * (NWG >> 3) + (flat >> 3);
  const int m0 = (flat & 15) * 256;
  const int n0 = (flat >> 4) * 256;
  const int tid = threadIdx.x;

  if (m0 >= M) {
    if (!do_pack) return;
    int total = 0, prefix = 0;
    for (int e2 = 0; e2 < NE; ++e2) {
      int mb = (counts[e2] + 255) >> 8; if (mb > 16) mb = 16;
      const int inv = 32 * (16 - mb);
      if (e2 < e) prefix += inv;
      total += inv;
    }
    int mb_e = (counts[e] + 255) >> 8; if (mb_e > 16) mb_e = 16;
    const int m_idx = flat & 15, n_idx = flat >> 4;
    const int rank = prefix + n_idx * (16 - mb_e) + (m_idx - mb_e);
    unsigned short* ps = smem;  // [2][64][73]
    const int NT = 10 * 128 * 32;
    const int kk = tid >> 3, cc = (tid & 7) * 8;
    float4 r0a, r0b;
    int i = rank;
    if (i < NT) {
      const int e2 = i >> 12, rem = i & 4095, ktt = rem >> 5, ntt = rem & 31;
      const float* src = (e2 < NE) ? (we_w2 + (size_t)e2 * FF * HD)
                                   : (ws_w2 + (size_t)(e2 - NE) * FF * HD);
      const float* sp = src + (size_t)(ktt * 64 + kk) * HD + ntt * 64 + cc;
      r0a = *(const float4*)sp; r0b = *(const float4*)(sp + 4);
    }
    int it = 0;
    while (i < NT) {
      const int inext = i + total;
      float4 r1a, r1b;
      if (inext < NT) {
        const int e2 = inext >> 12, rem = inext & 4095, ktt = rem >> 5, ntt = rem & 31;
        const float* src = (e2 < NE) ? (we_w2 + (size_t)e2 * FF * HD)
                                     : (ws_w2 + (size_t)(e2 - NE) * FF * HD);
        const float* sp = src + (size_t)(ktt * 64 + kk) * HD + ntt * 64 + cc;
        r1a = *(const float4*)sp; r1b = *(const float4*)(sp + 4);
      }
      unsigned short* pb = ps + (it & 1) * (64 * 73);
      {
        unsigned short* tp = pb + kk * 73 + cc;
        tp[0] = f2bf(r0a.x); tp[1] = f2bf(r0a.y); tp[2] = f2bf(r0a.z); tp[3] = f2bf(r0a.w);
        tp[4] = f2bf(r0b.x); tp[5] = f2bf(r0b.y); tp[6] = f2bf(r0b.z); tp[7] = f2bf(r0b.w);
      }
      __syncthreads();
      {
        const int e2 = i >> 12, rem = i & 4095, ktt = rem >> 5, ntt = rem & 31;
        unsigned short* dst = wt2 + (size_t)e2 * HD * FF;
        const int nn = tid >> 3, kc = (tid & 7) * 8;
        unsigned u[4];
#pragma unroll
        for (int j = 0; j < 4; ++j)
          u[j] = (unsigned)pb[(kc + 2 * j) * 73 + nn] |
                 ((unsigned)pb[(kc + 2 * j + 1) * 73 + nn] << 16);
        uint4 v; v.x = u[0]; v.y = u[1]; v.z = u[2]; v.w = u[3];
        *(uint4*)(dst + (size_t)(ntt * 64 + nn) * FF + ktt * 64 + kc) = v;
      }
      r0a = r1a; r0b = r1b;
      i = inext; ++it;
    }
    return;
  }

  const int wid = tid >> 6, ln = tid & 63;
  const int wr = wid >> 2, wc = wid & 3;
  const int fr = ln & 15, fq = ln >> 4;
  const int swz = fr & 7;
  const int lr8 = ln >> 3;
  const int lc8 = ln & 7;
  const int scol = (lc8 ^ lr8) << 3;
  const int wrA = wr * 128 + wc * 16;
  const int wcB = wc * 64 + wr * 16;

  f32x4 acc[8][4];
#pragma unroll
  for (int i = 0; i < 8; ++i)
#pragma unroll
    for (int j = 0; j < 4; ++j) acc[i][j] = (f32x4){0.f, 0.f, 0.f, 0.f};

  kloop<K>(A, A, Bt, Bt, 1 << 30, smem, m0, n0, acc, wr, wc, fr, fq, swz,
           wrA, wcB, lr8, lc8, scol, K / 64);

#pragma unroll
  for (int nn = 0; nn < 4; ++nn) {
#pragma unroll
    for (int mm = 0; mm < 8; ++mm) {
      const int col = n0 + wc * 64 + (nn >> 1) * 32 + (nn & 1) * 16 + fr;
      const float bb = bias[col];
#pragma unroll
      for (int j = 0; j < 4; ++j) {
        const int r = m0 + wr * 128 + (mm >> 2) * 64 + (mm & 3) * 16 + fq * 4 + j;
        if (r < M) {
          float v = acc[mm][nn][j] + bb;
          v = v > 0.f ? v : 0.f;
          hout[(size_t)(hbase + r) * FF + col] = f2bf(v);
        }
      }
    }
  }
}

// =======================================================================
// GEMM2 (z=9): routed experts (z<8) + ONE merged shared slice (z=8,
// K-concat of both shared experts: nkt=256, dual base switch at 128).
// ybuf[row] = h * W2t^T + b2 (f32, no gate, no atomics).
// =======================================================================
__global__ __launch_bounds__(512, 2) void g2k(
    const unsigned short* __restrict__ hbuf, const unsigned short* __restrict__ wt2,
    const float* __restrict__ bE, const float* __restrict__ bS,
    float* __restrict__ ybuf,
    const int* __restrict__ counts, const int* __restrict__ offs) {
  constexpr int K = FF;
  constexpr int NBX = HD / 256;         // 8
  constexpr int NWG = NBX * 16;         // 128
  extern __shared__ unsigned short smem[];

  const int e = blockIdx.z;
  const bool merged = (e == NE);
  int M, nkt, ksw, hbase;
  const unsigned short *A, *A2, *B, *B2;
  const float *bias, *bias2;
  if (!merged) {
    M = counts[e];
    A = hbuf + (size_t)offs[e] * K;  A2 = A;
    B = wt2 + (size_t)e * HD * FF;   B2 = B;
    bias = bE + (size_t)e * HD;      bias2 = nullptr;
    hbase = offs[e];
    nkt = 128; ksw = 1 << 30;
  } else {
    M = TOKENS;
    A  = hbuf + (size_t)(2 * TOKENS) * K;
    A2 = hbuf + (size_t)(3 * TOKENS) * K;
    B  = wt2 + (size_t)NE * HD * FF;
    B2 = wt2 + (size_t)(NE + 1) * HD * FF;
    bias = bS;  bias2 = bS + HD;
    hbase = 2 * TOKENS;
    nkt = 256; ksw = 128;
  }

  int flat = blockIdx.x + NBX * blockIdx.y;
  flat = (flat & 7) * (NWG >> 3) + (flat >> 3);
  const int m0 = (flat & 15) * 256;
  const int n0 = (flat >> 4) * 256;
  if (m0 >= M) return;

  const int tid = threadIdx.x;
  const int wid = tid >> 6, ln = tid & 63;
  const int wr = wid >> 2, wc = wid & 3;
  const int fr = ln & 15, fq = ln >> 4;
  const int swz = fr & 7;
  const int lr8 = ln >> 3;
  const int lc8 = ln & 7;
  const int scol = (lc8 ^ lr8) << 3;
  const int wrA = wr * 128 + wc * 16;
  const int wcB = wc * 64 + wr * 16;

  f32x4 acc[8][4];
#pragma unroll
  for (int i = 0; i < 8; ++i)
#pragma unroll
    for (int j = 0; j < 4; ++j) acc[i][j] = (f32x4){0.f, 0.f, 0.f, 0.f};

  kloop<K>(A, A2, B, B2, ksw, smem, m0, n0, acc, wr, wc, fr, fq, swz,
           wrA, wcB, lr8, lc8, scol, nkt);

#pragma unroll
  for (int nn = 0; nn < 4; ++nn) {
#pragma unroll
    for (int mm = 0; mm < 8; ++mm) {
      const int colw = wc * 64 + (nn >> 1) * 32 + (nn & 1) * 16 + fr;
      float bb = bias[n0 + colw];
      if (merged) bb += bias2[n0 + colw];
#pragma unroll
      for (int j = 0; j < 4; ++j) {
        const int r = m0 + wr * 128 + (mm >> 2) * 64 + (mm & 3) * 16 + fq * 4 + j;
        if (r < M)
          ybuf[(size_t)(hbase + r) * HD + n0 + colw] = acc[mm][nn][j] + bb;
      }
    }
  }
}

// ---------------- final reduce: out = s_merged + g0*ye0 + g1*ye1 ----------------
__global__ __launch_bounds__(256) void reduce_kernel(
    const float* __restrict__ ybuf, const int* __restrict__ row_of,
    const float* __restrict__ topv, float* __restrict__ out) {
  const int t = blockIdx.x;
  const int d = threadIdx.x * 8;
  const float g0 = topv[2 * t], g1 = topv[2 * t + 1];
  const float* y0 = ybuf + (size_t)row_of[2 * t] * HD + d;
  const float* y1 = ybuf + (size_t)row_of[2 * t + 1] * HD + d;
  const float* s0 = ybuf + (size_t)(2 * TOKENS + t) * HD + d;
  float* o = out + (size_t)t * HD + d;
#pragma unroll
  for (int q = 0; q < 2; ++q) {
    const float4 a = *(const float4*)(s0 + q * 4);
    const float4 c = *(const float4*)(y0 + q * 4);
    const float4 e = *(const float4*)(y1 + q * 4);
    float4 r;
    r.x = a.x + g0 * c.x + g1 * e.x;
    r.y = a.y + g0 * c.y + g1 * e.y;
    r.z = a.z + g0 * c.z + g1 * e.z;
    r.w = a.w + g0 * c.w + g1 * e.w;
    *(float4*)(o + q * 4) = r;
  }
}

extern "C" void kernel_launch(void* const* d_in, const int* in_sizes, int n_in,
                              void* d_out, int out_size, void* d_ws, size_t ws_size,
                              hipStream_t stream) {
  const float* x     = (const float*)d_in[0];
  const float* ws_w1 = (const float*)d_in[1];
  const float* ws_b1 = (const float*)d_in[2];
  const float* ws_w2 = (const float*)d_in[3];
  const float* ws_b2 = (const float*)d_in[4];
  const float* we_w1 = (const float*)d_in[5];
  const float* we_b1 = (const float*)d_in[6];
  const float* we_w2 = (const float*)d_in[7];
  const float* we_b2 = (const float*)d_in[8];
  const float* wg    = (const float*)d_in[9];

  float* out = (float*)d_out;
  float* logits = out + (size_t)TOKENS * HD;

  hipFuncSetAttribute(reinterpret_cast<const void*>(g1k),
                      hipFuncAttributeMaxDynamicSharedMemorySize, 131072);
  hipFuncSetAttribute(reinterpret_cast<const void*>(g2k),
                      hipFuncAttributeMaxDynamicSharedMemorySize, 131072);

  char* ws = (char*)d_ws;
  unsigned short* wt1  = (unsigned short*)ws;                   // 335,544,320
  unsigned short* wt2  = (unsigned short*)(ws + 335544320);     // 335,544,320
  unsigned short* xb   = (unsigned short*)(ws + 671088640);     //  16,777,216
  unsigned short* xg   = (unsigned short*)(ws + 687865856);     //  34,078,720
  unsigned short* hbuf = (unsigned short*)(ws + 721944576);     // 268,435,456
  char* ctrl = ws + 990380032;
  float* ybuf = (float*)ws;   // alias wt1 (dead by GEMM2): 12288 rows = 100 MB
  int*   row_token = (int*)(ctrl);
  float* row_gate  = (float*)(ctrl + 32768);
  int*   topi      = (int*)(ctrl + 65536);
  float* topv      = (float*)(ctrl + 98304);
  int*   counts    = (int*)(ctrl + 131072);
  int*   offs      = (int*)(ctrl + 131104);
  int*   cursors   = (int*)(ctrl + 131136);
  int*   row_of    = (int*)(ctrl + 131168);

  hipMemsetAsync(counts, 0, NE * sizeof(int), stream);
  router_kernel<<<1024, 256, 0, stream>>>(x, wg, logits, topi, topv, counts, xb);
  offs_kernel<<<1, 64, 0, stream>>>(counts, offs, cursors);
  gather_kernel<<<1024, 256, 0, stream>>>(xb, topi, topv, cursors, xg,
                                          row_token, row_gate, row_of);
  pack_wt<HD, FF><<<dim3(FF / 64, HD / 64, 10), 256, 0, stream>>>(we_w1, ws_w1, wt1);
  g1k<<<dim3(32, 16, 10), 512, 131072, stream>>>(
      xb, xg, wt1, we_b1, ws_b1, hbuf, counts, offs, 1, we_w2, ws_w2, wt2);
  g2k<<<dim3(8, 16, 9), 512, 131072, stream>>>(
      hbuf, wt2, we_b2, ws_b2, ybuf, counts, offs);
  reduce_kernel<<<TOKENS, 256, 0, stream>>>(ybuf, row_of, topv, out);

  (void)in_sizes; (void)n_in; (void)out_size; (void)ws_size;
}